// Round 3
// baseline (823.546 us; speedup 1.0000x reference)
//
#include <hip/hip_runtime.h>
#include <math.h>

// GLA: B=2, N=1024, D=1024, H=4, KD=512, VD=1024, DK=128, DV=256, LR=16
// M = B*N = 2048 rows. All inputs/outputs fp32 (per reference dtypes).
// Workspace: all fp32, ~34.2 MB.

typedef __attribute__((ext_vector_type(4))) float vf4;

#define DEVI static __device__ __forceinline__
DEVI vf4 vzero() { vf4 x = {0.f, 0.f, 0.f, 0.f}; return x; }

// ---------------------------------------------------------------------------
// Projection GEMM: X[2048,1024] @ {Wq,Wk,Wv,Wg} (all fp32).
// 128x128 tile, 256 threads, 8x8 per thread, K-step 16. grid (24,16).
// nt 0..3 -> q, 4..7 -> k, 8..15 -> v, 16..23 -> g(silu).
// ---------------------------------------------------------------------------
__global__ __launch_bounds__(256)
void proj_k(const float* __restrict__ X,
            const float* __restrict__ Wq, const float* __restrict__ Wk,
            const float* __restrict__ Wv, const float* __restrict__ Wg,
            float* __restrict__ qb, float* __restrict__ kb,
            float* __restrict__ vb, float* __restrict__ sgb) {
  __shared__ float As[16][128];
  __shared__ float Bs[16][128];
  const int t = threadIdx.x;
  const int m0 = blockIdx.y << 7;
  const int nt = blockIdx.x;
  const float* W; float* Y; int N; int n0; int silu = 0;
  if (nt < 4)       { W = Wq; Y = qb;  N = 512;  n0 = nt * 128; }
  else if (nt < 8)  { W = Wk; Y = kb;  N = 512;  n0 = (nt - 4) * 128; }
  else if (nt < 16) { W = Wv; Y = vb;  N = 1024; n0 = (nt - 8) * 128; }
  else              { W = Wg; Y = sgb; N = 1024; n0 = (nt - 16) * 128; silu = 1; }

  const int r = t >> 4, c = t & 15;
  const int am = t >> 1, ah = t & 1;
  const int bk = t >> 4, bs = t & 15;
  const int K = 1024;
  float acc[8][8];
#pragma unroll
  for (int i = 0; i < 8; ++i)
#pragma unroll
    for (int j = 0; j < 8; ++j) acc[i][j] = 0.f;

  for (int k0 = 0; k0 < K; k0 += 16) {
    const float* ap = X + (size_t)(m0 + am) * K + k0 + ah * 8;
    vf4 a0 = *(const vf4*)ap, a1 = *(const vf4*)(ap + 4);
    const float* bp = W + (size_t)(k0 + bk) * N + n0 + bs * 8;
    vf4 b0 = *(const vf4*)bp, b1 = *(const vf4*)(bp + 4);
    float fa[8] = {a0.x, a0.y, a0.z, a0.w, a1.x, a1.y, a1.z, a1.w};
    float fb[8] = {b0.x, b0.y, b0.z, b0.w, b1.x, b1.y, b1.z, b1.w};
#pragma unroll
    for (int j = 0; j < 8; ++j) As[ah * 8 + j][am] = fa[j];
#pragma unroll
    for (int j = 0; j < 8; ++j) Bs[bk][bs * 8 + j] = fb[j];
    __syncthreads();
#pragma unroll
    for (int kk = 0; kk < 16; ++kk) {
      vf4 x0 = *(const vf4*)&As[kk][r * 8];
      vf4 x1 = *(const vf4*)&As[kk][r * 8 + 4];
      vf4 y0 = *(const vf4*)&Bs[kk][c * 8];
      vf4 y1 = *(const vf4*)&Bs[kk][c * 8 + 4];
      float av[8] = {x0.x, x0.y, x0.z, x0.w, x1.x, x1.y, x1.z, x1.w};
      float bv[8] = {y0.x, y0.y, y0.z, y0.w, y1.x, y1.y, y1.z, y1.w};
#pragma unroll
      for (int i = 0; i < 8; ++i)
#pragma unroll
        for (int j = 0; j < 8; ++j)
          acc[i][j] = fmaf(av[i], bv[j], acc[i][j]);
    }
    __syncthreads();
  }
#pragma unroll
  for (int i = 0; i < 8; ++i) {
    const size_t row = (size_t)(m0 + r * 8 + i);
#pragma unroll
    for (int j = 0; j < 8; ++j) {
      float v = acc[i][j];
      if (silu) v = v / (1.f + expf(-v));
      Y[row * N + n0 + c * 8 + j] = v;
    }
  }
}

// ---------------------------------------------------------------------------
// Output GEMM: obuf[2048,1024] @ Wout[1024,1024] -> d_out (all fp32). grid (8,16).
// ---------------------------------------------------------------------------
__global__ __launch_bounds__(256)
void out_k(const float* __restrict__ A, const float* __restrict__ W,
           float* __restrict__ Y) {
  __shared__ float As[16][128];
  __shared__ float Bs[16][128];
  const int t = threadIdx.x;
  const int m0 = blockIdx.y << 7;
  const int n0 = blockIdx.x << 7;
  const int N = 1024, K = 1024;
  const int r = t >> 4, c = t & 15;
  const int am = t >> 1, ah = t & 1;
  const int bk = t >> 4, bs = t & 15;
  float acc[8][8];
#pragma unroll
  for (int i = 0; i < 8; ++i)
#pragma unroll
    for (int j = 0; j < 8; ++j) acc[i][j] = 0.f;

  for (int k0 = 0; k0 < K; k0 += 16) {
    const float* ap = A + (size_t)(m0 + am) * K + k0 + ah * 8;
    vf4 a0 = *(const vf4*)ap, a1 = *(const vf4*)(ap + 4);
    const float* bp = W + (size_t)(k0 + bk) * N + n0 + bs * 8;
    vf4 b0 = *(const vf4*)bp, b1 = *(const vf4*)(bp + 4);
    float fa[8] = {a0.x, a0.y, a0.z, a0.w, a1.x, a1.y, a1.z, a1.w};
    float fb[8] = {b0.x, b0.y, b0.z, b0.w, b1.x, b1.y, b1.z, b1.w};
#pragma unroll
    for (int j = 0; j < 8; ++j) As[ah * 8 + j][am] = fa[j];
#pragma unroll
    for (int j = 0; j < 8; ++j) Bs[bk][bs * 8 + j] = fb[j];
    __syncthreads();
#pragma unroll
    for (int kk = 0; kk < 16; ++kk) {
      vf4 x0 = *(const vf4*)&As[kk][r * 8];
      vf4 x1 = *(const vf4*)&As[kk][r * 8 + 4];
      vf4 y0 = *(const vf4*)&Bs[kk][c * 8];
      vf4 y1 = *(const vf4*)&Bs[kk][c * 8 + 4];
      float av[8] = {x0.x, x0.y, x0.z, x0.w, x1.x, x1.y, x1.z, x1.w};
      float bv[8] = {y0.x, y0.y, y0.z, y0.w, y1.x, y1.y, y1.z, y1.w};
#pragma unroll
      for (int i = 0; i < 8; ++i)
#pragma unroll
        for (int j = 0; j < 8; ++j)
          acc[i][j] = fmaf(av[i], bv[j], acc[i][j]);
    }
    __syncthreads();
  }
#pragma unroll
  for (int i = 0; i < 8; ++i) {
    const size_t row = (size_t)(m0 + r * 8 + i);
#pragma unroll
    for (int j = 0; j < 8; ++j)
      Y[row * N + n0 + c * 8 + j] = acc[i][j];
  }
}

// ---------------------------------------------------------------------------
// xl = x @ Wgk1 [2048,16]. One wave per row.
// ---------------------------------------------------------------------------
__global__ __launch_bounds__(64)
void lowrank_k(const float* __restrict__ X, const float* __restrict__ W1,
               float* __restrict__ xl) {
  const int row = blockIdx.x;
  const int t = threadIdx.x;
  float acc[16];
#pragma unroll
  for (int c2 = 0; c2 < 16; ++c2) acc[c2] = 0.f;
  const float* xp = X + (size_t)row * 1024 + t * 16;
  float xv[16];
#pragma unroll
  for (int u = 0; u < 4; ++u)
    *(vf4*)&xv[u * 4] = *(const vf4*)(xp + u * 4);
#pragma unroll
  for (int j = 0; j < 16; ++j) {
    const float* wp = W1 + (size_t)(t * 16 + j) * 16;
    float wv[16];
#pragma unroll
    for (int u = 0; u < 4; ++u)
      *(vf4*)&wv[u * 4] = *(const vf4*)(wp + u * 4);
#pragma unroll
    for (int c2 = 0; c2 < 16; ++c2) acc[c2] = fmaf(xv[j], wv[c2], acc[c2]);
  }
#pragma unroll
  for (int m = 1; m < 64; m <<= 1) {
#pragma unroll
    for (int c2 = 0; c2 < 16; ++c2) acc[c2] += __shfl_xor(acc[c2], m, 64);
  }
  if (t == 0) {
#pragma unroll
    for (int c2 = 0; c2 < 16; ++c2) xl[(size_t)row * 16 + c2] = acc[c2];
  }
}

// ---------------------------------------------------------------------------
// Fused gate + in-chunk cumsum + q/k scaling. One thread per (b,chunk,kcol).
// g = max(logsigmoid(xl@W2+b)/16, -3); run = cumsum(g) <= 0;
// q *= e^run; k *= e^-run (clamped); ebtot = e^{run_total}.
// ---------------------------------------------------------------------------
__global__ __launch_bounds__(256)
void cumsum_gate_k(const float* __restrict__ xl, const float* __restrict__ W2,
                   const float* __restrict__ bias,
                   float* __restrict__ q, float* __restrict__ k,
                   float* __restrict__ ebtot) {
  const int idx = blockIdx.x * 256 + threadIdx.x;  // 0..16383
  const int kcol = idx & 511;
  const int c = (idx >> 9) & 15;
  const int bb = idx >> 13;
  float w2[16];
#pragma unroll
  for (int r = 0; r < 16; ++r) w2[r] = W2[r * 512 + kcol];
  const float bz = bias[kcol];

  float run = 0.f;
  for (int i = 0; i < 64; ++i) {
    const size_t row = (size_t)bb * 1024 + c * 64 + i;
    const float* xp = xl + row * 16;
    float z = bz;
#pragma unroll
    for (int r = 0; r < 16; ++r) z = fmaf(xp[r], w2[r], z);
    float ls = fminf(z, 0.f) - log1pf(expf(-fabsf(z)));
    run += fmaxf(ls * (1.f / 16.f), -3.f);  // g in [-3, 0]
    const size_t a = row * 512 + kcol;
    q[a] *= expf(run);                      // run <= 0
    k[a] *= expf(fminf(-run, 80.f));        // clamped, never inf
  }
  ebtot[(((size_t)bb * 16 + c) << 9) + kcol] = expf(run);
}

// ---------------------------------------------------------------------------
// A = tril(Q~ K~^T) per (chunk, bh): [64x64], K=128. grid (16,8).
// ---------------------------------------------------------------------------
__global__ __launch_bounds__(256)
void qk_k(const float* __restrict__ q, const float* __restrict__ kb,
          float* __restrict__ A) {
  __shared__ float Ks[64 * 128];  // 32 KB
  const int t = threadIdx.x;
  const int c = blockIdx.x, bh = blockIdx.y;
  const int b = bh >> 2, h = bh & 3;
  const size_t rowbase = (size_t)b * 1024 + c * 64;
  {
    const int r = t >> 2, s = t & 3;
    const float* kp = kb + (rowbase + r) * 512 + h * 128 + s * 32;
#pragma unroll
    for (int u = 0; u < 8; ++u)
      *(vf4*)&Ks[r * 128 + s * 32 + u * 4] = *(const vf4*)(kp + u * 4);
  }
  __syncthreads();
  const int i = t >> 2, jb = t & 3;
  float acc[16];
#pragma unroll
  for (int u = 0; u < 16; ++u) acc[u] = 0.f;
  const float* qp = q + (rowbase + i) * 512 + h * 128;
  for (int kk = 0; kk < 128; kk += 4) {
    vf4 qv = *(const vf4*)(qp + kk);
#pragma unroll
    for (int u = 0; u < 16; ++u) {
      const float* kr = &Ks[(jb + 4 * u) * 128 + kk];
      acc[u] += qv.x * kr[0] + qv.y * kr[1] + qv.z * kr[2] + qv.w * kr[3];
    }
  }
  float* Ap = A + (((size_t)bh * 16 + c) * 64 + i) * 64;
#pragma unroll
  for (int u = 0; u < 16; ++u) {
    const int j = jb + 4 * u;
    Ap[j] = (j <= i) ? acc[u] : 0.f;
  }
}

// ---------------------------------------------------------------------------
// o_intra = A @ V : [64x256] per (chunk, bh). Writes obuf. grid (16,8).
// ---------------------------------------------------------------------------
__global__ __launch_bounds__(256)
void av_k(const float* __restrict__ A, const float* __restrict__ v,
          float* __restrict__ o) {
  __shared__ float As[64 * 64];  // 16 KB
  __shared__ float Vs[64 * 64];  // 16 KB
  const int t = threadIdx.x;
  const int c = blockIdx.x, bh = blockIdx.y;
  const int b = bh >> 2, h = bh & 3;
  const size_t rowbase = (size_t)b * 1024 + c * 64;
  {
    const int r = t >> 2, s = t & 3;
    const float* Ap = A + (((size_t)bh * 16 + c) * 64 + r) * 64 + s * 16;
#pragma unroll
    for (int u = 0; u < 4; ++u)
      *(vf4*)&As[r * 64 + s * 16 + u * 4] = *(const vf4*)(Ap + u * 4);
  }
  const int i = t >> 2, sb = t & 3;
  for (int vt = 0; vt < 4; ++vt) {
    __syncthreads();  // As staged (vt=0); prior Vs reads done (vt>0)
    {
      const int r = t >> 2, s = t & 3;
      const float* vp = v + (rowbase + r) * 1024 + h * 256 + vt * 64 + s * 16;
#pragma unroll
      for (int u = 0; u < 4; ++u)
        *(vf4*)&Vs[r * 64 + s * 16 + u * 4] = *(const vf4*)(vp + u * 4);
    }
    __syncthreads();
    vf4 acc[4];
#pragma unroll
    for (int u = 0; u < 4; ++u) acc[u] = vzero();
    for (int jj = 0; jj < 64; ++jj) {
      const float a = As[i * 64 + jj];
#pragma unroll
      for (int u = 0; u < 4; ++u)
        acc[u] += a * *(const vf4*)&Vs[jj * 64 + sb * 16 + u * 4];
    }
    float* op = o + (rowbase + i) * 1024 + h * 256 + vt * 64 + sb * 16;
#pragma unroll
    for (int u = 0; u < 4; ++u) *(vf4*)(op + u * 4) = acc[u];
  }
}

// ---------------------------------------------------------------------------
// Sequential inter-chunk scan. grid (vt=4, bh=8) = 32 blocks.
// S[128,64] in LDS. Per chunk: o += Q~ @ S; S = ebtot*(S + K~^T V).
// ---------------------------------------------------------------------------
__global__ __launch_bounds__(256)
void scan_k(const float* __restrict__ q, const float* __restrict__ kb,
            const float* __restrict__ v, const float* __restrict__ ebtot,
            float* __restrict__ o) {
  __shared__ float S[128 * 64];   // 32 KB
  __shared__ float Vs[64 * 64];   // 16 KB
  const int t = threadIdx.x;
  const int vt = blockIdx.x, bh = blockIdx.y;
  const int b = bh >> 2, h = bh & 3;
  for (int u = t; u < 128 * 64; u += 256) S[u] = 0.f;
  const int i = t >> 2, sb = t & 3;         // phase 1: row i, 16 cols
  const int kk = t & 127, hf = t >> 7;      // phase 2: k-row kk, 32 cols

  for (int c = 0; c < 16; ++c) {
    const size_t rowbase = (size_t)b * 1024 + c * 64;
    const int hcol = h * 256 + vt * 64;
    __syncthreads();  // S init/update complete; prior Vs reads done
    // stage V tile [64 x 64]
    {
      const int r = t >> 2, s = t & 3;
      const float* vp = v + (rowbase + r) * 1024 + hcol + s * 16;
#pragma unroll
      for (int u = 0; u < 4; ++u)
        *(vf4*)&Vs[r * 64 + s * 16 + u * 4] = *(const vf4*)(vp + u * 4);
    }
    // phase 1: o += Q~ @ S_in (reads S only; Vs staging may overlap)
    vf4 acc[4];
#pragma unroll
    for (int u = 0; u < 4; ++u) acc[u] = vzero();
    const float* qp = q + (rowbase + i) * 512 + h * 128;
    for (int k4 = 0; k4 < 128; k4 += 4) {
      vf4 qv = *(const vf4*)(qp + k4);
#pragma unroll
      for (int kq = 0; kq < 4; ++kq) {
        const float qs = (kq == 0) ? qv.x : (kq == 1) ? qv.y : (kq == 2) ? qv.z : qv.w;
        const float* sp = &S[(k4 + kq) * 64 + sb * 16];
#pragma unroll
        for (int u = 0; u < 4; ++u)
          acc[u] += qs * *(const vf4*)(sp + u * 4);
      }
    }
    {
      float* op = o + (rowbase + i) * 1024 + hcol + sb * 16;
#pragma unroll
      for (int u = 0; u < 4; ++u) {
        vf4 x0 = *(const vf4*)(op + u * 4);
        x0 += acc[u];
        *(vf4*)(op + u * 4) = x0;
      }
    }
    __syncthreads();  // S reads + Vs staging complete
    // phase 2: S[kk][hf*32..+32] = e_kk * (S + sum_j k~[j][kk] * V[j][:])
    float su[32];
#pragma unroll
    for (int u = 0; u < 32; ++u) su[u] = 0.f;
    for (int j = 0; j < 64; ++j) {
      const float kv = kb[(rowbase + j) * 512 + h * 128 + kk];
      const float* vrow = &Vs[j * 64 + hf * 32];
#pragma unroll
      for (int u = 0; u < 32; ++u) su[u] = fmaf(kv, vrow[u], su[u]);
    }
    const float ev = ebtot[((size_t)b * 16 + c) * 512 + h * 128 + kk];
    float* Sp = &S[kk * 64 + hf * 32];
#pragma unroll
    for (int u = 0; u < 32; ++u) Sp[u] = ev * (Sp[u] + su[u]);
  }
}

// ---------------------------------------------------------------------------
// RMSNorm over DV=256 per (b,n,h) + silu-gate multiply, in place on o.
// ---------------------------------------------------------------------------
__global__ __launch_bounds__(256)
void norm_gate_k(float* __restrict__ o, const float* __restrict__ rmsw,
                 const float* __restrict__ sg) {
  __shared__ float red[4];
  const int grp = blockIdx.x;          // 0..8191
  const int row = grp >> 2, h = grp & 3;
  const int t = threadIdx.x;
  const size_t idx = (size_t)row * 1024 + h * 256 + t;
  const float val = o[idx];
  float ss = val * val;
#pragma unroll
  for (int m = 1; m < 64; m <<= 1) ss += __shfl_xor(ss, m, 64);
  if ((t & 63) == 0) red[t >> 6] = ss;
  __syncthreads();
  const float tot = red[0] + red[1] + red[2] + red[3];
  const float scale = rsqrtf(tot * (1.f / 256.f) + 1e-5f);
  o[idx] = val * scale * rmsw[t] * sg[idx];
}

// ---------------------------------------------------------------------------
extern "C" void kernel_launch(void* const* d_in, const int* in_sizes, int n_in,
                              void* d_out, int out_size, void* d_ws, size_t ws_size,
                              hipStream_t stream) {
  const float* x    = (const float*)d_in[0];
  const float* Wq   = (const float*)d_in[1];
  const float* Wk   = (const float*)d_in[2];
  const float* Wv   = (const float*)d_in[3];
  const float* Wg   = (const float*)d_in[4];
  const float* Wgk1 = (const float*)d_in[5];
  const float* Wgk2 = (const float*)d_in[6];
  const float* bgk2 = (const float*)d_in[7];
  const float* Wout = (const float*)d_in[8];
  const float* rmsw = (const float*)d_in[9];

  // Workspace layout (fp32, ~34.2 MB)
  float* qbuf  = (float*)d_ws;         // 1,048,576
  float* kbuf  = qbuf  + 1048576;      // 1,048,576
  float* vbuf  = kbuf  + 1048576;      // 2,097,152
  float* sgbuf = vbuf  + 2097152;      // 2,097,152
  float* Abuf  = sgbuf + 2097152;      //   524,288
  float* obuf  = Abuf  + 524288;       // 2,097,152
  float* xlbuf = obuf  + 2097152;      //    32,768
  float* ebbuf = xlbuf + 32768;        //    16,384

  proj_k<<<dim3(24, 16), 256, 0, stream>>>(x, Wq, Wk, Wv, Wg, qbuf, kbuf, vbuf, sgbuf);
  lowrank_k<<<2048, 64, 0, stream>>>(x, Wgk1, xlbuf);
  cumsum_gate_k<<<64, 256, 0, stream>>>(xlbuf, Wgk2, bgk2, qbuf, kbuf, ebbuf);
  qk_k<<<dim3(16, 8), 256, 0, stream>>>(qbuf, kbuf, Abuf);
  av_k<<<dim3(16, 8), 256, 0, stream>>>(Abuf, vbuf, obuf);
  scan_k<<<dim3(4, 8), 256, 0, stream>>>(qbuf, kbuf, vbuf, ebbuf, obuf);
  norm_gate_k<<<8192, 256, 0, stream>>>(obuf, rmsw, sgbuf);
  out_k<<<dim3(8, 16), 256, 0, stream>>>(obuf, Wout, (float*)d_out);
}

// Round 4
// 537.055 us; speedup vs baseline: 1.5334x; 1.5334x over previous
//
#include <hip/hip_runtime.h>
#include <math.h>

// GLA: B=2, N=1024, D=1024, H=4, KD=512, VD=1024, DK=128, DV=256, LR=16
// M = B*N = 2048 rows. Inputs/outputs fp32.
// Chunked scan decomposition: per-chunk KV (parallel) -> elementwise state
// scan over 16 chunks (serial but 65k-thread parallel) -> o_inter (parallel).
// Workspace ~40.2 MB: q,k fp32; v,sg bf16; obuf fp32; Sbuf fp32 (Abuf aliased).

typedef __attribute__((ext_vector_type(4))) float vf4;
typedef __attribute__((ext_vector_type(4))) unsigned int vu4;

#define DEVI static __device__ __forceinline__
DEVI vf4 vzero() { vf4 x = {0.f, 0.f, 0.f, 0.f}; return x; }

DEVI float bf2f(unsigned int u) {
  union { unsigned int i; float f; } c; c.i = u << 16; return c.f;
}
DEVI unsigned short f2bf(float f) {
  union { float f; unsigned int i; } c; c.f = f;
  unsigned int i = c.i;
  return (unsigned short)((i + 0x7fffu + ((i >> 16) & 1u)) >> 16);
}
DEVI void unpack16(const unsigned short* p, float* f) {
  vu4 a = *(const vu4*)p;
  vu4 b = *(const vu4*)(p + 8);
  f[0] = bf2f(a.x & 0xffffu); f[1] = bf2f(a.x >> 16);
  f[2] = bf2f(a.y & 0xffffu); f[3] = bf2f(a.y >> 16);
  f[4] = bf2f(a.z & 0xffffu); f[5] = bf2f(a.z >> 16);
  f[6] = bf2f(a.w & 0xffffu); f[7] = bf2f(a.w >> 16);
  f[8]  = bf2f(b.x & 0xffffu); f[9]  = bf2f(b.x >> 16);
  f[10] = bf2f(b.y & 0xffffu); f[11] = bf2f(b.y >> 16);
  f[12] = bf2f(b.z & 0xffffu); f[13] = bf2f(b.z >> 16);
  f[14] = bf2f(b.w & 0xffffu); f[15] = bf2f(b.w >> 16);
}

// ---------------------------------------------------------------------------
// Projection GEMM: X[2048,1024] @ {Wq,Wk,Wv,Wg}. q,k fp32; v,sg(silu) bf16.
// 128x128 tile, 256 threads, 8x8/thread. grid (24,16).
// ---------------------------------------------------------------------------
__global__ __launch_bounds__(256)
void proj_k(const float* __restrict__ X,
            const float* __restrict__ Wq, const float* __restrict__ Wk,
            const float* __restrict__ Wv, const float* __restrict__ Wg,
            float* __restrict__ qb, float* __restrict__ kb,
            unsigned short* __restrict__ vb, unsigned short* __restrict__ sgb) {
  __shared__ float As[16][128];
  __shared__ float Bs[16][128];
  const int t = threadIdx.x;
  const int m0 = blockIdx.y << 7;
  const int nt = blockIdx.x;
  const float* W; int N; int n0; int kind;
  if (nt < 4)       { W = Wq; N = 512;  n0 = nt * 128;        kind = 0; }
  else if (nt < 8)  { W = Wk; N = 512;  n0 = (nt - 4) * 128;  kind = 1; }
  else if (nt < 16) { W = Wv; N = 1024; n0 = (nt - 8) * 128;  kind = 2; }
  else              { W = Wg; N = 1024; n0 = (nt - 16) * 128; kind = 3; }

  const int r = t >> 4, c = t & 15;
  const int am = t >> 1, ah = t & 1;
  const int bk = t >> 4, bs = t & 15;
  const int K = 1024;
  float acc[8][8];
#pragma unroll
  for (int i = 0; i < 8; ++i)
#pragma unroll
    for (int j = 0; j < 8; ++j) acc[i][j] = 0.f;

  for (int k0 = 0; k0 < K; k0 += 16) {
    const float* ap = X + (size_t)(m0 + am) * K + k0 + ah * 8;
    vf4 a0 = *(const vf4*)ap, a1 = *(const vf4*)(ap + 4);
    const float* bp = W + (size_t)(k0 + bk) * N + n0 + bs * 8;
    vf4 b0 = *(const vf4*)bp, b1 = *(const vf4*)(bp + 4);
    float fa[8] = {a0.x, a0.y, a0.z, a0.w, a1.x, a1.y, a1.z, a1.w};
    float fb[8] = {b0.x, b0.y, b0.z, b0.w, b1.x, b1.y, b1.z, b1.w};
#pragma unroll
    for (int j = 0; j < 8; ++j) As[ah * 8 + j][am] = fa[j];
#pragma unroll
    for (int j = 0; j < 8; ++j) Bs[bk][bs * 8 + j] = fb[j];
    __syncthreads();
#pragma unroll
    for (int kk = 0; kk < 16; ++kk) {
      vf4 x0 = *(const vf4*)&As[kk][r * 8];
      vf4 x1 = *(const vf4*)&As[kk][r * 8 + 4];
      vf4 y0 = *(const vf4*)&Bs[kk][c * 8];
      vf4 y1 = *(const vf4*)&Bs[kk][c * 8 + 4];
      float av[8] = {x0.x, x0.y, x0.z, x0.w, x1.x, x1.y, x1.z, x1.w};
      float bv[8] = {y0.x, y0.y, y0.z, y0.w, y1.x, y1.y, y1.z, y1.w};
#pragma unroll
      for (int i = 0; i < 8; ++i)
#pragma unroll
        for (int j = 0; j < 8; ++j)
          acc[i][j] = fmaf(av[i], bv[j], acc[i][j]);
    }
    __syncthreads();
  }
  if (kind < 2) {
    float* Y = (kind == 0) ? qb : kb;
#pragma unroll
    for (int i = 0; i < 8; ++i) {
      const size_t row = (size_t)(m0 + r * 8 + i);
#pragma unroll
      for (int j = 0; j < 8; ++j)
        Y[row * 512 + n0 + c * 8 + j] = acc[i][j];
    }
  } else {
    unsigned short* Y = (kind == 2) ? vb : sgb;
#pragma unroll
    for (int i = 0; i < 8; ++i) {
      const size_t row = (size_t)(m0 + r * 8 + i);
#pragma unroll
      for (int j = 0; j < 8; ++j) {
        float val = acc[i][j];
        if (kind == 3) val = val / (1.f + expf(-val));
        Y[row * 1024 + n0 + c * 8 + j] = f2bf(val);
      }
    }
  }
}

// ---------------------------------------------------------------------------
// Output GEMM: obuf[2048,1024] @ Wout -> d_out (fp32). grid (8,16).
// ---------------------------------------------------------------------------
__global__ __launch_bounds__(256)
void out_k(const float* __restrict__ A, const float* __restrict__ W,
           float* __restrict__ Y) {
  __shared__ float As[16][128];
  __shared__ float Bs[16][128];
  const int t = threadIdx.x;
  const int m0 = blockIdx.y << 7;
  const int n0 = blockIdx.x << 7;
  const int N = 1024, K = 1024;
  const int r = t >> 4, c = t & 15;
  const int am = t >> 1, ah = t & 1;
  const int bk = t >> 4, bs = t & 15;
  float acc[8][8];
#pragma unroll
  for (int i = 0; i < 8; ++i)
#pragma unroll
    for (int j = 0; j < 8; ++j) acc[i][j] = 0.f;

  for (int k0 = 0; k0 < K; k0 += 16) {
    const float* ap = A + (size_t)(m0 + am) * K + k0 + ah * 8;
    vf4 a0 = *(const vf4*)ap, a1 = *(const vf4*)(ap + 4);
    const float* bp = W + (size_t)(k0 + bk) * N + n0 + bs * 8;
    vf4 b0 = *(const vf4*)bp, b1 = *(const vf4*)(bp + 4);
    float fa[8] = {a0.x, a0.y, a0.z, a0.w, a1.x, a1.y, a1.z, a1.w};
    float fb[8] = {b0.x, b0.y, b0.z, b0.w, b1.x, b1.y, b1.z, b1.w};
#pragma unroll
    for (int j = 0; j < 8; ++j) As[ah * 8 + j][am] = fa[j];
#pragma unroll
    for (int j = 0; j < 8; ++j) Bs[bk][bs * 8 + j] = fb[j];
    __syncthreads();
#pragma unroll
    for (int kk = 0; kk < 16; ++kk) {
      vf4 x0 = *(const vf4*)&As[kk][r * 8];
      vf4 x1 = *(const vf4*)&As[kk][r * 8 + 4];
      vf4 y0 = *(const vf4*)&Bs[kk][c * 8];
      vf4 y1 = *(const vf4*)&Bs[kk][c * 8 + 4];
      float av[8] = {x0.x, x0.y, x0.z, x0.w, x1.x, x1.y, x1.z, x1.w};
      float bv[8] = {y0.x, y0.y, y0.z, y0.w, y1.x, y1.y, y1.z, y1.w};
#pragma unroll
      for (int i = 0; i < 8; ++i)
#pragma unroll
        for (int j = 0; j < 8; ++j)
          acc[i][j] = fmaf(av[i], bv[j], acc[i][j]);
    }
    __syncthreads();
  }
#pragma unroll
  for (int i = 0; i < 8; ++i) {
    const size_t row = (size_t)(m0 + r * 8 + i);
#pragma unroll
    for (int j = 0; j < 8; ++j)
      Y[row * N + n0 + c * 8 + j] = acc[i][j];
  }
}

// ---------------------------------------------------------------------------
// xl = x @ Wgk1 [2048,16]. One wave per row.
// ---------------------------------------------------------------------------
__global__ __launch_bounds__(64)
void lowrank_k(const float* __restrict__ X, const float* __restrict__ W1,
               float* __restrict__ xl) {
  const int row = blockIdx.x;
  const int t = threadIdx.x;
  float acc[16];
#pragma unroll
  for (int c2 = 0; c2 < 16; ++c2) acc[c2] = 0.f;
  const float* xp = X + (size_t)row * 1024 + t * 16;
  float xv[16];
#pragma unroll
  for (int u = 0; u < 4; ++u)
    *(vf4*)&xv[u * 4] = *(const vf4*)(xp + u * 4);
#pragma unroll
  for (int j = 0; j < 16; ++j) {
    const float* wp = W1 + (size_t)(t * 16 + j) * 16;
    float wv[16];
#pragma unroll
    for (int u = 0; u < 4; ++u)
      *(vf4*)&wv[u * 4] = *(const vf4*)(wp + u * 4);
#pragma unroll
    for (int c2 = 0; c2 < 16; ++c2) acc[c2] = fmaf(xv[j], wv[c2], acc[c2]);
  }
#pragma unroll
  for (int m = 1; m < 64; m <<= 1) {
#pragma unroll
    for (int c2 = 0; c2 < 16; ++c2) acc[c2] += __shfl_xor(acc[c2], m, 64);
  }
  if (t == 0) {
#pragma unroll
    for (int c2 = 0; c2 < 16; ++c2) xl[(size_t)row * 16 + c2] = acc[c2];
  }
}

// ---------------------------------------------------------------------------
// Fused gate + in-chunk cumsum + q/k scaling. One thread per (b,chunk,kcol).
// ---------------------------------------------------------------------------
__global__ __launch_bounds__(256)
void cumsum_gate_k(const float* __restrict__ xl, const float* __restrict__ W2,
                   const float* __restrict__ bias,
                   float* __restrict__ q, float* __restrict__ k,
                   float* __restrict__ ebtot) {
  const int idx = blockIdx.x * 256 + threadIdx.x;  // 0..16383
  const int kcol = idx & 511;
  const int c = (idx >> 9) & 15;
  const int bb = idx >> 13;
  float w2[16];
#pragma unroll
  for (int r = 0; r < 16; ++r) w2[r] = W2[r * 512 + kcol];
  const float bz = bias[kcol];

  float run = 0.f;
  for (int i = 0; i < 64; ++i) {
    const size_t row = (size_t)bb * 1024 + c * 64 + i;
    const float* xp = xl + row * 16;
    float z = bz;
#pragma unroll
    for (int r = 0; r < 16; ++r) z = fmaf(xp[r], w2[r], z);
    float ls = fminf(z, 0.f) - log1pf(expf(-fabsf(z)));
    run += fmaxf(ls * (1.f / 16.f), -3.f);  // g in [-3, 0]
    const size_t a = row * 512 + kcol;
    q[a] *= expf(run);
    k[a] *= expf(fminf(-run, 80.f));
  }
  ebtot[(((size_t)bb * 16 + c) << 9) + kcol] = expf(run);
}

// ---------------------------------------------------------------------------
// A = tril(Q~ K~^T) per (chunk, bh): [64x64], K=128. grid (16,8).
// ---------------------------------------------------------------------------
__global__ __launch_bounds__(256)
void qk_k(const float* __restrict__ q, const float* __restrict__ kb,
          float* __restrict__ A) {
  __shared__ float Ks[64 * 128];
  const int t = threadIdx.x;
  const int c = blockIdx.x, bh = blockIdx.y;
  const int b = bh >> 2, h = bh & 3;
  const size_t rowbase = (size_t)b * 1024 + c * 64;
  {
    const int r = t >> 2, s = t & 3;
    const float* kp = kb + (rowbase + r) * 512 + h * 128 + s * 32;
#pragma unroll
    for (int u = 0; u < 8; ++u)
      *(vf4*)&Ks[r * 128 + s * 32 + u * 4] = *(const vf4*)(kp + u * 4);
  }
  __syncthreads();
  const int i = t >> 2, jb = t & 3;
  float acc[16];
#pragma unroll
  for (int u = 0; u < 16; ++u) acc[u] = 0.f;
  const float* qp = q + (rowbase + i) * 512 + h * 128;
  for (int kk = 0; kk < 128; kk += 4) {
    vf4 qv = *(const vf4*)(qp + kk);
#pragma unroll
    for (int u = 0; u < 16; ++u) {
      const float* kr = &Ks[(jb + 4 * u) * 128 + kk];
      acc[u] += qv.x * kr[0] + qv.y * kr[1] + qv.z * kr[2] + qv.w * kr[3];
    }
  }
  float* Ap = A + (((size_t)bh * 16 + c) * 64 + i) * 64;
#pragma unroll
  for (int u = 0; u < 16; ++u) {
    const int j = jb + 4 * u;
    Ap[j] = (j <= i) ? acc[u] : 0.f;
  }
}

// ---------------------------------------------------------------------------
// o_intra = A @ V : [64x256] per (chunk, bh). Writes obuf. grid (16,8).
// ---------------------------------------------------------------------------
__global__ __launch_bounds__(256)
void av_k(const float* __restrict__ A, const unsigned short* __restrict__ v,
          float* __restrict__ o) {
  __shared__ float As[64 * 64];
  __shared__ float Vs[64 * 64];
  const int t = threadIdx.x;
  const int c = blockIdx.x, bh = blockIdx.y;
  const int b = bh >> 2, h = bh & 3;
  const size_t rowbase = (size_t)b * 1024 + c * 64;
  {
    const int r = t >> 2, s = t & 3;
    const float* Ap = A + (((size_t)bh * 16 + c) * 64 + r) * 64 + s * 16;
#pragma unroll
    for (int u = 0; u < 4; ++u)
      *(vf4*)&As[r * 64 + s * 16 + u * 4] = *(const vf4*)(Ap + u * 4);
  }
  const int i = t >> 2, sb = t & 3;
  for (int vt = 0; vt < 4; ++vt) {
    __syncthreads();
    {
      const int r = t >> 2, s = t & 3;
      const unsigned short* vp = v + (rowbase + r) * 1024 + h * 256 + vt * 64 + s * 16;
      float f[16];
      unpack16(vp, f);
#pragma unroll
      for (int u = 0; u < 16; ++u) Vs[r * 64 + s * 16 + u] = f[u];
    }
    __syncthreads();
    vf4 acc[4];
#pragma unroll
    for (int u = 0; u < 4; ++u) acc[u] = vzero();
    for (int jj = 0; jj < 64; ++jj) {
      const float a = As[i * 64 + jj];
#pragma unroll
      for (int u = 0; u < 4; ++u)
        acc[u] += a * *(const vf4*)&Vs[jj * 64 + sb * 16 + u * 4];
    }
    float* op = o + (rowbase + i) * 1024 + h * 256 + vt * 64 + sb * 16;
#pragma unroll
    for (int u = 0; u < 4; ++u) *(vf4*)(op + u * 4) = acc[u];
  }
}

// ---------------------------------------------------------------------------
// KV_c = K~^T V per (vt, chunk, bh): [128 x 64cols]. grid (4,16,8). Parallel.
// ---------------------------------------------------------------------------
__global__ __launch_bounds__(256)
void kv_k(const float* __restrict__ kb, const unsigned short* __restrict__ v,
          float* __restrict__ S) {
  __shared__ float Ks[64 * 128];  // 32 KB
  __shared__ float Vs[64 * 64];   // 16 KB
  const int t = threadIdx.x;
  const int vt = blockIdx.x, c = blockIdx.y, bh = blockIdx.z;
  const int b = bh >> 2, h = bh & 3;
  const size_t rowbase = (size_t)b * 1024 + c * 64;
  {
    const int r = t >> 2, s = t & 3;
    const float* kp = kb + (rowbase + r) * 512 + h * 128 + s * 32;
#pragma unroll
    for (int u = 0; u < 8; ++u)
      *(vf4*)&Ks[r * 128 + s * 32 + u * 4] = *(const vf4*)(kp + u * 4);
    const unsigned short* vp = v + (rowbase + r) * 1024 + h * 256 + vt * 64 + s * 16;
    float f[16];
    unpack16(vp, f);
#pragma unroll
    for (int u = 0; u < 16; ++u) Vs[r * 64 + s * 16 + u] = f[u];
  }
  __syncthreads();
  const int kk = t >> 1, half = t & 1;
  float su[32];
#pragma unroll
  for (int u = 0; u < 32; ++u) su[u] = 0.f;
  for (int j = 0; j < 64; ++j) {
    const float kv = Ks[j * 128 + kk];
    const float* vrow = &Vs[j * 64 + half * 32];
#pragma unroll
    for (int u = 0; u < 32; ++u) su[u] = fmaf(kv, vrow[u], su[u]);
  }
  float* Sp = S + (((size_t)bh * 16 + c) * 128 + kk) * 256 + vt * 64 + half * 32;
#pragma unroll
  for (int u = 0; u < 8; ++u) *(vf4*)(Sp + u * 4) = *(const vf4*)&su[u * 4];
}

// ---------------------------------------------------------------------------
// Elementwise state scan, in place: reads KV_c, writes S_c (chunk-entry state).
// s_{c+1} = e_c * (s_c + KV_c), s_0 = 0. 65536 threads, 16 serial steps.
// ---------------------------------------------------------------------------
__global__ __launch_bounds__(256)
void state_scan_k(float* __restrict__ S, const float* __restrict__ ebtot) {
  const int idx = blockIdx.x * 256 + threadIdx.x;  // 0..65535
  const int vseg = idx & 63;        // 64 vf4 = 256 cols
  const int kk = (idx >> 6) & 127;
  const int bh = idx >> 13;
  const int b = bh >> 2, h = bh & 3;
  vf4 s = vzero();
  for (int c = 0; c < 16; ++c) {
    float* p = S + (((size_t)bh * 16 + c) * 128 + kk) * 256 + vseg * 4;
    const float e = ebtot[(((size_t)b * 16 + c) << 9) + h * 128 + kk];
    vf4 kv = *(const vf4*)p;
    *(vf4*)p = s;
    s = (s + kv) * e;
  }
}

// ---------------------------------------------------------------------------
// obuf += Q~ @ S_c per (vt8, chunk, bh): [64 x 32cols]. grid (8,16,8).
// Qs padded to 132 (bank stride 4 -> 2-way aliasing = free).
// ---------------------------------------------------------------------------
__global__ __launch_bounds__(256)
void o_inter_k(const float* __restrict__ q, const float* __restrict__ S,
               float* __restrict__ o) {
  __shared__ float Qs[64 * 132];  // 33.8 KB
  __shared__ float Ss[128 * 32];  // 16 KB
  const int t = threadIdx.x;
  const int vt = blockIdx.x, c = blockIdx.y, bh = blockIdx.z;
  const int b = bh >> 2, h = bh & 3;
  const size_t rowbase = (size_t)b * 1024 + c * 64;
  {
    const int r = t >> 2, s = t & 3;
    const float* qp = q + (rowbase + r) * 512 + h * 128 + s * 32;
#pragma unroll
    for (int u = 0; u < 8; ++u)
      *(vf4*)&Qs[r * 132 + s * 32 + u * 4] = *(const vf4*)(qp + u * 4);
    const int r2 = t >> 1, s2 = t & 1;
    const float* sp = S + (((size_t)bh * 16 + c) * 128 + r2) * 256 + vt * 32 + s2 * 16;
#pragma unroll
    for (int u = 0; u < 4; ++u)
      *(vf4*)&Ss[r2 * 32 + s2 * 16 + u * 4] = *(const vf4*)(sp + u * 4);
  }
  __syncthreads();
  const int i = t >> 2, sb = t & 3;
  vf4 acc0 = vzero(), acc1 = vzero();
  for (int k4 = 0; k4 < 128; ++k4) {
    const float qs = Qs[i * 132 + k4];
    const float* sp = &Ss[k4 * 32 + sb * 8];
    acc0 += qs * *(const vf4*)sp;
    acc1 += qs * *(const vf4*)(sp + 4);
  }
  float* op = o + (rowbase + i) * 1024 + h * 256 + vt * 32 + sb * 8;
  vf4 x0 = *(const vf4*)op;
  vf4 x1 = *(const vf4*)(op + 4);
  x0 += acc0; x1 += acc1;
  *(vf4*)op = x0;
  *(vf4*)(op + 4) = x1;
}

// ---------------------------------------------------------------------------
// RMSNorm over DV=256 per (b,n,h) + silu-gate multiply, in place on o.
// ---------------------------------------------------------------------------
__global__ __launch_bounds__(256)
void norm_gate_k(float* __restrict__ o, const float* __restrict__ rmsw,
                 const unsigned short* __restrict__ sg) {
  __shared__ float red[4];
  const int grp = blockIdx.x;          // 0..8191
  const int row = grp >> 2, h = grp & 3;
  const int t = threadIdx.x;
  const size_t idx = (size_t)row * 1024 + h * 256 + t;
  const float val = o[idx];
  float ss = val * val;
#pragma unroll
  for (int m = 1; m < 64; m <<= 1) ss += __shfl_xor(ss, m, 64);
  if ((t & 63) == 0) red[t >> 6] = ss;
  __syncthreads();
  const float tot = red[0] + red[1] + red[2] + red[3];
  const float scale = rsqrtf(tot * (1.f / 256.f) + 1e-5f);
  o[idx] = val * scale * rmsw[t] * bf2f((unsigned int)sg[idx]);
}

// ---------------------------------------------------------------------------
extern "C" void kernel_launch(void* const* d_in, const int* in_sizes, int n_in,
                              void* d_out, int out_size, void* d_ws, size_t ws_size,
                              hipStream_t stream) {
  const float* x    = (const float*)d_in[0];
  const float* Wq   = (const float*)d_in[1];
  const float* Wk   = (const float*)d_in[2];
  const float* Wv   = (const float*)d_in[3];
  const float* Wg   = (const float*)d_in[4];
  const float* Wgk1 = (const float*)d_in[5];
  const float* Wgk2 = (const float*)d_in[6];
  const float* bgk2 = (const float*)d_in[7];
  const float* Wout = (const float*)d_in[8];
  const float* rmsw = (const float*)d_in[9];

  // Workspace (~40.2 MB)
  float*          qbuf  = (float*)d_ws;                       // 1,048,576 f32
  float*          kbuf  = qbuf + 1048576;                     // 1,048,576 f32
  unsigned short* vbuf  = (unsigned short*)(kbuf + 1048576);  // 2,097,152 bf16
  unsigned short* sgbuf = vbuf + 2097152;                     // 2,097,152 bf16
  float*          obuf  = (float*)(sgbuf + 2097152);          // 2,097,152 f32
  float*          Sbuf  = obuf + 2097152;                     // 4,194,304 f32
  float*          Abuf  = Sbuf;   // alias: lifetime ends before kv_k writes S
  float*          xlbuf = Sbuf + 4194304;                     //    32,768 f32
  float*          ebbuf = xlbuf + 32768;                      //    16,384 f32

  proj_k<<<dim3(24, 16), 256, 0, stream>>>(x, Wq, Wk, Wv, Wg, qbuf, kbuf, vbuf, sgbuf);
  lowrank_k<<<2048, 64, 0, stream>>>(x, Wgk1, xlbuf);
  cumsum_gate_k<<<64, 256, 0, stream>>>(xlbuf, Wgk2, bgk2, qbuf, kbuf, ebbuf);
  qk_k<<<dim3(16, 8), 256, 0, stream>>>(qbuf, kbuf, Abuf);
  av_k<<<dim3(16, 8), 256, 0, stream>>>(Abuf, vbuf, obuf);
  kv_k<<<dim3(4, 16, 8), 256, 0, stream>>>(kbuf, vbuf, Sbuf);
  state_scan_k<<<256, 256, 0, stream>>>(Sbuf, ebbuf);
  o_inter_k<<<dim3(8, 16, 8), 256, 0, stream>>>(qbuf, Sbuf, obuf);
  norm_gate_k<<<8192, 256, 0, stream>>>(obuf, rmsw, sgbuf);
  out_k<<<dim3(8, 16), 256, 0, stream>>>(obuf, Wout, (float*)d_out);
}

// Round 5
// 288.026 us; speedup vs baseline: 2.8593x; 1.8646x over previous
//
#include <hip/hip_runtime.h>
#include <math.h>

// GLA: B=2, N=1024, D=1024, H=4, KD=512, VD=1024, DK=128, DV=256, LR=16
// M = B*N = 2048 rows. Inputs/outputs fp32.
// Round 5: big GEMMs (proj, out) moved to bf16 MFMA (16x16x32), weights
// transposed+converted to bf16 [N][K] once per call. Chunk state S stored
// bf16; xb / A / obuf_b alias the S region across disjoint lifetimes.
// Workspace: 41 MB.

typedef __attribute__((ext_vector_type(4))) float vf4;
typedef __attribute__((ext_vector_type(4))) unsigned int vu4;
typedef __attribute__((ext_vector_type(8))) short short8;

#define DEVI static __device__ __forceinline__
DEVI vf4 vzero() { vf4 x = {0.f, 0.f, 0.f, 0.f}; return x; }

DEVI float bf2f(unsigned int u) {
  union { unsigned int i; float f; } c; c.i = u << 16; return c.f;
}
DEVI unsigned short f2bf(float f) {
  union { float f; unsigned int i; } c; c.f = f;
  unsigned int i = c.i;
  return (unsigned short)((i + 0x7fffu + ((i >> 16) & 1u)) >> 16);
}
DEVI void unpack8(vu4 r, float* f) {
  f[0] = bf2f(r.x & 0xffffu); f[1] = bf2f(r.x >> 16);
  f[2] = bf2f(r.y & 0xffffu); f[3] = bf2f(r.y >> 16);
  f[4] = bf2f(r.z & 0xffffu); f[5] = bf2f(r.z >> 16);
  f[6] = bf2f(r.w & 0xffffu); f[7] = bf2f(r.w >> 16);
}
DEVI void unpack16(const unsigned short* p, float* f) {
  unpack8(*(const vu4*)p, f);
  unpack8(*(const vu4*)(p + 8), f + 8);
}
DEVI vu4 pack8(const float* f) {
  vu4 o;
  o.x = (unsigned int)f2bf(f[0]) | ((unsigned int)f2bf(f[1]) << 16);
  o.y = (unsigned int)f2bf(f[2]) | ((unsigned int)f2bf(f[3]) << 16);
  o.z = (unsigned int)f2bf(f[4]) | ((unsigned int)f2bf(f[5]) << 16);
  o.w = (unsigned int)f2bf(f[6]) | ((unsigned int)f2bf(f[7]) << 16);
  return o;
}

// ---------------------------------------------------------------------------
// Weight transpose+convert: W[1024][N] fp32 -> WT[N][1024] bf16. 64x64 tiles.
// grid (64 col-tiles over 5 weights, 16 k-tiles).
// ---------------------------------------------------------------------------
__global__ __launch_bounds__(256)
void wtconv_k(const float* __restrict__ Wq, const float* __restrict__ Wk,
              const float* __restrict__ Wv, const float* __restrict__ Wg,
              const float* __restrict__ Wo,
              unsigned short* __restrict__ wqT, unsigned short* __restrict__ wkT,
              unsigned short* __restrict__ wvT, unsigned short* __restrict__ wgT,
              unsigned short* __restrict__ woT) {
  __shared__ float T[64][65];
  const int ct = blockIdx.x, kt = blockIdx.y;
  const float* W; unsigned short* O; int N; int cb;
  if (ct < 8)       { W = Wq; O = wqT; N = 512;  cb = ct; }
  else if (ct < 16) { W = Wk; O = wkT; N = 512;  cb = ct - 8; }
  else if (ct < 32) { W = Wv; O = wvT; N = 1024; cb = ct - 16; }
  else if (ct < 48) { W = Wg; O = wgT; N = 1024; cb = ct - 32; }
  else              { W = Wo; O = woT; N = 1024; cb = ct - 48; }
  const int t = threadIdx.x;
  const int r = t >> 2, s = t & 3;
  const float* src = W + (size_t)(kt * 64 + r) * N + cb * 64 + s * 16;
#pragma unroll
  for (int u = 0; u < 4; ++u) {
    vf4 v4 = *(const vf4*)(src + u * 4);
    T[r][s * 16 + u * 4 + 0] = v4.x;
    T[r][s * 16 + u * 4 + 1] = v4.y;
    T[r][s * 16 + u * 4 + 2] = v4.z;
    T[r][s * 16 + u * 4 + 3] = v4.w;
  }
  __syncthreads();
  unsigned int pk[8];
#pragma unroll
  for (int u = 0; u < 8; ++u) {
    unsigned int lo = f2bf(T[s * 16 + 2 * u][r]);
    unsigned int hi = f2bf(T[s * 16 + 2 * u + 1][r]);
    pk[u] = lo | (hi << 16);
  }
  unsigned short* dst = O + (size_t)(cb * 64 + r) * 1024 + kt * 64 + s * 16;
  *(vu4*)dst = *(vu4*)&pk[0];
  *(vu4*)(dst + 8) = *(vu4*)&pk[4];
}

// ---------------------------------------------------------------------------
// x [2048*1024] fp32 -> bf16. 1024 blocks x 256 threads x 8 elems.
// ---------------------------------------------------------------------------
__global__ __launch_bounds__(256)
void xconv_k(const float* __restrict__ X, unsigned short* __restrict__ xb) {
  const size_t idx = (size_t)blockIdx.x * 256 + threadIdx.x;
  const float* p = X + idx * 8;
  float f[8];
  *(vf4*)&f[0] = *(const vf4*)p;
  *(vf4*)&f[4] = *(const vf4*)(p + 4);
  *(vu4*)(xb + idx * 8) = pack8(f);
}

// ---------------------------------------------------------------------------
// MFMA projection GEMM: xb[2048,1024]bf16 @ WT -> q,k fp32; v,sg(silu) bf16.
// 128x128 tile, BK=64, 4 waves x (4x4 16x16x32 tiles). grid (24,16).
// LDS rows padded to 72 elems (bank-uniform b128).
// ---------------------------------------------------------------------------
__global__ __launch_bounds__(256)
void proj_mfma_k(const unsigned short* __restrict__ xb,
                 const unsigned short* __restrict__ wqT, const unsigned short* __restrict__ wkT,
                 const unsigned short* __restrict__ wvT, const unsigned short* __restrict__ wgT,
                 float* __restrict__ qb, float* __restrict__ kb,
                 unsigned short* __restrict__ vb, unsigned short* __restrict__ sgb) {
  __shared__ __align__(16) unsigned short As[128 * 72];
  __shared__ __align__(16) unsigned short Bs[128 * 72];
  const int t = threadIdx.x;
  const int m0 = blockIdx.y << 7;
  const int nt = blockIdx.x;
  const unsigned short* WT; int n0; int kind;
  if (nt < 4)       { WT = wqT; n0 = nt * 128;        kind = 0; }
  else if (nt < 8)  { WT = wkT; n0 = (nt - 4) * 128;  kind = 1; }
  else if (nt < 16) { WT = wvT; n0 = (nt - 8) * 128;  kind = 2; }
  else              { WT = wgT; n0 = (nt - 16) * 128; kind = 3; }

  const int w = t >> 6, lane = t & 63;
  const int wm = (w >> 1) * 64, wn = (w & 1) * 64;
  const int q = lane >> 4, m = lane & 15;

  vf4 acc[4][4];
#pragma unroll
  for (int i = 0; i < 4; ++i)
#pragma unroll
    for (int j = 0; j < 4; ++j) acc[i][j] = vzero();

  for (int k0 = 0; k0 < 1024; k0 += 64) {
    __syncthreads();
#pragma unroll
    for (int u2 = 0; u2 < 4; ++u2) {
      const int id = t + (u2 << 8);
      const int row = id >> 3, kg = id & 7;
      vu4 ra = *(const vu4*)(xb + (size_t)(m0 + row) * 1024 + k0 + kg * 8);
      *(vu4*)&As[row * 72 + kg * 8] = ra;
      vu4 rb = *(const vu4*)(WT + (size_t)(n0 + row) * 1024 + k0 + kg * 8);
      *(vu4*)&Bs[row * 72 + kg * 8] = rb;
    }
    __syncthreads();
#pragma unroll
    for (int ks = 0; ks < 2; ++ks) {
      short8 af[4], bf[4];
#pragma unroll
      for (int i = 0; i < 4; ++i) {
        af[i] = *(const short8*)&As[(wm + i * 16 + m) * 72 + ks * 32 + q * 8];
        bf[i] = *(const short8*)&Bs[(wn + i * 16 + m) * 72 + ks * 32 + q * 8];
      }
#pragma unroll
      for (int i = 0; i < 4; ++i)
#pragma unroll
        for (int j = 0; j < 4; ++j)
          acc[i][j] = __builtin_amdgcn_mfma_f32_16x16x32_bf16(af[i], bf[j], acc[i][j], 0, 0, 0);
    }
  }
  // epilogue: C[row=q*4+reg][col=m] per 16x16 tile
#pragma unroll
  for (int i = 0; i < 4; ++i) {
#pragma unroll
    for (int j = 0; j < 4; ++j) {
#pragma unroll
      for (int r = 0; r < 4; ++r) {
        const int grow = m0 + wm + i * 16 + q * 4 + r;
        const int gcol = n0 + wn + j * 16 + m;
        float val = acc[i][j][r];
        if (kind == 0)      qb[(size_t)grow * 512 + gcol] = val;
        else if (kind == 1) kb[(size_t)grow * 512 + gcol] = val;
        else if (kind == 2) vb[(size_t)grow * 1024 + gcol] = f2bf(val);
        else {
          val = val / (1.f + expf(-val));
          sgb[(size_t)grow * 1024 + gcol] = f2bf(val);
        }
      }
    }
  }
}

// ---------------------------------------------------------------------------
// MFMA output GEMM: obuf_b[2048,1024]bf16 @ woT -> d_out fp32. grid (8,16).
// ---------------------------------------------------------------------------
__global__ __launch_bounds__(256)
void out_mfma_k(const unsigned short* __restrict__ Ab,
                const unsigned short* __restrict__ woT, float* __restrict__ Y) {
  __shared__ __align__(16) unsigned short As[128 * 72];
  __shared__ __align__(16) unsigned short Bs[128 * 72];
  const int t = threadIdx.x;
  const int m0 = blockIdx.y << 7;
  const int n0 = blockIdx.x << 7;
  const int w = t >> 6, lane = t & 63;
  const int wm = (w >> 1) * 64, wn = (w & 1) * 64;
  const int q = lane >> 4, m = lane & 15;

  vf4 acc[4][4];
#pragma unroll
  for (int i = 0; i < 4; ++i)
#pragma unroll
    for (int j = 0; j < 4; ++j) acc[i][j] = vzero();

  for (int k0 = 0; k0 < 1024; k0 += 64) {
    __syncthreads();
#pragma unroll
    for (int u2 = 0; u2 < 4; ++u2) {
      const int id = t + (u2 << 8);
      const int row = id >> 3, kg = id & 7;
      vu4 ra = *(const vu4*)(Ab + (size_t)(m0 + row) * 1024 + k0 + kg * 8);
      *(vu4*)&As[row * 72 + kg * 8] = ra;
      vu4 rb = *(const vu4*)(woT + (size_t)(n0 + row) * 1024 + k0 + kg * 8);
      *(vu4*)&Bs[row * 72 + kg * 8] = rb;
    }
    __syncthreads();
#pragma unroll
    for (int ks = 0; ks < 2; ++ks) {
      short8 af[4], bf[4];
#pragma unroll
      for (int i = 0; i < 4; ++i) {
        af[i] = *(const short8*)&As[(wm + i * 16 + m) * 72 + ks * 32 + q * 8];
        bf[i] = *(const short8*)&Bs[(wn + i * 16 + m) * 72 + ks * 32 + q * 8];
      }
#pragma unroll
      for (int i = 0; i < 4; ++i)
#pragma unroll
        for (int j = 0; j < 4; ++j)
          acc[i][j] = __builtin_amdgcn_mfma_f32_16x16x32_bf16(af[i], bf[j], acc[i][j], 0, 0, 0);
    }
  }
#pragma unroll
  for (int i = 0; i < 4; ++i)
#pragma unroll
    for (int j = 0; j < 4; ++j)
#pragma unroll
      for (int r = 0; r < 4; ++r) {
        const int grow = m0 + wm + i * 16 + q * 4 + r;
        const int gcol = n0 + wn + j * 16 + m;
        Y[(size_t)grow * 1024 + gcol] = acc[i][j][r];
      }
}

// ---------------------------------------------------------------------------
// xl = x @ Wgk1 [2048,16] fp32. One wave per row.
// ---------------------------------------------------------------------------
__global__ __launch_bounds__(64)
void lowrank_k(const float* __restrict__ X, const float* __restrict__ W1,
               float* __restrict__ xl) {
  const int row = blockIdx.x;
  const int t = threadIdx.x;
  float acc[16];
#pragma unroll
  for (int c2 = 0; c2 < 16; ++c2) acc[c2] = 0.f;
  const float* xp = X + (size_t)row * 1024 + t * 16;
  float xv[16];
#pragma unroll
  for (int u = 0; u < 4; ++u)
    *(vf4*)&xv[u * 4] = *(const vf4*)(xp + u * 4);
#pragma unroll
  for (int j = 0; j < 16; ++j) {
    const float* wp = W1 + (size_t)(t * 16 + j) * 16;
    float wv[16];
#pragma unroll
    for (int u = 0; u < 4; ++u)
      *(vf4*)&wv[u * 4] = *(const vf4*)(wp + u * 4);
#pragma unroll
    for (int c2 = 0; c2 < 16; ++c2) acc[c2] = fmaf(xv[j], wv[c2], acc[c2]);
  }
#pragma unroll
  for (int mm = 1; mm < 64; mm <<= 1) {
#pragma unroll
    for (int c2 = 0; c2 < 16; ++c2) acc[c2] += __shfl_xor(acc[c2], mm, 64);
  }
  if (t == 0) {
#pragma unroll
    for (int c2 = 0; c2 < 16; ++c2) xl[(size_t)row * 16 + c2] = acc[c2];
  }
}

// ---------------------------------------------------------------------------
// Fused gate + in-chunk cumsum + q/k scaling (fp32 q,k in place).
// ---------------------------------------------------------------------------
__global__ __launch_bounds__(256)
void cumsum_gate_k(const float* __restrict__ xl, const float* __restrict__ W2,
                   const float* __restrict__ bias,
                   float* __restrict__ q, float* __restrict__ k,
                   float* __restrict__ ebtot) {
  const int idx = blockIdx.x * 256 + threadIdx.x;  // 0..16383
  const int kcol = idx & 511;
  const int c = (idx >> 9) & 15;
  const int bb = idx >> 13;
  float w2[16];
#pragma unroll
  for (int r = 0; r < 16; ++r) w2[r] = W2[r * 512 + kcol];
  const float bz = bias[kcol];

  float run = 0.f;
  for (int i = 0; i < 64; ++i) {
    const size_t row = (size_t)bb * 1024 + c * 64 + i;
    const float* xp = xl + row * 16;
    float z = bz;
#pragma unroll
    for (int r = 0; r < 16; ++r) z = fmaf(xp[r], w2[r], z);
    float ls = fminf(z, 0.f) - log1pf(expf(-fabsf(z)));
    run += fmaxf(ls * (1.f / 16.f), -3.f);
    const size_t a = row * 512 + kcol;
    q[a] *= expf(run);
    k[a] *= expf(fminf(-run, 80.f));
  }
  ebtot[(((size_t)bb * 16 + c) << 9) + kcol] = expf(run);
}

// ---------------------------------------------------------------------------
// A = tril(Q~ K~^T) per (chunk, bh): [64x64], K=128. grid (16,8). fp32.
// ---------------------------------------------------------------------------
__global__ __launch_bounds__(256)
void qk_k(const float* __restrict__ q, const float* __restrict__ kb,
          float* __restrict__ A) {
  __shared__ float Ks[64 * 128];
  const int t = threadIdx.x;
  const int c = blockIdx.x, bh = blockIdx.y;
  const int b = bh >> 2, h = bh & 3;
  const size_t rowbase = (size_t)b * 1024 + c * 64;
  {
    const int r = t >> 2, s = t & 3;
    const float* kp = kb + (rowbase + r) * 512 + h * 128 + s * 32;
#pragma unroll
    for (int u = 0; u < 8; ++u)
      *(vf4*)&Ks[r * 128 + s * 32 + u * 4] = *(const vf4*)(kp + u * 4);
  }
  __syncthreads();
  const int i = t >> 2, jb = t & 3;
  float acc[16];
#pragma unroll
  for (int u = 0; u < 16; ++u) acc[u] = 0.f;
  const float* qp = q + (rowbase + i) * 512 + h * 128;
  for (int kk = 0; kk < 128; kk += 4) {
    vf4 qv = *(const vf4*)(qp + kk);
#pragma unroll
    for (int u = 0; u < 16; ++u) {
      const float* kr = &Ks[(jb + 4 * u) * 128 + kk];
      acc[u] += qv.x * kr[0] + qv.y * kr[1] + qv.z * kr[2] + qv.w * kr[3];
    }
  }
  float* Ap = A + (((size_t)bh * 16 + c) * 64 + i) * 64;
#pragma unroll
  for (int u = 0; u < 16; ++u) {
    const int j = jb + 4 * u;
    Ap[j] = (j <= i) ? acc[u] : 0.f;
  }
}

// ---------------------------------------------------------------------------
// o_intra = A @ V : [64x256] per (chunk, bh). Writes obuf fp32. grid (16,8).
// ---------------------------------------------------------------------------
__global__ __launch_bounds__(256)
void av_k(const float* __restrict__ A, const unsigned short* __restrict__ v,
          float* __restrict__ o) {
  __shared__ float As[64 * 64];
  __shared__ float Vs[64 * 64];
  const int t = threadIdx.x;
  const int c = blockIdx.x, bh = blockIdx.y;
  const int b = bh >> 2, h = bh & 3;
  const size_t rowbase = (size_t)b * 1024 + c * 64;
  {
    const int r = t >> 2, s = t & 3;
    const float* Ap = A + (((size_t)bh * 16 + c) * 64 + r) * 64 + s * 16;
#pragma unroll
    for (int u = 0; u < 4; ++u)
      *(vf4*)&As[r * 64 + s * 16 + u * 4] = *(const vf4*)(Ap + u * 4);
  }
  const int i = t >> 2, sb = t & 3;
  for (int vt = 0; vt < 4; ++vt) {
    __syncthreads();
    {
      const int r = t >> 2, s = t & 3;
      const unsigned short* vp = v + (rowbase + r) * 1024 + h * 256 + vt * 64 + s * 16;
      float f[16];
      unpack16(vp, f);
#pragma unroll
      for (int u = 0; u < 16; ++u) Vs[r * 64 + s * 16 + u] = f[u];
    }
    __syncthreads();
    vf4 acc[4];
#pragma unroll
    for (int u = 0; u < 4; ++u) acc[u] = vzero();
    for (int jj = 0; jj < 64; ++jj) {
      const float a = As[i * 64 + jj];
#pragma unroll
      for (int u = 0; u < 4; ++u)
        acc[u] += a * *(const vf4*)&Vs[jj * 64 + sb * 16 + u * 4];
    }
    float* op = o + (rowbase + i) * 1024 + h * 256 + vt * 64 + sb * 16;
#pragma unroll
    for (int u = 0; u < 4; ++u) *(vf4*)(op + u * 4) = acc[u];
  }
}

// ---------------------------------------------------------------------------
// KV_c = K~^T V per (vt, chunk, bh): [128 x 64cols] -> bf16 S. grid (4,16,8).
// ---------------------------------------------------------------------------
__global__ __launch_bounds__(256)
void kv_k(const float* __restrict__ kb, const unsigned short* __restrict__ v,
          unsigned short* __restrict__ S) {
  __shared__ float Ks[64 * 128];
  __shared__ float Vs[64 * 64];
  const int t = threadIdx.x;
  const int vt = blockIdx.x, c = blockIdx.y, bh = blockIdx.z;
  const int b = bh >> 2, h = bh & 3;
  const size_t rowbase = (size_t)b * 1024 + c * 64;
  {
    const int r = t >> 2, s = t & 3;
    const float* kp = kb + (rowbase + r) * 512 + h * 128 + s * 32;
#pragma unroll
    for (int u = 0; u < 8; ++u)
      *(vf4*)&Ks[r * 128 + s * 32 + u * 4] = *(const vf4*)(kp + u * 4);
    const unsigned short* vp = v + (rowbase + r) * 1024 + h * 256 + vt * 64 + s * 16;
    float f[16];
    unpack16(vp, f);
#pragma unroll
    for (int u = 0; u < 16; ++u) Vs[r * 64 + s * 16 + u] = f[u];
  }
  __syncthreads();
  const int kk = t >> 1, half = t & 1;
  float su[32];
#pragma unroll
  for (int u = 0; u < 32; ++u) su[u] = 0.f;
  for (int j = 0; j < 64; ++j) {
    const float kv = Ks[j * 128 + kk];
    const float* vrow = &Vs[j * 64 + half * 32];
#pragma unroll
    for (int u = 0; u < 32; ++u) su[u] = fmaf(kv, vrow[u], su[u]);
  }
  unsigned short* Sp = S + (((size_t)bh * 16 + c) * 128 + kk) * 256 + vt * 64 + half * 32;
#pragma unroll
  for (int u = 0; u < 4; ++u)
    *(vu4*)(Sp + u * 8) = pack8(&su[u * 8]);
}

// ---------------------------------------------------------------------------
// Elementwise state scan in place on bf16 S; fp32 carry in registers.
// s_{c+1} = e_c * (s_c + KV_c). 32768 threads, 16 serial steps.
// ---------------------------------------------------------------------------
__global__ __launch_bounds__(256)
void state_scan_k(unsigned short* __restrict__ S, const float* __restrict__ ebtot) {
  const int idx = blockIdx.x * 256 + threadIdx.x;  // 0..32767
  const int vg = idx & 31;
  const int kk = (idx >> 5) & 127;
  const int bh = idx >> 12;
  const int b = bh >> 2, h = bh & 3;
  float s[8];
#pragma unroll
  for (int u = 0; u < 8; ++u) s[u] = 0.f;
  for (int c = 0; c < 16; ++c) {
    unsigned short* p = S + (((size_t)bh * 16 + c) * 128 + kk) * 256 + vg * 8;
    const float e = ebtot[(((size_t)b * 16 + c) << 9) + h * 128 + kk];
    float kv[8];
    unpack8(*(const vu4*)p, kv);
    *(vu4*)p = pack8(s);
#pragma unroll
    for (int u = 0; u < 8; ++u) s[u] = (s[u] + kv[u]) * e;
  }
}

// ---------------------------------------------------------------------------
// obuf += Q~ @ S_c per (vt8, chunk, bh): [64 x 32cols]. grid (8,16,8).
// ---------------------------------------------------------------------------
__global__ __launch_bounds__(256)
void o_inter_k(const float* __restrict__ q, const unsigned short* __restrict__ S,
               float* __restrict__ o) {
  __shared__ float Qs[64 * 132];
  __shared__ float Ss[128 * 32];
  const int t = threadIdx.x;
  const int vt = blockIdx.x, c = blockIdx.y, bh = blockIdx.z;
  const int b = bh >> 2, h = bh & 3;
  const size_t rowbase = (size_t)b * 1024 + c * 64;
  {
    const int r = t >> 2, s = t & 3;
    const float* qp = q + (rowbase + r) * 512 + h * 128 + s * 32;
#pragma unroll
    for (int u = 0; u < 8; ++u)
      *(vf4*)&Qs[r * 132 + s * 32 + u * 4] = *(const vf4*)(qp + u * 4);
    const int r2 = t >> 1, s2 = t & 1;
    const unsigned short* sp = S + (((size_t)bh * 16 + c) * 128 + r2) * 256 + vt * 32 + s2 * 16;
    float f[16];
    unpack16(sp, f);
#pragma unroll
    for (int u = 0; u < 16; ++u) Ss[r2 * 32 + s2 * 16 + u] = f[u];
  }
  __syncthreads();
  const int i = t >> 2, sb = t & 3;
  vf4 acc0 = vzero(), acc1 = vzero();
  for (int k4 = 0; k4 < 128; ++k4) {
    const float qs = Qs[i * 132 + k4];
    const float* sp = &Ss[k4 * 32 + sb * 8];
    acc0 += qs * *(const vf4*)sp;
    acc1 += qs * *(const vf4*)(sp + 4);
  }
  float* op = o + (rowbase + i) * 1024 + h * 256 + vt * 32 + sb * 8;
  vf4 x0 = *(const vf4*)op;
  vf4 x1 = *(const vf4*)(op + 4);
  x0 += acc0; x1 += acc1;
  *(vf4*)op = x0;
  *(vf4*)(op + 4) = x1;
}

// ---------------------------------------------------------------------------
// RMSNorm over DV=256 + silu-gate; reads obuf fp32, writes obuf_b bf16.
// ---------------------------------------------------------------------------
__global__ __launch_bounds__(256)
void norm_gate_k(const float* __restrict__ o, const float* __restrict__ rmsw,
                 const unsigned short* __restrict__ sg,
                 unsigned short* __restrict__ ob) {
  __shared__ float red[4];
  const int grp = blockIdx.x;          // 0..8191
  const int row = grp >> 2, h = grp & 3;
  const int t = threadIdx.x;
  const size_t idx = (size_t)row * 1024 + h * 256 + t;
  const float val = o[idx];
  float ss = val * val;
#pragma unroll
  for (int mm = 1; mm < 64; mm <<= 1) ss += __shfl_xor(ss, mm, 64);
  if ((t & 63) == 0) red[t >> 6] = ss;
  __syncthreads();
  const float tot = red[0] + red[1] + red[2] + red[3];
  const float scale = rsqrtf(tot * (1.f / 256.f) + 1e-5f);
  ob[idx] = f2bf(val * scale * rmsw[t] * bf2f((unsigned int)sg[idx]));
}

// ---------------------------------------------------------------------------
extern "C" void kernel_launch(void* const* d_in, const int* in_sizes, int n_in,
                              void* d_out, int out_size, void* d_ws, size_t ws_size,
                              hipStream_t stream) {
  const float* x    = (const float*)d_in[0];
  const float* Wq   = (const float*)d_in[1];
  const float* Wk   = (const float*)d_in[2];
  const float* Wv   = (const float*)d_in[3];
  const float* Wg   = (const float*)d_in[4];
  const float* Wgk1 = (const float*)d_in[5];
  const float* Wgk2 = (const float*)d_in[6];
  const float* bgk2 = (const float*)d_in[7];
  const float* Wout = (const float*)d_in[8];
  const float* rmsw = (const float*)d_in[9];

  // Workspace (41 MB, byte offsets)
  const size_t MB = 1u << 20;
  char* w = (char*)d_ws;
  float*          qbuf   = (float*)(w);                    // [0,4) MB
  float*          kbuf   = (float*)(w + 4 * MB);           // [4,8)
  unsigned short* vbuf   = (unsigned short*)(w + 8 * MB);  // [8,12)
  unsigned short* sgbuf  = (unsigned short*)(w + 12 * MB); // [12,16)
  float*          obuf   = (float*)(w + 16 * MB);          // [16,24)
  char*           sreg   = w + 24 * MB;                    // [24,32) multi-phase
  unsigned short* xb     = (unsigned short*)sreg;          //   phase 1: 4 MB
  float*          Abuf   = (float*)(sreg + 4 * MB);        //   phase 2: 2 MB
  unsigned short* Sbuf   = (unsigned short*)sreg;          //   phase 3: 8 MB
  unsigned short* obuf_b = (unsigned short*)sreg;          //   phase 4: 4 MB
  float*          xlbuf  = (float*)(w + 32 * MB);          // 128 KB
  float*          ebbuf  = (float*)(w + 32 * MB + 131072); // 64 KB
  unsigned short* wqT    = (unsigned short*)(w + 33 * MB); // 1 MB
  unsigned short* wkT    = (unsigned short*)(w + 34 * MB); // 1 MB
  unsigned short* wvT    = (unsigned short*)(w + 35 * MB); // 2 MB
  unsigned short* wgT    = (unsigned short*)(w + 37 * MB); // 2 MB
  unsigned short* woT    = (unsigned short*)(w + 39 * MB); // 2 MB

  wtconv_k<<<dim3(64, 16), 256, 0, stream>>>(Wq, Wk, Wv, Wg, Wout, wqT, wkT, wvT, wgT, woT);
  xconv_k<<<1024, 256, 0, stream>>>(x, xb);
  lowrank_k<<<2048, 64, 0, stream>>>(x, Wgk1, xlbuf);
  proj_mfma_k<<<dim3(24, 16), 256, 0, stream>>>(xb, wqT, wkT, wvT, wgT, qbuf, kbuf, vbuf, sgbuf);
  cumsum_gate_k<<<64, 256, 0, stream>>>(xlbuf, Wgk2, bgk2, qbuf, kbuf, ebbuf);
  qk_k<<<dim3(16, 8), 256, 0, stream>>>(qbuf, kbuf, Abuf);
  av_k<<<dim3(16, 8), 256, 0, stream>>>(Abuf, vbuf, obuf);
  kv_k<<<dim3(4, 16, 8), 256, 0, stream>>>(kbuf, vbuf, Sbuf);
  state_scan_k<<<128, 256, 0, stream>>>(Sbuf, ebbuf);
  o_inter_k<<<dim3(8, 16, 8), 256, 0, stream>>>(qbuf, Sbuf, obuf);
  norm_gate_k<<<8192, 256, 0, stream>>>(obuf, rmsw, sgbuf, obuf_b);
  out_mfma_k<<<dim3(8, 16), 256, 0, stream>>>(obuf_b, woT, (float*)d_out);
}

// Round 6
// 274.129 us; speedup vs baseline: 3.0042x; 1.0507x over previous
//
#include <hip/hip_runtime.h>
#include <math.h>

// GLA: B=2, N=1024, D=1024, H=4, KD=512, VD=1024, DK=128, DV=256, LR=16
// M = B*N = 2048 rows. Inputs/outputs fp32.
// Round 6: cumsum_gate_k (64-block, serial-64, 43 µs, 2.3% occupancy)
// replaced by gate_scan_k: one wave per (b,chunk,kcol), lane i = row i,
// __shfl_up inclusive scan; 4096 blocks. Everything else unchanged.

typedef __attribute__((ext_vector_type(4))) float vf4;
typedef __attribute__((ext_vector_type(4))) unsigned int vu4;
typedef __attribute__((ext_vector_type(8))) short short8;

#define DEVI static __device__ __forceinline__
DEVI vf4 vzero() { vf4 x = {0.f, 0.f, 0.f, 0.f}; return x; }

DEVI float bf2f(unsigned int u) {
  union { unsigned int i; float f; } c; c.i = u << 16; return c.f;
}
DEVI unsigned short f2bf(float f) {
  union { float f; unsigned int i; } c; c.f = f;
  unsigned int i = c.i;
  return (unsigned short)((i + 0x7fffu + ((i >> 16) & 1u)) >> 16);
}
DEVI void unpack8(vu4 r, float* f) {
  f[0] = bf2f(r.x & 0xffffu); f[1] = bf2f(r.x >> 16);
  f[2] = bf2f(r.y & 0xffffu); f[3] = bf2f(r.y >> 16);
  f[4] = bf2f(r.z & 0xffffu); f[5] = bf2f(r.z >> 16);
  f[6] = bf2f(r.w & 0xffffu); f[7] = bf2f(r.w >> 16);
}
DEVI void unpack16(const unsigned short* p, float* f) {
  unpack8(*(const vu4*)p, f);
  unpack8(*(const vu4*)(p + 8), f + 8);
}
DEVI vu4 pack8(const float* f) {
  vu4 o;
  o.x = (unsigned int)f2bf(f[0]) | ((unsigned int)f2bf(f[1]) << 16);
  o.y = (unsigned int)f2bf(f[2]) | ((unsigned int)f2bf(f[3]) << 16);
  o.z = (unsigned int)f2bf(f[4]) | ((unsigned int)f2bf(f[5]) << 16);
  o.w = (unsigned int)f2bf(f[6]) | ((unsigned int)f2bf(f[7]) << 16);
  return o;
}

// ---------------------------------------------------------------------------
// Weight transpose+convert: W[1024][N] fp32 -> WT[N][1024] bf16. 64x64 tiles.
// ---------------------------------------------------------------------------
__global__ __launch_bounds__(256)
void wtconv_k(const float* __restrict__ Wq, const float* __restrict__ Wk,
              const float* __restrict__ Wv, const float* __restrict__ Wg,
              const float* __restrict__ Wo,
              unsigned short* __restrict__ wqT, unsigned short* __restrict__ wkT,
              unsigned short* __restrict__ wvT, unsigned short* __restrict__ wgT,
              unsigned short* __restrict__ woT) {
  __shared__ float T[64][65];
  const int ct = blockIdx.x, kt = blockIdx.y;
  const float* W; unsigned short* O; int N; int cb;
  if (ct < 8)       { W = Wq; O = wqT; N = 512;  cb = ct; }
  else if (ct < 16) { W = Wk; O = wkT; N = 512;  cb = ct - 8; }
  else if (ct < 32) { W = Wv; O = wvT; N = 1024; cb = ct - 16; }
  else if (ct < 48) { W = Wg; O = wgT; N = 1024; cb = ct - 32; }
  else              { W = Wo; O = woT; N = 1024; cb = ct - 48; }
  const int t = threadIdx.x;
  const int r = t >> 2, s = t & 3;
  const float* src = W + (size_t)(kt * 64 + r) * N + cb * 64 + s * 16;
#pragma unroll
  for (int u = 0; u < 4; ++u) {
    vf4 v4 = *(const vf4*)(src + u * 4);
    T[r][s * 16 + u * 4 + 0] = v4.x;
    T[r][s * 16 + u * 4 + 1] = v4.y;
    T[r][s * 16 + u * 4 + 2] = v4.z;
    T[r][s * 16 + u * 4 + 3] = v4.w;
  }
  __syncthreads();
  unsigned int pk[8];
#pragma unroll
  for (int u = 0; u < 8; ++u) {
    unsigned int lo = f2bf(T[s * 16 + 2 * u][r]);
    unsigned int hi = f2bf(T[s * 16 + 2 * u + 1][r]);
    pk[u] = lo | (hi << 16);
  }
  unsigned short* dst = O + (size_t)(cb * 64 + r) * 1024 + kt * 64 + s * 16;
  *(vu4*)dst = *(vu4*)&pk[0];
  *(vu4*)(dst + 8) = *(vu4*)&pk[4];
}

// ---------------------------------------------------------------------------
// x [2048*1024] fp32 -> bf16.
// ---------------------------------------------------------------------------
__global__ __launch_bounds__(256)
void xconv_k(const float* __restrict__ X, unsigned short* __restrict__ xb) {
  const size_t idx = (size_t)blockIdx.x * 256 + threadIdx.x;
  const float* p = X + idx * 8;
  float f[8];
  *(vf4*)&f[0] = *(const vf4*)p;
  *(vf4*)&f[4] = *(const vf4*)(p + 4);
  *(vu4*)(xb + idx * 8) = pack8(f);
}

// ---------------------------------------------------------------------------
// MFMA projection GEMM: xb[2048,1024]bf16 @ WT -> q,k fp32; v,sg(silu) bf16.
// 128x128 tile, BK=64, 4 waves x (4x4 16x16x32 tiles). grid (24,16).
// ---------------------------------------------------------------------------
__global__ __launch_bounds__(256)
void proj_mfma_k(const unsigned short* __restrict__ xb,
                 const unsigned short* __restrict__ wqT, const unsigned short* __restrict__ wkT,
                 const unsigned short* __restrict__ wvT, const unsigned short* __restrict__ wgT,
                 float* __restrict__ qb, float* __restrict__ kb,
                 unsigned short* __restrict__ vb, unsigned short* __restrict__ sgb) {
  __shared__ __align__(16) unsigned short As[128 * 72];
  __shared__ __align__(16) unsigned short Bs[128 * 72];
  const int t = threadIdx.x;
  const int m0 = blockIdx.y << 7;
  const int nt = blockIdx.x;
  const unsigned short* WT; int n0; int kind;
  if (nt < 4)       { WT = wqT; n0 = nt * 128;        kind = 0; }
  else if (nt < 8)  { WT = wkT; n0 = (nt - 4) * 128;  kind = 1; }
  else if (nt < 16) { WT = wvT; n0 = (nt - 8) * 128;  kind = 2; }
  else              { WT = wgT; n0 = (nt - 16) * 128; kind = 3; }

  const int w = t >> 6, lane = t & 63;
  const int wm = (w >> 1) * 64, wn = (w & 1) * 64;
  const int q = lane >> 4, m = lane & 15;

  vf4 acc[4][4];
#pragma unroll
  for (int i = 0; i < 4; ++i)
#pragma unroll
    for (int j = 0; j < 4; ++j) acc[i][j] = vzero();

  for (int k0 = 0; k0 < 1024; k0 += 64) {
    __syncthreads();
#pragma unroll
    for (int u2 = 0; u2 < 4; ++u2) {
      const int id = t + (u2 << 8);
      const int row = id >> 3, kg = id & 7;
      vu4 ra = *(const vu4*)(xb + (size_t)(m0 + row) * 1024 + k0 + kg * 8);
      *(vu4*)&As[row * 72 + kg * 8] = ra;
      vu4 rb = *(const vu4*)(WT + (size_t)(n0 + row) * 1024 + k0 + kg * 8);
      *(vu4*)&Bs[row * 72 + kg * 8] = rb;
    }
    __syncthreads();
#pragma unroll
    for (int ks = 0; ks < 2; ++ks) {
      short8 af[4], bf[4];
#pragma unroll
      for (int i = 0; i < 4; ++i) {
        af[i] = *(const short8*)&As[(wm + i * 16 + m) * 72 + ks * 32 + q * 8];
        bf[i] = *(const short8*)&Bs[(wn + i * 16 + m) * 72 + ks * 32 + q * 8];
      }
#pragma unroll
      for (int i = 0; i < 4; ++i)
#pragma unroll
        for (int j = 0; j < 4; ++j)
          acc[i][j] = __builtin_amdgcn_mfma_f32_16x16x32_bf16(af[i], bf[j], acc[i][j], 0, 0, 0);
    }
  }
#pragma unroll
  for (int i = 0; i < 4; ++i) {
#pragma unroll
    for (int j = 0; j < 4; ++j) {
#pragma unroll
      for (int r = 0; r < 4; ++r) {
        const int grow = m0 + wm + i * 16 + q * 4 + r;
        const int gcol = n0 + wn + j * 16 + m;
        float val = acc[i][j][r];
        if (kind == 0)      qb[(size_t)grow * 512 + gcol] = val;
        else if (kind == 1) kb[(size_t)grow * 512 + gcol] = val;
        else if (kind == 2) vb[(size_t)grow * 1024 + gcol] = f2bf(val);
        else {
          val = val / (1.f + expf(-val));
          sgb[(size_t)grow * 1024 + gcol] = f2bf(val);
        }
      }
    }
  }
}

// ---------------------------------------------------------------------------
// MFMA output GEMM: obuf_b[2048,1024]bf16 @ woT -> d_out fp32. grid (8,16).
// ---------------------------------------------------------------------------
__global__ __launch_bounds__(256)
void out_mfma_k(const unsigned short* __restrict__ Ab,
                const unsigned short* __restrict__ woT, float* __restrict__ Y) {
  __shared__ __align__(16) unsigned short As[128 * 72];
  __shared__ __align__(16) unsigned short Bs[128 * 72];
  const int t = threadIdx.x;
  const int m0 = blockIdx.y << 7;
  const int n0 = blockIdx.x << 7;
  const int w = t >> 6, lane = t & 63;
  const int wm = (w >> 1) * 64, wn = (w & 1) * 64;
  const int q = lane >> 4, m = lane & 15;

  vf4 acc[4][4];
#pragma unroll
  for (int i = 0; i < 4; ++i)
#pragma unroll
    for (int j = 0; j < 4; ++j) acc[i][j] = vzero();

  for (int k0 = 0; k0 < 1024; k0 += 64) {
    __syncthreads();
#pragma unroll
    for (int u2 = 0; u2 < 4; ++u2) {
      const int id = t + (u2 << 8);
      const int row = id >> 3, kg = id & 7;
      vu4 ra = *(const vu4*)(Ab + (size_t)(m0 + row) * 1024 + k0 + kg * 8);
      *(vu4*)&As[row * 72 + kg * 8] = ra;
      vu4 rb = *(const vu4*)(woT + (size_t)(n0 + row) * 1024 + k0 + kg * 8);
      *(vu4*)&Bs[row * 72 + kg * 8] = rb;
    }
    __syncthreads();
#pragma unroll
    for (int ks = 0; ks < 2; ++ks) {
      short8 af[4], bf[4];
#pragma unroll
      for (int i = 0; i < 4; ++i) {
        af[i] = *(const short8*)&As[(wm + i * 16 + m) * 72 + ks * 32 + q * 8];
        bf[i] = *(const short8*)&Bs[(wn + i * 16 + m) * 72 + ks * 32 + q * 8];
      }
#pragma unroll
      for (int i = 0; i < 4; ++i)
#pragma unroll
        for (int j = 0; j < 4; ++j)
          acc[i][j] = __builtin_amdgcn_mfma_f32_16x16x32_bf16(af[i], bf[j], acc[i][j], 0, 0, 0);
    }
  }
#pragma unroll
  for (int i = 0; i < 4; ++i)
#pragma unroll
    for (int j = 0; j < 4; ++j)
#pragma unroll
      for (int r = 0; r < 4; ++r) {
        const int grow = m0 + wm + i * 16 + q * 4 + r;
        const int gcol = n0 + wn + j * 16 + m;
        Y[(size_t)grow * 1024 + gcol] = acc[i][j][r];
      }
}

// ---------------------------------------------------------------------------
// xl = x @ Wgk1 [2048,16] fp32. One wave per row.
// ---------------------------------------------------------------------------
__global__ __launch_bounds__(64)
void lowrank_k(const float* __restrict__ X, const float* __restrict__ W1,
               float* __restrict__ xl) {
  const int row = blockIdx.x;
  const int t = threadIdx.x;
  float acc[16];
#pragma unroll
  for (int c2 = 0; c2 < 16; ++c2) acc[c2] = 0.f;
  const float* xp = X + (size_t)row * 1024 + t * 16;
  float xv[16];
#pragma unroll
  for (int u = 0; u < 4; ++u)
    *(vf4*)&xv[u * 4] = *(const vf4*)(xp + u * 4);
#pragma unroll
  for (int j = 0; j < 16; ++j) {
    const float* wp = W1 + (size_t)(t * 16 + j) * 16;
    float wv[16];
#pragma unroll
    for (int u = 0; u < 4; ++u)
      *(vf4*)&wv[u * 4] = *(const vf4*)(wp + u * 4);
#pragma unroll
    for (int c2 = 0; c2 < 16; ++c2) acc[c2] = fmaf(xv[j], wv[c2], acc[c2]);
  }
#pragma unroll
  for (int mm = 1; mm < 64; mm <<= 1) {
#pragma unroll
    for (int c2 = 0; c2 < 16; ++c2) acc[c2] += __shfl_xor(acc[c2], mm, 64);
  }
  if (t == 0) {
#pragma unroll
    for (int c2 = 0; c2 < 16; ++c2) xl[(size_t)row * 16 + c2] = acc[c2];
  }
}

// ---------------------------------------------------------------------------
// Fused gate + wave-parallel scan + q/k scaling. One WAVE per (b,chunk,kcol);
// lane i handles row i of the chunk. Inclusive scan via __shfl_up (6 steps).
// grid 4096 x 256 (4 waves/block, consecutive kcols share (b,c)).
// ---------------------------------------------------------------------------
__global__ __launch_bounds__(256)
void gate_scan_k(const float* __restrict__ xl, const float* __restrict__ W2,
                 const float* __restrict__ bias,
                 float* __restrict__ q, float* __restrict__ k,
                 float* __restrict__ ebtot) {
  const int t = threadIdx.x;
  const int w = t >> 6, lane = t & 63;
  const int wid = blockIdx.x * 4 + w;     // 0..16383
  const int kcol = wid & 511;
  const int c = (wid >> 9) & 15;
  const int b = wid >> 13;
  const size_t rowbase = (size_t)b * 1024 + c * 64;

  // lane i: z = xl[row_i] . W2[:,kcol] + bias[kcol]
  const float* xp = xl + (rowbase + lane) * 16;
  float xv[16];
#pragma unroll
  for (int u = 0; u < 4; ++u)
    *(vf4*)&xv[u * 4] = *(const vf4*)(xp + u * 4);
  float z = bias[kcol];
#pragma unroll
  for (int r = 0; r < 16; ++r) z = fmaf(xv[r], W2[r * 512 + kcol], z);
  float ls = fminf(z, 0.f) - log1pf(expf(-fabsf(z)));
  float g = fmaxf(ls * (1.f / 16.f), -3.f);

  // inclusive scan over 64 lanes
#pragma unroll
  for (int d = 1; d < 64; d <<= 1) {
    float up = __shfl_up(g, d, 64);
    if (lane >= d) g += up;
  }

  const size_t a = (rowbase + lane) * 512 + kcol;
  q[a] *= expf(g);                     // g <= 0
  k[a] *= expf(fminf(-g, 80.f));       // clamped, never inf
  if (lane == 63)
    ebtot[((size_t)b * 16 + c) * 512 + kcol] = expf(g);
}

// ---------------------------------------------------------------------------
// A = tril(Q~ K~^T) per (chunk, bh): [64x64], K=128. grid (16,8). fp32.
// ---------------------------------------------------------------------------
__global__ __launch_bounds__(256)
void qk_k(const float* __restrict__ q, const float* __restrict__ kb,
          float* __restrict__ A) {
  __shared__ float Ks[64 * 128];
  const int t = threadIdx.x;
  const int c = blockIdx.x, bh = blockIdx.y;
  const int b = bh >> 2, h = bh & 3;
  const size_t rowbase = (size_t)b * 1024 + c * 64;
  {
    const int r = t >> 2, s = t & 3;
    const float* kp = kb + (rowbase + r) * 512 + h * 128 + s * 32;
#pragma unroll
    for (int u = 0; u < 8; ++u)
      *(vf4*)&Ks[r * 128 + s * 32 + u * 4] = *(const vf4*)(kp + u * 4);
  }
  __syncthreads();
  const int i = t >> 2, jb = t & 3;
  float acc[16];
#pragma unroll
  for (int u = 0; u < 16; ++u) acc[u] = 0.f;
  const float* qp = q + (rowbase + i) * 512 + h * 128;
  for (int kk = 0; kk < 128; kk += 4) {
    vf4 qv = *(const vf4*)(qp + kk);
#pragma unroll
    for (int u = 0; u < 16; ++u) {
      const float* kr = &Ks[(jb + 4 * u) * 128 + kk];
      acc[u] += qv.x * kr[0] + qv.y * kr[1] + qv.z * kr[2] + qv.w * kr[3];
    }
  }
  float* Ap = A + (((size_t)bh * 16 + c) * 64 + i) * 64;
#pragma unroll
  for (int u = 0; u < 16; ++u) {
    const int j = jb + 4 * u;
    Ap[j] = (j <= i) ? acc[u] : 0.f;
  }
}

// ---------------------------------------------------------------------------
// o_intra = A @ V : [64x256] per (chunk, bh). Writes obuf fp32. grid (16,8).
// ---------------------------------------------------------------------------
__global__ __launch_bounds__(256)
void av_k(const float* __restrict__ A, const unsigned short* __restrict__ v,
          float* __restrict__ o) {
  __shared__ float As[64 * 64];
  __shared__ float Vs[64 * 64];
  const int t = threadIdx.x;
  const int c = blockIdx.x, bh = blockIdx.y;
  const int b = bh >> 2, h = bh & 3;
  const size_t rowbase = (size_t)b * 1024 + c * 64;
  {
    const int r = t >> 2, s = t & 3;
    const float* Ap = A + (((size_t)bh * 16 + c) * 64 + r) * 64 + s * 16;
#pragma unroll
    for (int u = 0; u < 4; ++u)
      *(vf4*)&As[r * 64 + s * 16 + u * 4] = *(const vf4*)(Ap + u * 4);
  }
  const int i = t >> 2, sb = t & 3;
  for (int vt = 0; vt < 4; ++vt) {
    __syncthreads();
    {
      const int r = t >> 2, s = t & 3;
      const unsigned short* vp = v + (rowbase + r) * 1024 + h * 256 + vt * 64 + s * 16;
      float f[16];
      unpack16(vp, f);
#pragma unroll
      for (int u = 0; u < 16; ++u) Vs[r * 64 + s * 16 + u] = f[u];
    }
    __syncthreads();
    vf4 acc[4];
#pragma unroll
    for (int u = 0; u < 4; ++u) acc[u] = vzero();
    for (int jj = 0; jj < 64; ++jj) {
      const float a = As[i * 64 + jj];
#pragma unroll
      for (int u = 0; u < 4; ++u)
        acc[u] += a * *(const vf4*)&Vs[jj * 64 + sb * 16 + u * 4];
    }
    float* op = o + (rowbase + i) * 1024 + h * 256 + vt * 64 + sb * 16;
#pragma unroll
    for (int u = 0; u < 4; ++u) *(vf4*)(op + u * 4) = acc[u];
  }
}

// ---------------------------------------------------------------------------
// KV_c = K~^T V per (vt, chunk, bh): [128 x 64cols] -> bf16 S. grid (4,16,8).
// ---------------------------------------------------------------------------
__global__ __launch_bounds__(256)
void kv_k(const float* __restrict__ kb, const unsigned short* __restrict__ v,
          unsigned short* __restrict__ S) {
  __shared__ float Ks[64 * 128];
  __shared__ float Vs[64 * 64];
  const int t = threadIdx.x;
  const int vt = blockIdx.x, c = blockIdx.y, bh = blockIdx.z;
  const int b = bh >> 2, h = bh & 3;
  const size_t rowbase = (size_t)b * 1024 + c * 64;
  {
    const int r = t >> 2, s = t & 3;
    const float* kp = kb + (rowbase + r) * 512 + h * 128 + s * 32;
#pragma unroll
    for (int u = 0; u < 8; ++u)
      *(vf4*)&Ks[r * 128 + s * 32 + u * 4] = *(const vf4*)(kp + u * 4);
    const unsigned short* vp = v + (rowbase + r) * 1024 + h * 256 + vt * 64 + s * 16;
    float f[16];
    unpack16(vp, f);
#pragma unroll
    for (int u = 0; u < 16; ++u) Vs[r * 64 + s * 16 + u] = f[u];
  }
  __syncthreads();
  const int kk = t >> 1, half = t & 1;
  float su[32];
#pragma unroll
  for (int u = 0; u < 32; ++u) su[u] = 0.f;
  for (int j = 0; j < 64; ++j) {
    const float kv = Ks[j * 128 + kk];
    const float* vrow = &Vs[j * 64 + half * 32];
#pragma unroll
    for (int u = 0; u < 32; ++u) su[u] = fmaf(kv, vrow[u], su[u]);
  }
  unsigned short* Sp = S + (((size_t)bh * 16 + c) * 128 + kk) * 256 + vt * 64 + half * 32;
#pragma unroll
  for (int u = 0; u < 4; ++u)
    *(vu4*)(Sp + u * 8) = pack8(&su[u * 8]);
}

// ---------------------------------------------------------------------------
// Elementwise state scan in place on bf16 S; fp32 carry in registers.
// ---------------------------------------------------------------------------
__global__ __launch_bounds__(256)
void state_scan_k(unsigned short* __restrict__ S, const float* __restrict__ ebtot) {
  const int idx = blockIdx.x * 256 + threadIdx.x;  // 0..32767
  const int vg = idx & 31;
  const int kk = (idx >> 5) & 127;
  const int bh = idx >> 12;
  const int b = bh >> 2, h = bh & 3;
  float s[8];
#pragma unroll
  for (int u = 0; u < 8; ++u) s[u] = 0.f;
  for (int c = 0; c < 16; ++c) {
    unsigned short* p = S + (((size_t)bh * 16 + c) * 128 + kk) * 256 + vg * 8;
    const float e = ebtot[(((size_t)b * 16 + c) << 9) + h * 128 + kk];
    float kv[8];
    unpack8(*(const vu4*)p, kv);
    *(vu4*)p = pack8(s);
#pragma unroll
    for (int u = 0; u < 8; ++u) s[u] = (s[u] + kv[u]) * e;
  }
}

// ---------------------------------------------------------------------------
// obuf += Q~ @ S_c per (vt8, chunk, bh): [64 x 32cols]. grid (8,16,8).
// ---------------------------------------------------------------------------
__global__ __launch_bounds__(256)
void o_inter_k(const float* __restrict__ q, const unsigned short* __restrict__ S,
               float* __restrict__ o) {
  __shared__ float Qs[64 * 132];
  __shared__ float Ss[128 * 32];
  const int t = threadIdx.x;
  const int vt = blockIdx.x, c = blockIdx.y, bh = blockIdx.z;
  const int b = bh >> 2, h = bh & 3;
  const size_t rowbase = (size_t)b * 1024 + c * 64;
  {
    const int r = t >> 2, s = t & 3;
    const float* qp = q + (rowbase + r) * 512 + h * 128 + s * 32;
#pragma unroll
    for (int u = 0; u < 8; ++u)
      *(vf4*)&Qs[r * 132 + s * 32 + u * 4] = *(const vf4*)(qp + u * 4);
    const int r2 = t >> 1, s2 = t & 1;
    const unsigned short* sp = S + (((size_t)bh * 16 + c) * 128 + r2) * 256 + vt * 32 + s2 * 16;
    float f[16];
    unpack16(sp, f);
#pragma unroll
    for (int u = 0; u < 16; ++u) Ss[r2 * 32 + s2 * 16 + u] = f[u];
  }
  __syncthreads();
  const int i = t >> 2, sb = t & 3;
  vf4 acc0 = vzero(), acc1 = vzero();
  for (int k4 = 0; k4 < 128; ++k4) {
    const float qs = Qs[i * 132 + k4];
    const float* sp = &Ss[k4 * 32 + sb * 8];
    acc0 += qs * *(const vf4*)sp;
    acc1 += qs * *(const vf4*)(sp + 4);
  }
  float* op = o + (rowbase + i) * 1024 + h * 256 + vt * 32 + sb * 8;
  vf4 x0 = *(const vf4*)op;
  vf4 x1 = *(const vf4*)(op + 4);
  x0 += acc0; x1 += acc1;
  *(vf4*)op = x0;
  *(vf4*)(op + 4) = x1;
}

// ---------------------------------------------------------------------------
// RMSNorm over DV=256 + silu-gate; reads obuf fp32, writes obuf_b bf16.
// ---------------------------------------------------------------------------
__global__ __launch_bounds__(256)
void norm_gate_k(const float* __restrict__ o, const float* __restrict__ rmsw,
                 const unsigned short* __restrict__ sg,
                 unsigned short* __restrict__ ob) {
  __shared__ float red[4];
  const int grp = blockIdx.x;          // 0..8191
  const int row = grp >> 2, h = grp & 3;
  const int t = threadIdx.x;
  const size_t idx = (size_t)row * 1024 + h * 256 + t;
  const float val = o[idx];
  float ss = val * val;
#pragma unroll
  for (int mm = 1; mm < 64; mm <<= 1) ss += __shfl_xor(ss, mm, 64);
  if ((t & 63) == 0) red[t >> 6] = ss;
  __syncthreads();
  const float tot = red[0] + red[1] + red[2] + red[3];
  const float scale = rsqrtf(tot * (1.f / 256.f) + 1e-5f);
  ob[idx] = f2bf(val * scale * rmsw[t] * bf2f((unsigned int)sg[idx]));
}

// ---------------------------------------------------------------------------
extern "C" void kernel_launch(void* const* d_in, const int* in_sizes, int n_in,
                              void* d_out, int out_size, void* d_ws, size_t ws_size,
                              hipStream_t stream) {
  const float* x    = (const float*)d_in[0];
  const float* Wq   = (const float*)d_in[1];
  const float* Wk   = (const float*)d_in[2];
  const float* Wv   = (const float*)d_in[3];
  const float* Wg   = (const float*)d_in[4];
  const float* Wgk1 = (const float*)d_in[5];
  const float* Wgk2 = (const float*)d_in[6];
  const float* bgk2 = (const float*)d_in[7];
  const float* Wout = (const float*)d_in[8];
  const float* rmsw = (const float*)d_in[9];

  // Workspace (41 MB, byte offsets)
  const size_t MB = 1u << 20;
  char* w = (char*)d_ws;
  float*          qbuf   = (float*)(w);                    // [0,4) MB
  float*          kbuf   = (float*)(w + 4 * MB);           // [4,8)
  unsigned short* vbuf   = (unsigned short*)(w + 8 * MB);  // [8,12)
  unsigned short* sgbuf  = (unsigned short*)(w + 12 * MB); // [12,16)
  float*          obuf   = (float*)(w + 16 * MB);          // [16,24)
  char*           sreg   = w + 24 * MB;                    // [24,32) multi-phase
  unsigned short* xb     = (unsigned short*)sreg;          //   phase 1: 4 MB
  float*          Abuf   = (float*)(sreg + 4 * MB);        //   phase 2: 2 MB
  unsigned short* Sbuf   = (unsigned short*)sreg;          //   phase 3: 8 MB
  unsigned short* obuf_b = (unsigned short*)sreg;          //   phase 4: 4 MB
  float*          xlbuf  = (float*)(w + 32 * MB);          // 128 KB
  float*          ebbuf  = (float*)(w + 32 * MB + 131072); // 64 KB
  unsigned short* wqT    = (unsigned short*)(w + 33 * MB); // 1 MB
  unsigned short* wkT    = (unsigned short*)(w + 34 * MB); // 1 MB
  unsigned short* wvT    = (unsigned short*)(w + 35 * MB); // 2 MB
  unsigned short* wgT    = (unsigned short*)(w + 37 * MB); // 2 MB
  unsigned short* woT    = (unsigned short*)(w + 39 * MB); // 2 MB

  wtconv_k<<<dim3(64, 16), 256, 0, stream>>>(Wq, Wk, Wv, Wg, Wout, wqT, wkT, wvT, wgT, woT);
  xconv_k<<<1024, 256, 0, stream>>>(x, xb);
  lowrank_k<<<2048, 64, 0, stream>>>(x, Wgk1, xlbuf);
  proj_mfma_k<<<dim3(24, 16), 256, 0, stream>>>(xb, wqT, wkT, wvT, wgT, qbuf, kbuf, vbuf, sgbuf);
  gate_scan_k<<<4096, 256, 0, stream>>>(xlbuf, Wgk2, bgk2, qbuf, kbuf, ebbuf);
  qk_k<<<dim3(16, 8), 256, 0, stream>>>(qbuf, kbuf, Abuf);
  av_k<<<dim3(16, 8), 256, 0, stream>>>(Abuf, vbuf, obuf);
  kv_k<<<dim3(4, 16, 8), 256, 0, stream>>>(kbuf, vbuf, Sbuf);
  state_scan_k<<<128, 256, 0, stream>>>(Sbuf, ebbuf);
  o_inter_k<<<dim3(8, 16, 8), 256, 0, stream>>>(qbuf, Sbuf, obuf);
  norm_gate_k<<<8192, 256, 0, stream>>>(obuf, rmsw, sgbuf, obuf_b);
  out_mfma_k<<<dim3(8, 16), 256, 0, stream>>>(obuf_b, woT, (float*)d_out);
}

// Round 7
// 228.001 us; speedup vs baseline: 3.6120x; 1.2023x over previous
//
#include <hip/hip_runtime.h>
#include <math.h>

// GLA: B=2, N=1024, D=1024, H=4, KD=512, VD=1024, DK=128, DV=256, LR=16
// Round 7: mid-section MFMA-ized. q~,k~ bf16; qk+av fused (A in LDS);
// chunk-state S stored transposed [v][k] so kv/state_scan/o_inter are
// layout-friendly; o_inter pure MFMA; xconv folded into proj staging.
// 10 kernels. Workspace ~37 MB.

typedef __attribute__((ext_vector_type(4))) float vf4;
typedef __attribute__((ext_vector_type(4))) unsigned int vu4;
typedef __attribute__((ext_vector_type(8))) short short8;

#define DEVI static __device__ __forceinline__
DEVI vf4 vzero() { vf4 x = {0.f, 0.f, 0.f, 0.f}; return x; }

DEVI float bf2f(unsigned int u) {
  union { unsigned int i; float f; } c; c.i = u << 16; return c.f;
}
DEVI unsigned short f2bf(float f) {
  union { float f; unsigned int i; } c; c.f = f;
  unsigned int i = c.i;
  return (unsigned short)((i + 0x7fffu + ((i >> 16) & 1u)) >> 16);
}
DEVI void unpack8(vu4 r, float* f) {
  f[0] = bf2f(r.x & 0xffffu); f[1] = bf2f(r.x >> 16);
  f[2] = bf2f(r.y & 0xffffu); f[3] = bf2f(r.y >> 16);
  f[4] = bf2f(r.z & 0xffffu); f[5] = bf2f(r.z >> 16);
  f[6] = bf2f(r.w & 0xffffu); f[7] = bf2f(r.w >> 16);
}
DEVI void unpack16(const unsigned short* p, float* f) {
  unpack8(*(const vu4*)p, f);
  unpack8(*(const vu4*)(p + 8), f + 8);
}
DEVI vu4 pack8(const float* f) {
  vu4 o;
  o.x = (unsigned int)f2bf(f[0]) | ((unsigned int)f2bf(f[1]) << 16);
  o.y = (unsigned int)f2bf(f[2]) | ((unsigned int)f2bf(f[3]) << 16);
  o.z = (unsigned int)f2bf(f[4]) | ((unsigned int)f2bf(f[5]) << 16);
  o.w = (unsigned int)f2bf(f[6]) | ((unsigned int)f2bf(f[7]) << 16);
  return o;
}

// ---------------------------------------------------------------------------
// Weight transpose+convert: W[1024][N] fp32 -> WT[N][1024] bf16. 64x64 tiles.
// ---------------------------------------------------------------------------
__global__ __launch_bounds__(256)
void wtconv_k(const float* __restrict__ Wq, const float* __restrict__ Wk,
              const float* __restrict__ Wv, const float* __restrict__ Wg,
              const float* __restrict__ Wo,
              unsigned short* __restrict__ wqT, unsigned short* __restrict__ wkT,
              unsigned short* __restrict__ wvT, unsigned short* __restrict__ wgT,
              unsigned short* __restrict__ woT) {
  __shared__ float T[64][65];
  const int ct = blockIdx.x, kt = blockIdx.y;
  const float* W; unsigned short* O; int N; int cb;
  if (ct < 8)       { W = Wq; O = wqT; N = 512;  cb = ct; }
  else if (ct < 16) { W = Wk; O = wkT; N = 512;  cb = ct - 8; }
  else if (ct < 32) { W = Wv; O = wvT; N = 1024; cb = ct - 16; }
  else if (ct < 48) { W = Wg; O = wgT; N = 1024; cb = ct - 32; }
  else              { W = Wo; O = woT; N = 1024; cb = ct - 48; }
  const int t = threadIdx.x;
  const int r = t >> 2, s = t & 3;
  const float* src = W + (size_t)(kt * 64 + r) * N + cb * 64 + s * 16;
#pragma unroll
  for (int u = 0; u < 4; ++u) {
    vf4 v4 = *(const vf4*)(src + u * 4);
    T[r][s * 16 + u * 4 + 0] = v4.x;
    T[r][s * 16 + u * 4 + 1] = v4.y;
    T[r][s * 16 + u * 4 + 2] = v4.z;
    T[r][s * 16 + u * 4 + 3] = v4.w;
  }
  __syncthreads();
  unsigned int pk[8];
#pragma unroll
  for (int u = 0; u < 8; ++u) {
    unsigned int lo = f2bf(T[s * 16 + 2 * u][r]);
    unsigned int hi = f2bf(T[s * 16 + 2 * u + 1][r]);
    pk[u] = lo | (hi << 16);
  }
  unsigned short* dst = O + (size_t)(cb * 64 + r) * 1024 + kt * 64 + s * 16;
  *(vu4*)dst = *(vu4*)&pk[0];
  *(vu4*)(dst + 8) = *(vu4*)&pk[4];
}

// ---------------------------------------------------------------------------
// MFMA projection: x[2048,1024]fp32 (converted in staging) @ WT(bf16) ->
// q,k bf16; v,sg(silu) bf16. 128x128 tile, BK=64. grid (24,16).
// ---------------------------------------------------------------------------
__global__ __launch_bounds__(256)
void proj_mfma_k(const float* __restrict__ X,
                 const unsigned short* __restrict__ wqT, const unsigned short* __restrict__ wkT,
                 const unsigned short* __restrict__ wvT, const unsigned short* __restrict__ wgT,
                 unsigned short* __restrict__ qb, unsigned short* __restrict__ kb,
                 unsigned short* __restrict__ vb, unsigned short* __restrict__ sgb) {
  __shared__ __align__(16) unsigned short As[128 * 72];
  __shared__ __align__(16) unsigned short Bs[128 * 72];
  const int t = threadIdx.x;
  const int m0 = blockIdx.y << 7;
  const int nt = blockIdx.x;
  const unsigned short* WT; int n0; int kind;
  if (nt < 4)       { WT = wqT; n0 = nt * 128;        kind = 0; }
  else if (nt < 8)  { WT = wkT; n0 = (nt - 4) * 128;  kind = 1; }
  else if (nt < 16) { WT = wvT; n0 = (nt - 8) * 128;  kind = 2; }
  else              { WT = wgT; n0 = (nt - 16) * 128; kind = 3; }

  const int w = t >> 6, lane = t & 63;
  const int wm = (w >> 1) * 64, wn = (w & 1) * 64;
  const int qd = lane >> 4, m = lane & 15;

  vf4 acc[4][4];
#pragma unroll
  for (int i = 0; i < 4; ++i)
#pragma unroll
    for (int j = 0; j < 4; ++j) acc[i][j] = vzero();

  for (int k0 = 0; k0 < 1024; k0 += 64) {
    __syncthreads();
#pragma unroll
    for (int u2 = 0; u2 < 4; ++u2) {
      const int id = t + (u2 << 8);
      const int row = id >> 3, kg = id & 7;
      const float* ap = X + (size_t)(m0 + row) * 1024 + k0 + kg * 8;
      float fa[8];
      *(vf4*)&fa[0] = *(const vf4*)ap;
      *(vf4*)&fa[4] = *(const vf4*)(ap + 4);
      *(vu4*)&As[row * 72 + kg * 8] = pack8(fa);
      vu4 rb = *(const vu4*)(WT + (size_t)(n0 + row) * 1024 + k0 + kg * 8);
      *(vu4*)&Bs[row * 72 + kg * 8] = rb;
    }
    __syncthreads();
#pragma unroll
    for (int ks = 0; ks < 2; ++ks) {
      short8 af[4], bf[4];
#pragma unroll
      for (int i = 0; i < 4; ++i) {
        af[i] = *(const short8*)&As[(wm + i * 16 + m) * 72 + ks * 32 + qd * 8];
        bf[i] = *(const short8*)&Bs[(wn + i * 16 + m) * 72 + ks * 32 + qd * 8];
      }
#pragma unroll
      for (int i = 0; i < 4; ++i)
#pragma unroll
        for (int j = 0; j < 4; ++j)
          acc[i][j] = __builtin_amdgcn_mfma_f32_16x16x32_bf16(af[i], bf[j], acc[i][j], 0, 0, 0);
    }
  }
#pragma unroll
  for (int i = 0; i < 4; ++i) {
#pragma unroll
    for (int j = 0; j < 4; ++j) {
#pragma unroll
      for (int r = 0; r < 4; ++r) {
        const int grow = m0 + wm + i * 16 + qd * 4 + r;
        const int gcol = n0 + wn + j * 16 + m;
        float val = acc[i][j][r];
        if (kind == 0)      qb[(size_t)grow * 512 + gcol] = f2bf(val);
        else if (kind == 1) kb[(size_t)grow * 512 + gcol] = f2bf(val);
        else if (kind == 2) vb[(size_t)grow * 1024 + gcol] = f2bf(val);
        else {
          val = val / (1.f + expf(-val));
          sgb[(size_t)grow * 1024 + gcol] = f2bf(val);
        }
      }
    }
  }
}

// ---------------------------------------------------------------------------
// MFMA output GEMM: obuf_b[2048,1024]bf16 @ woT -> d_out fp32. grid (8,16).
// ---------------------------------------------------------------------------
__global__ __launch_bounds__(256)
void out_mfma_k(const unsigned short* __restrict__ Ab,
                const unsigned short* __restrict__ woT, float* __restrict__ Y) {
  __shared__ __align__(16) unsigned short As[128 * 72];
  __shared__ __align__(16) unsigned short Bs[128 * 72];
  const int t = threadIdx.x;
  const int m0 = blockIdx.y << 7;
  const int n0 = blockIdx.x << 7;
  const int w = t >> 6, lane = t & 63;
  const int wm = (w >> 1) * 64, wn = (w & 1) * 64;
  const int qd = lane >> 4, m = lane & 15;

  vf4 acc[4][4];
#pragma unroll
  for (int i = 0; i < 4; ++i)
#pragma unroll
    for (int j = 0; j < 4; ++j) acc[i][j] = vzero();

  for (int k0 = 0; k0 < 1024; k0 += 64) {
    __syncthreads();
#pragma unroll
    for (int u2 = 0; u2 < 4; ++u2) {
      const int id = t + (u2 << 8);
      const int row = id >> 3, kg = id & 7;
      vu4 ra = *(const vu4*)(Ab + (size_t)(m0 + row) * 1024 + k0 + kg * 8);
      *(vu4*)&As[row * 72 + kg * 8] = ra;
      vu4 rb = *(const vu4*)(woT + (size_t)(n0 + row) * 1024 + k0 + kg * 8);
      *(vu4*)&Bs[row * 72 + kg * 8] = rb;
    }
    __syncthreads();
#pragma unroll
    for (int ks = 0; ks < 2; ++ks) {
      short8 af[4], bf[4];
#pragma unroll
      for (int i = 0; i < 4; ++i) {
        af[i] = *(const short8*)&As[(wm + i * 16 + m) * 72 + ks * 32 + qd * 8];
        bf[i] = *(const short8*)&Bs[(wn + i * 16 + m) * 72 + ks * 32 + qd * 8];
      }
#pragma unroll
      for (int i = 0; i < 4; ++i)
#pragma unroll
        for (int j = 0; j < 4; ++j)
          acc[i][j] = __builtin_amdgcn_mfma_f32_16x16x32_bf16(af[i], bf[j], acc[i][j], 0, 0, 0);
    }
  }
#pragma unroll
  for (int i = 0; i < 4; ++i)
#pragma unroll
    for (int j = 0; j < 4; ++j)
#pragma unroll
      for (int r = 0; r < 4; ++r) {
        const int grow = m0 + wm + i * 16 + qd * 4 + r;
        const int gcol = n0 + wn + j * 16 + m;
        Y[(size_t)grow * 1024 + gcol] = acc[i][j][r];
      }
}

// ---------------------------------------------------------------------------
// xl = x @ Wgk1 [2048,16] fp32. One wave per row.
// ---------------------------------------------------------------------------
__global__ __launch_bounds__(64)
void lowrank_k(const float* __restrict__ X, const float* __restrict__ W1,
               float* __restrict__ xl) {
  const int row = blockIdx.x;
  const int t = threadIdx.x;
  float acc[16];
#pragma unroll
  for (int c2 = 0; c2 < 16; ++c2) acc[c2] = 0.f;
  const float* xp = X + (size_t)row * 1024 + t * 16;
  float xv[16];
#pragma unroll
  for (int u = 0; u < 4; ++u)
    *(vf4*)&xv[u * 4] = *(const vf4*)(xp + u * 4);
#pragma unroll
  for (int j = 0; j < 16; ++j) {
    const float* wp = W1 + (size_t)(t * 16 + j) * 16;
    float wv[16];
#pragma unroll
    for (int u = 0; u < 4; ++u)
      *(vf4*)&wv[u * 4] = *(const vf4*)(wp + u * 4);
#pragma unroll
    for (int c2 = 0; c2 < 16; ++c2) acc[c2] = fmaf(xv[j], wv[c2], acc[c2]);
  }
#pragma unroll
  for (int mm = 1; mm < 64; mm <<= 1) {
#pragma unroll
    for (int c2 = 0; c2 < 16; ++c2) acc[c2] += __shfl_xor(acc[c2], mm, 64);
  }
  if (t == 0) {
#pragma unroll
    for (int c2 = 0; c2 < 16; ++c2) xl[(size_t)row * 16 + c2] = acc[c2];
  }
}

// ---------------------------------------------------------------------------
// Fused gate + wave-parallel scan + q/k scaling (bf16 RMW).
// One wave per (b,chunk,kcol); lane i = row i. grid 4096 x 256.
// ---------------------------------------------------------------------------
__global__ __launch_bounds__(256)
void gate_scan_k(const float* __restrict__ xl, const float* __restrict__ W2,
                 const float* __restrict__ bias,
                 unsigned short* __restrict__ q, unsigned short* __restrict__ k,
                 float* __restrict__ ebtot) {
  const int t = threadIdx.x;
  const int w = t >> 6, lane = t & 63;
  const int wid = blockIdx.x * 4 + w;     // 0..16383
  const int kcol = wid & 511;
  const int c = (wid >> 9) & 15;
  const int b = wid >> 13;
  const size_t rowbase = (size_t)b * 1024 + c * 64;

  const float* xp = xl + (rowbase + lane) * 16;
  float xv[16];
#pragma unroll
  for (int u = 0; u < 4; ++u)
    *(vf4*)&xv[u * 4] = *(const vf4*)(xp + u * 4);
  float z = bias[kcol];
#pragma unroll
  for (int r = 0; r < 16; ++r) z = fmaf(xv[r], W2[r * 512 + kcol], z);
  float ls = fminf(z, 0.f) - log1pf(expf(-fabsf(z)));
  float g = fmaxf(ls * (1.f / 16.f), -3.f);

#pragma unroll
  for (int d = 1; d < 64; d <<= 1) {
    float up = __shfl_up(g, d, 64);
    if (lane >= d) g += up;
  }

  const size_t a = (rowbase + lane) * 512 + kcol;
  float qv = bf2f((unsigned int)q[a]) * expf(g);
  float kv = bf2f((unsigned int)k[a]) * expf(fminf(-g, 80.f));
  q[a] = f2bf(qv);
  k[a] = f2bf(kv);
  if (lane == 63)
    ebtot[((size_t)b * 16 + c) * 512 + kcol] = expf(g);
}

// ---------------------------------------------------------------------------
// Fused intra-chunk: A = tril(Q~K~^T) via MFMA (A in LDS), o_intra = A@V via
// VALU. grid (vh2, chunk16, bh8) = 256 blocks; block does 128 v-cols.
// ---------------------------------------------------------------------------
__global__ __launch_bounds__(256)
void intra_k(const unsigned short* __restrict__ q16, const unsigned short* __restrict__ k16,
             const unsigned short* __restrict__ v, float* __restrict__ o) {
  __shared__ __align__(16) unsigned short Qs[64 * 136];  // 17.4 KB
  __shared__ __align__(16) unsigned short Ks[64 * 136];  // 17.4 KB
  __shared__ float As[64 * 68];                          // 17.4 KB
  __shared__ float Vs[64 * 64];                          // 16 KB
  const int t = threadIdx.x;
  const int vh = blockIdx.x, c = blockIdx.y, bh = blockIdx.z;
  const int b = bh >> 2, h = bh & 3;
  const size_t rowbase = (size_t)b * 1024 + c * 64;

  // stage Q~,K~ tiles [64 x 128] bf16
#pragma unroll
  for (int u2 = 0; u2 < 4; ++u2) {
    const int id = t + (u2 << 8);
    const int row = id >> 4, kg = id & 15;
    *(vu4*)&Qs[row * 136 + kg * 8] =
        *(const vu4*)(q16 + (rowbase + row) * 512 + h * 128 + kg * 8);
    *(vu4*)&Ks[row * 136 + kg * 8] =
        *(const vu4*)(k16 + (rowbase + row) * 512 + h * 128 + kg * 8);
  }
  __syncthreads();

  // A = Q K^T via MFMA; wave w -> rows w*16..+15
  {
    const int w = t >> 6, lane = t & 63;
    const int qd = lane >> 4, m = lane & 15;
    short8 af[4];
#pragma unroll
    for (int kf = 0; kf < 4; ++kf)
      af[kf] = *(const short8*)&Qs[(w * 16 + m) * 136 + kf * 32 + qd * 8];
    vf4 acc[4];
#pragma unroll
    for (int jt = 0; jt < 4; ++jt) acc[jt] = vzero();
#pragma unroll
    for (int jt = 0; jt < 4; ++jt)
#pragma unroll
      for (int kf = 0; kf < 4; ++kf) {
        short8 bfr = *(const short8*)&Ks[(jt * 16 + m) * 136 + kf * 32 + qd * 8];
        acc[jt] = __builtin_amdgcn_mfma_f32_16x16x32_bf16(af[kf], bfr, acc[jt], 0, 0, 0);
      }
#pragma unroll
    for (int jt = 0; jt < 4; ++jt)
#pragma unroll
      for (int r = 0; r < 4; ++r) {
        const int i = w * 16 + qd * 4 + r;
        const int j = jt * 16 + m;
        As[i * 68 + j] = (j <= i) ? acc[jt][r] : 0.f;
      }
  }

  // o_intra = A @ V (VALU), two 64-col phases
  const int i2 = t >> 2, sb = t & 3;
  for (int p = 0; p < 2; ++p) {
    const int vt = vh * 2 + p;
    __syncthreads();  // As ready (p=0) / prior Vs reads done (p=1)
    {
      const int r = t >> 2, s = t & 3;
      const unsigned short* vp = v + (rowbase + r) * 1024 + h * 256 + vt * 64 + s * 16;
      float f[16];
      unpack16(vp, f);
#pragma unroll
      for (int u = 0; u < 16; ++u) Vs[r * 64 + s * 16 + u] = f[u];
    }
    __syncthreads();
    vf4 acc[4];
#pragma unroll
    for (int u = 0; u < 4; ++u) acc[u] = vzero();
    for (int jj = 0; jj < 64; ++jj) {
      const float a = As[i2 * 68 + jj];
#pragma unroll
      for (int u = 0; u < 4; ++u)
        acc[u] += a * *(const vf4*)&Vs[jj * 64 + sb * 16 + u * 4];
    }
    float* op = o + (rowbase + i2) * 1024 + h * 256 + vt * 64 + sb * 16;
#pragma unroll
    for (int u = 0; u < 4; ++u) *(vf4*)(op + u * 4) = acc[u];
  }
}

// ---------------------------------------------------------------------------
// KV^T_c = (K~^T V)^T stored [v][k] bf16. grid (vt4, chunk16, bh8).
// ---------------------------------------------------------------------------
__global__ __launch_bounds__(256)
void kv_k(const unsigned short* __restrict__ k16, const unsigned short* __restrict__ v,
          unsigned short* __restrict__ ST) {
  __shared__ float Ks[64 * 128];
  __shared__ float Vs[64 * 64];
  const int t = threadIdx.x;
  const int vt = blockIdx.x, c = blockIdx.y, bh = blockIdx.z;
  const int b = bh >> 2, h = bh & 3;
  const size_t rowbase = (size_t)b * 1024 + c * 64;
  {
    const int r = t >> 2, s = t & 3;
    const unsigned short* kp = k16 + (rowbase + r) * 512 + h * 128 + s * 32;
    float fk[32];
    unpack16(kp, fk);
    unpack16(kp + 16, fk + 16);
#pragma unroll
    for (int u = 0; u < 8; ++u)
      *(vf4*)&Ks[r * 128 + s * 32 + u * 4] = *(const vf4*)&fk[u * 4];
    const unsigned short* vp = v + (rowbase + r) * 1024 + h * 256 + vt * 64 + s * 16;
    float f[16];
    unpack16(vp, f);
#pragma unroll
    for (int u = 0; u < 16; ++u) Vs[r * 64 + s * 16 + u] = f[u];
  }
  __syncthreads();
  const int kk = t >> 1, half = t & 1;
  float su[32];
#pragma unroll
  for (int u = 0; u < 32; ++u) su[u] = 0.f;
  for (int j = 0; j < 64; ++j) {
    const float kv = Ks[j * 128 + kk];
    const float* vrow = &Vs[j * 64 + half * 32];
#pragma unroll
    for (int u = 0; u < 32; ++u) su[u] = fmaf(kv, vrow[u], su[u]);
  }
  // transposed store: ST[(bh,c)][v][k]
  unsigned short* Sp = ST + ((size_t)(bh * 16 + c) * 256 + vt * 64 + half * 32) * 128 + kk;
#pragma unroll
  for (int u = 0; u < 32; ++u)
    Sp[(size_t)u * 128] = f2bf(su[u]);
}

// ---------------------------------------------------------------------------
// State scan in place on bf16 ST[v][k]; fp32 carry; per-k decay vector.
// 32768 threads, 16 serial steps.
// ---------------------------------------------------------------------------
__global__ __launch_bounds__(256)
void state_scan_k(unsigned short* __restrict__ ST, const float* __restrict__ ebtot) {
  const int idx = blockIdx.x * 256 + threadIdx.x;  // 0..32767
  const int kg = idx & 15;
  const int vv = (idx >> 4) & 255;
  const int bh = idx >> 12;
  const int b = bh >> 2, h = bh & 3;
  float s[8];
#pragma unroll
  for (int u = 0; u < 8; ++u) s[u] = 0.f;
  for (int c = 0; c < 16; ++c) {
    unsigned short* p = ST + ((size_t)(bh * 16 + c) * 256 + vv) * 128 + kg * 8;
    const float* ep = ebtot + ((size_t)b * 16 + c) * 512 + h * 128 + kg * 8;
    float e[8];
    *(vf4*)&e[0] = *(const vf4*)ep;
    *(vf4*)&e[4] = *(const vf4*)(ep + 4);
    float kv[8];
    unpack8(*(const vu4*)p, kv);
    *(vu4*)p = pack8(s);
#pragma unroll
    for (int u = 0; u < 8; ++u) s[u] = (s[u] + kv[u]) * e[u];
  }
}

// ---------------------------------------------------------------------------
// o += Q~ @ S_c via MFMA. grid (vt2, chunk16, bh8) = 256 blocks.
// S^T staged [128 v][128 k] bf16 -> B-frag rows contiguous.
// ---------------------------------------------------------------------------
__global__ __launch_bounds__(256)
void o_inter_k(const unsigned short* __restrict__ q16, const unsigned short* __restrict__ ST,
               float* __restrict__ o) {
  __shared__ __align__(16) unsigned short Qs[64 * 136];   // 17.4 KB
  __shared__ __align__(16) unsigned short Ss[128 * 136];  // 34.8 KB
  const int t = threadIdx.x;
  const int vt = blockIdx.x, c = blockIdx.y, bh = blockIdx.z;
  const int b = bh >> 2, h = bh & 3;
  const size_t rowbase = (size_t)b * 1024 + c * 64;

#pragma unroll
  for (int u2 = 0; u2 < 4; ++u2) {
    const int id = t + (u2 << 8);
    const int row = id >> 4, kg = id & 15;
    *(vu4*)&Qs[row * 136 + kg * 8] =
        *(const vu4*)(q16 + (rowbase + row) * 512 + h * 128 + kg * 8);
  }
#pragma unroll
  for (int u2 = 0; u2 < 8; ++u2) {
    const int id = t + (u2 << 8);
    const int vrow = id >> 4, kg = id & 15;
    *(vu4*)&Ss[vrow * 136 + kg * 8] =
        *(const vu4*)(ST + ((size_t)(bh * 16 + c) * 256 + vt * 128 + vrow) * 128 + kg * 8);
  }
  __syncthreads();

  const int w = t >> 6, lane = t & 63;
  const int qd = lane >> 4, m = lane & 15;
  short8 af[4];
#pragma unroll
  for (int kf = 0; kf < 4; ++kf)
    af[kf] = *(const short8*)&Qs[(w * 16 + m) * 136 + kf * 32 + qd * 8];
#pragma unroll
  for (int nt = 0; nt < 8; ++nt) {
    vf4 acc = vzero();
#pragma unroll
    for (int kf = 0; kf < 4; ++kf) {
      short8 bfr = *(const short8*)&Ss[(nt * 16 + m) * 136 + kf * 32 + qd * 8];
      acc = __builtin_amdgcn_mfma_f32_16x16x32_bf16(af[kf], bfr, acc, 0, 0, 0);
    }
    float* base = o + (rowbase + w * 16 + qd * 4) * 1024 + h * 256 + vt * 128 + nt * 16 + m;
#pragma unroll
    for (int r = 0; r < 4; ++r)
      base[(size_t)r * 1024] += acc[r];
  }
}

// ---------------------------------------------------------------------------
// RMSNorm over DV=256 + silu-gate; obuf fp32 -> obuf_b bf16.
// ---------------------------------------------------------------------------
__global__ __launch_bounds__(256)
void norm_gate_k(const float* __restrict__ o, const float* __restrict__ rmsw,
                 const unsigned short* __restrict__ sg,
                 unsigned short* __restrict__ ob) {
  __shared__ float red[4];
  const int grp = blockIdx.x;          // 0..8191
  const int row = grp >> 2, h = grp & 3;
  const int t = threadIdx.x;
  const size_t idx = (size_t)row * 1024 + h * 256 + t;
  const float val = o[idx];
  float ss = val * val;
#pragma unroll
  for (int mm = 1; mm < 64; mm <<= 1) ss += __shfl_xor(ss, mm, 64);
  if ((t & 63) == 0) red[t >> 6] = ss;
  __syncthreads();
  const float tot = red[0] + red[1] + red[2] + red[3];
  const float scale = rsqrtf(tot * (1.f / 256.f) + 1e-5f);
  ob[idx] = f2bf(val * scale * rmsw[t] * bf2f((unsigned int)sg[idx]));
}

// ---------------------------------------------------------------------------
extern "C" void kernel_launch(void* const* d_in, const int* in_sizes, int n_in,
                              void* d_out, int out_size, void* d_ws, size_t ws_size,
                              hipStream_t stream) {
  const float* x    = (const float*)d_in[0];
  const float* Wq   = (const float*)d_in[1];
  const float* Wk   = (const float*)d_in[2];
  const float* Wv   = (const float*)d_in[3];
  const float* Wg   = (const float*)d_in[4];
  const float* Wgk1 = (const float*)d_in[5];
  const float* Wgk2 = (const float*)d_in[6];
  const float* bgk2 = (const float*)d_in[7];
  const float* Wout = (const float*)d_in[8];
  const float* rmsw = (const float*)d_in[9];

  // Workspace (~37 MB, byte offsets)
  const size_t MB = 1u << 20;
  char* w = (char*)d_ws;
  unsigned short* qb16   = (unsigned short*)(w);           // [0,2) MB bf16
  unsigned short* kb16   = (unsigned short*)(w + 2 * MB);  // [2,4)
  unsigned short* vbuf   = (unsigned short*)(w + 4 * MB);  // [4,8)
  unsigned short* sgbuf  = (unsigned short*)(w + 8 * MB);  // [8,12)
  float*          obuf   = (float*)(w + 12 * MB);          // [12,20) fp32
  char*           sreg   = w + 20 * MB;                    // [20,28) multi-phase
  unsigned short* STbuf  = (unsigned short*)sreg;          //   phase A: 8 MB [v][k]
  unsigned short* obuf_b = (unsigned short*)sreg;          //   phase B: 4 MB
  float*          xlbuf  = (float*)(w + 28 * MB);          // 128 KB
  float*          ebbuf  = (float*)(w + 28 * MB + 131072); // 64 KB
  unsigned short* wqT    = (unsigned short*)(w + 29 * MB); // 1 MB
  unsigned short* wkT    = (unsigned short*)(w + 30 * MB); // 1 MB
  unsigned short* wvT    = (unsigned short*)(w + 31 * MB); // 2 MB
  unsigned short* wgT    = (unsigned short*)(w + 33 * MB); // 2 MB
  unsigned short* woT    = (unsigned short*)(w + 35 * MB); // 2 MB

  wtconv_k<<<dim3(64, 16), 256, 0, stream>>>(Wq, Wk, Wv, Wg, Wout, wqT, wkT, wvT, wgT, woT);
  lowrank_k<<<2048, 64, 0, stream>>>(x, Wgk1, xlbuf);
  proj_mfma_k<<<dim3(24, 16), 256, 0, stream>>>(x, wqT, wkT, wvT, wgT, qb16, kb16, vbuf, sgbuf);
  gate_scan_k<<<4096, 256, 0, stream>>>(xlbuf, Wgk2, bgk2, qb16, kb16, ebbuf);
  intra_k<<<dim3(2, 16, 8), 256, 0, stream>>>(qb16, kb16, vbuf, obuf);
  kv_k<<<dim3(4, 16, 8), 256, 0, stream>>>(kb16, vbuf, STbuf);
  state_scan_k<<<128, 256, 0, stream>>>(STbuf, ebbuf);
  o_inter_k<<<dim3(2, 16, 8), 256, 0, stream>>>(qb16, STbuf, obuf);
  norm_gate_k<<<8192, 256, 0, stream>>>(obuf, rmsw, sgbuf, obuf_b);
  out_mfma_k<<<dim3(8, 16), 256, 0, stream>>>(obuf_b, woT, (float*)d_out);
}

// Round 8
// 226.301 us; speedup vs baseline: 3.6392x; 1.0075x over previous
//
#include <hip/hip_runtime.h>
#include <math.h>

// GLA: B=2, N=1024, D=1024, H=4, KD=512, VD=1024, DK=128, DV=256, LR=16
// Round 8: prep_k fuses weight transpose+convert AND x fp32->bf16 conversion
// (grid 96x16). proj_mfma now stages pure bf16 (vu4) from xb — no per-tile
// pack8 in the hot loop. Everything else unchanged from round 7.
// 10 kernels. Workspace ~37 MB.

typedef __attribute__((ext_vector_type(4))) float vf4;
typedef __attribute__((ext_vector_type(4))) unsigned int vu4;
typedef __attribute__((ext_vector_type(8))) short short8;

#define DEVI static __device__ __forceinline__
DEVI vf4 vzero() { vf4 x = {0.f, 0.f, 0.f, 0.f}; return x; }

DEVI float bf2f(unsigned int u) {
  union { unsigned int i; float f; } c; c.i = u << 16; return c.f;
}
DEVI unsigned short f2bf(float f) {
  union { float f; unsigned int i; } c; c.f = f;
  unsigned int i = c.i;
  return (unsigned short)((i + 0x7fffu + ((i >> 16) & 1u)) >> 16);
}
DEVI void unpack8(vu4 r, float* f) {
  f[0] = bf2f(r.x & 0xffffu); f[1] = bf2f(r.x >> 16);
  f[2] = bf2f(r.y & 0xffffu); f[3] = bf2f(r.y >> 16);
  f[4] = bf2f(r.z & 0xffffu); f[5] = bf2f(r.z >> 16);
  f[6] = bf2f(r.w & 0xffffu); f[7] = bf2f(r.w >> 16);
}
DEVI void unpack16(const unsigned short* p, float* f) {
  unpack8(*(const vu4*)p, f);
  unpack8(*(const vu4*)(p + 8), f + 8);
}
DEVI vu4 pack8(const float* f) {
  vu4 o;
  o.x = (unsigned int)f2bf(f[0]) | ((unsigned int)f2bf(f[1]) << 16);
  o.y = (unsigned int)f2bf(f[2]) | ((unsigned int)f2bf(f[3]) << 16);
  o.z = (unsigned int)f2bf(f[4]) | ((unsigned int)f2bf(f[5]) << 16);
  o.w = (unsigned int)f2bf(f[6]) | ((unsigned int)f2bf(f[7]) << 16);
  return o;
}

// ---------------------------------------------------------------------------
// prep_k: ct<64 -> weight transpose+convert W[1024][N]->WT[N][1024] bf16
// (64x64 LDS tiles); ct>=64 -> x[2048,1024] fp32->bf16 flat tiles.
// grid (96,16).
// ---------------------------------------------------------------------------
__global__ __launch_bounds__(256)
void prep_k(const float* __restrict__ Wq, const float* __restrict__ Wk,
            const float* __restrict__ Wv, const float* __restrict__ Wg,
            const float* __restrict__ Wo, const float* __restrict__ X,
            unsigned short* __restrict__ wqT, unsigned short* __restrict__ wkT,
            unsigned short* __restrict__ wvT, unsigned short* __restrict__ wgT,
            unsigned short* __restrict__ woT, unsigned short* __restrict__ xb) {
  __shared__ float T[64][65];
  const int ct = blockIdx.x, kt = blockIdx.y;
  const int t = threadIdx.x;
  const int r = t >> 2, s = t & 3;
  if (ct >= 64) {
    // x conversion: row-tile rt covers rows rt*64..+64; cols kt*64..+64.
    const int rt = ct - 64;                      // 0..31
    const size_t base = (size_t)(rt * 64 + r) * 1024 + kt * 64 + s * 16;
    float f[16];
    *(vf4*)&f[0]  = *(const vf4*)(X + base);
    *(vf4*)&f[4]  = *(const vf4*)(X + base + 4);
    *(vf4*)&f[8]  = *(const vf4*)(X + base + 8);
    *(vf4*)&f[12] = *(const vf4*)(X + base + 12);
    *(vu4*)(xb + base) = pack8(f);
    *(vu4*)(xb + base + 8) = pack8(f + 8);
    return;
  }
  const float* W; unsigned short* O; int N; int cb;
  if (ct < 8)       { W = Wq; O = wqT; N = 512;  cb = ct; }
  else if (ct < 16) { W = Wk; O = wkT; N = 512;  cb = ct - 8; }
  else if (ct < 32) { W = Wv; O = wvT; N = 1024; cb = ct - 16; }
  else if (ct < 48) { W = Wg; O = wgT; N = 1024; cb = ct - 32; }
  else              { W = Wo; O = woT; N = 1024; cb = ct - 48; }
  const float* src = W + (size_t)(kt * 64 + r) * N + cb * 64 + s * 16;
#pragma unroll
  for (int u = 0; u < 4; ++u) {
    vf4 v4 = *(const vf4*)(src + u * 4);
    T[r][s * 16 + u * 4 + 0] = v4.x;
    T[r][s * 16 + u * 4 + 1] = v4.y;
    T[r][s * 16 + u * 4 + 2] = v4.z;
    T[r][s * 16 + u * 4 + 3] = v4.w;
  }
  __syncthreads();
  unsigned int pk[8];
#pragma unroll
  for (int u = 0; u < 8; ++u) {
    unsigned int lo = f2bf(T[s * 16 + 2 * u][r]);
    unsigned int hi = f2bf(T[s * 16 + 2 * u + 1][r]);
    pk[u] = lo | (hi << 16);
  }
  unsigned short* dst = O + (size_t)(cb * 64 + r) * 1024 + kt * 64 + s * 16;
  *(vu4*)dst = *(vu4*)&pk[0];
  *(vu4*)(dst + 8) = *(vu4*)&pk[4];
}

// ---------------------------------------------------------------------------
// MFMA projection: xb[2048,1024]bf16 @ WT(bf16) -> q,k,v,sg(silu) bf16.
// 128x128 tile, BK=64. grid (24,16). Pure bf16 staging.
// ---------------------------------------------------------------------------
__global__ __launch_bounds__(256)
void proj_mfma_k(const unsigned short* __restrict__ xb,
                 const unsigned short* __restrict__ wqT, const unsigned short* __restrict__ wkT,
                 const unsigned short* __restrict__ wvT, const unsigned short* __restrict__ wgT,
                 unsigned short* __restrict__ qb, unsigned short* __restrict__ kb,
                 unsigned short* __restrict__ vb, unsigned short* __restrict__ sgb) {
  __shared__ __align__(16) unsigned short As[128 * 72];
  __shared__ __align__(16) unsigned short Bs[128 * 72];
  const int t = threadIdx.x;
  const int m0 = blockIdx.y << 7;
  const int nt = blockIdx.x;
  const unsigned short* WT; int n0; int kind;
  if (nt < 4)       { WT = wqT; n0 = nt * 128;        kind = 0; }
  else if (nt < 8)  { WT = wkT; n0 = (nt - 4) * 128;  kind = 1; }
  else if (nt < 16) { WT = wvT; n0 = (nt - 8) * 128;  kind = 2; }
  else              { WT = wgT; n0 = (nt - 16) * 128; kind = 3; }

  const int w = t >> 6, lane = t & 63;
  const int wm = (w >> 1) * 64, wn = (w & 1) * 64;
  const int qd = lane >> 4, m = lane & 15;

  vf4 acc[4][4];
#pragma unroll
  for (int i = 0; i < 4; ++i)
#pragma unroll
    for (int j = 0; j < 4; ++j) acc[i][j] = vzero();

  for (int k0 = 0; k0 < 1024; k0 += 64) {
    __syncthreads();
#pragma unroll
    for (int u2 = 0; u2 < 4; ++u2) {
      const int id = t + (u2 << 8);
      const int row = id >> 3, kg = id & 7;
      vu4 ra = *(const vu4*)(xb + (size_t)(m0 + row) * 1024 + k0 + kg * 8);
      *(vu4*)&As[row * 72 + kg * 8] = ra;
      vu4 rb = *(const vu4*)(WT + (size_t)(n0 + row) * 1024 + k0 + kg * 8);
      *(vu4*)&Bs[row * 72 + kg * 8] = rb;
    }
    __syncthreads();
#pragma unroll
    for (int ks = 0; ks < 2; ++ks) {
      short8 af[4], bf[4];
#pragma unroll
      for (int i = 0; i < 4; ++i) {
        af[i] = *(const short8*)&As[(wm + i * 16 + m) * 72 + ks * 32 + qd * 8];
        bf[i] = *(const short8*)&Bs[(wn + i * 16 + m) * 72 + ks * 32 + qd * 8];
      }
#pragma unroll
      for (int i = 0; i < 4; ++i)
#pragma unroll
        for (int j = 0; j < 4; ++j)
          acc[i][j] = __builtin_amdgcn_mfma_f32_16x16x32_bf16(af[i], bf[j], acc[i][j], 0, 0, 0);
    }
  }
#pragma unroll
  for (int i = 0; i < 4; ++i) {
#pragma unroll
    for (int j = 0; j < 4; ++j) {
#pragma unroll
      for (int r = 0; r < 4; ++r) {
        const int grow = m0 + wm + i * 16 + qd * 4 + r;
        const int gcol = n0 + wn + j * 16 + m;
        float val = acc[i][j][r];
        if (kind == 0)      qb[(size_t)grow * 512 + gcol] = f2bf(val);
        else if (kind == 1) kb[(size_t)grow * 512 + gcol] = f2bf(val);
        else if (kind == 2) vb[(size_t)grow * 1024 + gcol] = f2bf(val);
        else {
          val = val / (1.f + expf(-val));
          sgb[(size_t)grow * 1024 + gcol] = f2bf(val);
        }
      }
    }
  }
}

// ---------------------------------------------------------------------------
// MFMA output GEMM: obuf_b[2048,1024]bf16 @ woT -> d_out fp32. grid (8,16).
// ---------------------------------------------------------------------------
__global__ __launch_bounds__(256)
void out_mfma_k(const unsigned short* __restrict__ Ab,
                const unsigned short* __restrict__ woT, float* __restrict__ Y) {
  __shared__ __align__(16) unsigned short As[128 * 72];
  __shared__ __align__(16) unsigned short Bs[128 * 72];
  const int t = threadIdx.x;
  const int m0 = blockIdx.y << 7;
  const int n0 = blockIdx.x << 7;
  const int w = t >> 6, lane = t & 63;
  const int wm = (w >> 1) * 64, wn = (w & 1) * 64;
  const int qd = lane >> 4, m = lane & 15;

  vf4 acc[4][4];
#pragma unroll
  for (int i = 0; i < 4; ++i)
#pragma unroll
    for (int j = 0; j < 4; ++j) acc[i][j] = vzero();

  for (int k0 = 0; k0 < 1024; k0 += 64) {
    __syncthreads();
#pragma unroll
    for (int u2 = 0; u2 < 4; ++u2) {
      const int id = t + (u2 << 8);
      const int row = id >> 3, kg = id & 7;
      vu4 ra = *(const vu4*)(Ab + (size_t)(m0 + row) * 1024 + k0 + kg * 8);
      *(vu4*)&As[row * 72 + kg * 8] = ra;
      vu4 rb = *(const vu4*)(woT + (size_t)(n0 + row) * 1024 + k0 + kg * 8);
      *(vu4*)&Bs[row * 72 + kg * 8] = rb;
    }
    __syncthreads();
#pragma unroll
    for (int ks = 0; ks < 2; ++ks) {
      short8 af[4], bf[4];
#pragma unroll
      for (int i = 0; i < 4; ++i) {
        af[i] = *(const short8*)&As[(wm + i * 16 + m) * 72 + ks * 32 + qd * 8];
        bf[i] = *(const short8*)&Bs[(wn + i * 16 + m) * 72 + ks * 32 + qd * 8];
      }
#pragma unroll
      for (int i = 0; i < 4; ++i)
#pragma unroll
        for (int j = 0; j < 4; ++j)
          acc[i][j] = __builtin_amdgcn_mfma_f32_16x16x32_bf16(af[i], bf[j], acc[i][j], 0, 0, 0);
    }
  }
#pragma unroll
  for (int i = 0; i < 4; ++i)
#pragma unroll
    for (int j = 0; j < 4; ++j)
#pragma unroll
      for (int r = 0; r < 4; ++r) {
        const int grow = m0 + wm + i * 16 + qd * 4 + r;
        const int gcol = n0 + wn + j * 16 + m;
        Y[(size_t)grow * 1024 + gcol] = acc[i][j][r];
      }
}

// ---------------------------------------------------------------------------
// xl = x @ Wgk1 [2048,16] fp32. One wave per row.
// ---------------------------------------------------------------------------
__global__ __launch_bounds__(64)
void lowrank_k(const float* __restrict__ X, const float* __restrict__ W1,
               float* __restrict__ xl) {
  const int row = blockIdx.x;
  const int t = threadIdx.x;
  float acc[16];
#pragma unroll
  for (int c2 = 0; c2 < 16; ++c2) acc[c2] = 0.f;
  const float* xp = X + (size_t)row * 1024 + t * 16;
  float xv[16];
#pragma unroll
  for (int u = 0; u < 4; ++u)
    *(vf4*)&xv[u * 4] = *(const vf4*)(xp + u * 4);
#pragma unroll
  for (int j = 0; j < 16; ++j) {
    const float* wp = W1 + (size_t)(t * 16 + j) * 16;
    float wv[16];
#pragma unroll
    for (int u = 0; u < 4; ++u)
      *(vf4*)&wv[u * 4] = *(const vf4*)(wp + u * 4);
#pragma unroll
    for (int c2 = 0; c2 < 16; ++c2) acc[c2] = fmaf(xv[j], wv[c2], acc[c2]);
  }
#pragma unroll
  for (int mm = 1; mm < 64; mm <<= 1) {
#pragma unroll
    for (int c2 = 0; c2 < 16; ++c2) acc[c2] += __shfl_xor(acc[c2], mm, 64);
  }
  if (t == 0) {
#pragma unroll
    for (int c2 = 0; c2 < 16; ++c2) xl[(size_t)row * 16 + c2] = acc[c2];
  }
}

// ---------------------------------------------------------------------------
// Fused gate + wave-parallel scan + q/k scaling (bf16 RMW).
// One wave per (b,chunk,kcol); lane i = row i. grid 4096 x 256.
// ---------------------------------------------------------------------------
__global__ __launch_bounds__(256)
void gate_scan_k(const float* __restrict__ xl, const float* __restrict__ W2,
                 const float* __restrict__ bias,
                 unsigned short* __restrict__ q, unsigned short* __restrict__ k,
                 float* __restrict__ ebtot) {
  const int t = threadIdx.x;
  const int w = t >> 6, lane = t & 63;
  const int wid = blockIdx.x * 4 + w;     // 0..16383
  const int kcol = wid & 511;
  const int c = (wid >> 9) & 15;
  const int b = wid >> 13;
  const size_t rowbase = (size_t)b * 1024 + c * 64;

  const float* xp = xl + (rowbase + lane) * 16;
  float xv[16];
#pragma unroll
  for (int u = 0; u < 4; ++u)
    *(vf4*)&xv[u * 4] = *(const vf4*)(xp + u * 4);
  float z = bias[kcol];
#pragma unroll
  for (int r = 0; r < 16; ++r) z = fmaf(xv[r], W2[r * 512 + kcol], z);
  float ls = fminf(z, 0.f) - log1pf(expf(-fabsf(z)));
  float g = fmaxf(ls * (1.f / 16.f), -3.f);

#pragma unroll
  for (int d = 1; d < 64; d <<= 1) {
    float up = __shfl_up(g, d, 64);
    if (lane >= d) g += up;
  }

  const size_t a = (rowbase + lane) * 512 + kcol;
  float qv = bf2f((unsigned int)q[a]) * expf(g);
  float kv = bf2f((unsigned int)k[a]) * expf(fminf(-g, 80.f));
  q[a] = f2bf(qv);
  k[a] = f2bf(kv);
  if (lane == 63)
    ebtot[((size_t)b * 16 + c) * 512 + kcol] = expf(g);
}

// ---------------------------------------------------------------------------
// Fused intra-chunk: A = tril(Q~K~^T) via MFMA (A in LDS), o_intra = A@V via
// VALU. grid (vh2, chunk16, bh8) = 256 blocks.
// ---------------------------------------------------------------------------
__global__ __launch_bounds__(256)
void intra_k(const unsigned short* __restrict__ q16, const unsigned short* __restrict__ k16,
             const unsigned short* __restrict__ v, float* __restrict__ o) {
  __shared__ __align__(16) unsigned short Qs[64 * 136];
  __shared__ __align__(16) unsigned short Ks[64 * 136];
  __shared__ float As[64 * 68];
  __shared__ float Vs[64 * 64];
  const int t = threadIdx.x;
  const int vh = blockIdx.x, c = blockIdx.y, bh = blockIdx.z;
  const int b = bh >> 2, h = bh & 3;
  const size_t rowbase = (size_t)b * 1024 + c * 64;

#pragma unroll
  for (int u2 = 0; u2 < 4; ++u2) {
    const int id = t + (u2 << 8);
    const int row = id >> 4, kg = id & 15;
    *(vu4*)&Qs[row * 136 + kg * 8] =
        *(const vu4*)(q16 + (rowbase + row) * 512 + h * 128 + kg * 8);
    *(vu4*)&Ks[row * 136 + kg * 8] =
        *(const vu4*)(k16 + (rowbase + row) * 512 + h * 128 + kg * 8);
  }
  __syncthreads();

  {
    const int w = t >> 6, lane = t & 63;
    const int qd = lane >> 4, m = lane & 15;
    short8 af[4];
#pragma unroll
    for (int kf = 0; kf < 4; ++kf)
      af[kf] = *(const short8*)&Qs[(w * 16 + m) * 136 + kf * 32 + qd * 8];
    vf4 acc[4];
#pragma unroll
    for (int jt = 0; jt < 4; ++jt) acc[jt] = vzero();
#pragma unroll
    for (int jt = 0; jt < 4; ++jt)
#pragma unroll
      for (int kf = 0; kf < 4; ++kf) {
        short8 bfr = *(const short8*)&Ks[(jt * 16 + m) * 136 + kf * 32 + qd * 8];
        acc[jt] = __builtin_amdgcn_mfma_f32_16x16x32_bf16(af[kf], bfr, acc[jt], 0, 0, 0);
      }
#pragma unroll
    for (int jt = 0; jt < 4; ++jt)
#pragma unroll
      for (int r = 0; r < 4; ++r) {
        const int i = w * 16 + qd * 4 + r;
        const int j = jt * 16 + m;
        As[i * 68 + j] = (j <= i) ? acc[jt][r] : 0.f;
      }
  }

  const int i2 = t >> 2, sb = t & 3;
  for (int p = 0; p < 2; ++p) {
    const int vt = vh * 2 + p;
    __syncthreads();
    {
      const int r = t >> 2, s = t & 3;
      const unsigned short* vp = v + (rowbase + r) * 1024 + h * 256 + vt * 64 + s * 16;
      float f[16];
      unpack16(vp, f);
#pragma unroll
      for (int u = 0; u < 16; ++u) Vs[r * 64 + s * 16 + u] = f[u];
    }
    __syncthreads();
    vf4 acc[4];
#pragma unroll
    for (int u = 0; u < 4; ++u) acc[u] = vzero();
    for (int jj = 0; jj < 64; ++jj) {
      const float a = As[i2 * 68 + jj];
#pragma unroll
      for (int u = 0; u < 4; ++u)
        acc[u] += a * *(const vf4*)&Vs[jj * 64 + sb * 16 + u * 4];
    }
    float* op = o + (rowbase + i2) * 1024 + h * 256 + vt * 64 + sb * 16;
#pragma unroll
    for (int u = 0; u < 4; ++u) *(vf4*)(op + u * 4) = acc[u];
  }
}

// ---------------------------------------------------------------------------
// KV^T_c = (K~^T V)^T stored [v][k] bf16. grid (vt4, chunk16, bh8).
// ---------------------------------------------------------------------------
__global__ __launch_bounds__(256)
void kv_k(const unsigned short* __restrict__ k16, const unsigned short* __restrict__ v,
          unsigned short* __restrict__ ST) {
  __shared__ float Ks[64 * 128];
  __shared__ float Vs[64 * 64];
  const int t = threadIdx.x;
  const int vt = blockIdx.x, c = blockIdx.y, bh = blockIdx.z;
  const int b = bh >> 2, h = bh & 3;
  const size_t rowbase = (size_t)b * 1024 + c * 64;
  {
    const int r = t >> 2, s = t & 3;
    const unsigned short* kp = k16 + (rowbase + r) * 512 + h * 128 + s * 32;
    float fk[32];
    unpack16(kp, fk);
    unpack16(kp + 16, fk + 16);
#pragma unroll
    for (int u = 0; u < 8; ++u)
      *(vf4*)&Ks[r * 128 + s * 32 + u * 4] = *(const vf4*)&fk[u * 4];
    const unsigned short* vp = v + (rowbase + r) * 1024 + h * 256 + vt * 64 + s * 16;
    float f[16];
    unpack16(vp, f);
#pragma unroll
    for (int u = 0; u < 16; ++u) Vs[r * 64 + s * 16 + u] = f[u];
  }
  __syncthreads();
  const int kk = t >> 1, half = t & 1;
  float su[32];
#pragma unroll
  for (int u = 0; u < 32; ++u) su[u] = 0.f;
  for (int j = 0; j < 64; ++j) {
    const float kv = Ks[j * 128 + kk];
    const float* vrow = &Vs[j * 64 + half * 32];
#pragma unroll
    for (int u = 0; u < 32; ++u) su[u] = fmaf(kv, vrow[u], su[u]);
  }
  unsigned short* Sp = ST + ((size_t)(bh * 16 + c) * 256 + vt * 64 + half * 32) * 128 + kk;
#pragma unroll
  for (int u = 0; u < 32; ++u)
    Sp[(size_t)u * 128] = f2bf(su[u]);
}

// ---------------------------------------------------------------------------
// State scan in place on bf16 ST[v][k]; fp32 carry; per-k decay vector.
// ---------------------------------------------------------------------------
__global__ __launch_bounds__(256)
void state_scan_k(unsigned short* __restrict__ ST, const float* __restrict__ ebtot) {
  const int idx = blockIdx.x * 256 + threadIdx.x;  // 0..32767
  const int kg = idx & 15;
  const int vv = (idx >> 4) & 255;
  const int bh = idx >> 12;
  const int b = bh >> 2, h = bh & 3;
  float s[8];
#pragma unroll
  for (int u = 0; u < 8; ++u) s[u] = 0.f;
  for (int c = 0; c < 16; ++c) {
    unsigned short* p = ST + ((size_t)(bh * 16 + c) * 256 + vv) * 128 + kg * 8;
    const float* ep = ebtot + ((size_t)b * 16 + c) * 512 + h * 128 + kg * 8;
    float e[8];
    *(vf4*)&e[0] = *(const vf4*)ep;
    *(vf4*)&e[4] = *(const vf4*)(ep + 4);
    float kv[8];
    unpack8(*(const vu4*)p, kv);
    *(vu4*)p = pack8(s);
#pragma unroll
    for (int u = 0; u < 8; ++u) s[u] = (s[u] + kv[u]) * e[u];
  }
}

// ---------------------------------------------------------------------------
// o += Q~ @ S_c via MFMA. grid (vt2, chunk16, bh8) = 256 blocks.
// ---------------------------------------------------------------------------
__global__ __launch_bounds__(256)
void o_inter_k(const unsigned short* __restrict__ q16, const unsigned short* __restrict__ ST,
               float* __restrict__ o) {
  __shared__ __align__(16) unsigned short Qs[64 * 136];
  __shared__ __align__(16) unsigned short Ss[128 * 136];
  const int t = threadIdx.x;
  const int vt = blockIdx.x, c = blockIdx.y, bh = blockIdx.z;
  const int b = bh >> 2, h = bh & 3;
  const size_t rowbase = (size_t)b * 1024 + c * 64;

#pragma unroll
  for (int u2 = 0; u2 < 4; ++u2) {
    const int id = t + (u2 << 8);
    const int row = id >> 4, kg = id & 15;
    *(vu4*)&Qs[row * 136 + kg * 8] =
        *(const vu4*)(q16 + (rowbase + row) * 512 + h * 128 + kg * 8);
  }
#pragma unroll
  for (int u2 = 0; u2 < 8; ++u2) {
    const int id = t + (u2 << 8);
    const int vrow = id >> 4, kg = id & 15;
    *(vu4*)&Ss[vrow * 136 + kg * 8] =
        *(const vu4*)(ST + ((size_t)(bh * 16 + c) * 256 + vt * 128 + vrow) * 128 + kg * 8);
  }
  __syncthreads();

  const int w = t >> 6, lane = t & 63;
  const int qd = lane >> 4, m = lane & 15;
  short8 af[4];
#pragma unroll
  for (int kf = 0; kf < 4; ++kf)
    af[kf] = *(const short8*)&Qs[(w * 16 + m) * 136 + kf * 32 + qd * 8];
#pragma unroll
  for (int nt = 0; nt < 8; ++nt) {
    vf4 acc = vzero();
#pragma unroll
    for (int kf = 0; kf < 4; ++kf) {
      short8 bfr = *(const short8*)&Ss[(nt * 16 + m) * 136 + kf * 32 + qd * 8];
      acc = __builtin_amdgcn_mfma_f32_16x16x32_bf16(af[kf], bfr, acc, 0, 0, 0);
    }
    float* base = o + (rowbase + w * 16 + qd * 4) * 1024 + h * 256 + vt * 128 + nt * 16 + m;
#pragma unroll
    for (int r = 0; r < 4; ++r)
      base[(size_t)r * 1024] += acc[r];
  }
}

// ---------------------------------------------------------------------------
// RMSNorm over DV=256 + silu-gate; obuf fp32 -> obuf_b bf16.
// ---------------------------------------------------------------------------
__global__ __launch_bounds__(256)
void norm_gate_k(const float* __restrict__ o, const float* __restrict__ rmsw,
                 const unsigned short* __restrict__ sg,
                 unsigned short* __restrict__ ob) {
  __shared__ float red[4];
  const int grp = blockIdx.x;          // 0..8191
  const int row = grp >> 2, h = grp & 3;
  const int t = threadIdx.x;
  const size_t idx = (size_t)row * 1024 + h * 256 + t;
  const float val = o[idx];
  float ss = val * val;
#pragma unroll
  for (int mm = 1; mm < 64; mm <<= 1) ss += __shfl_xor(ss, mm, 64);
  if ((t & 63) == 0) red[t >> 6] = ss;
  __syncthreads();
  const float tot = red[0] + red[1] + red[2] + red[3];
  const float scale = rsqrtf(tot * (1.f / 256.f) + 1e-5f);
  ob[idx] = f2bf(val * scale * rmsw[t] * bf2f((unsigned int)sg[idx]));
}

// ---------------------------------------------------------------------------
extern "C" void kernel_launch(void* const* d_in, const int* in_sizes, int n_in,
                              void* d_out, int out_size, void* d_ws, size_t ws_size,
                              hipStream_t stream) {
  const float* x    = (const float*)d_in[0];
  const float* Wq   = (const float*)d_in[1];
  const float* Wk   = (const float*)d_in[2];
  const float* Wv   = (const float*)d_in[3];
  const float* Wg   = (const float*)d_in[4];
  const float* Wgk1 = (const float*)d_in[5];
  const float* Wgk2 = (const float*)d_in[6];
  const float* bgk2 = (const float*)d_in[7];
  const float* Wout = (const float*)d_in[8];
  const float* rmsw = (const float*)d_in[9];

  // Workspace (~37 MB, byte offsets)
  const size_t MB = 1u << 20;
  char* w = (char*)d_ws;
  unsigned short* qb16   = (unsigned short*)(w);           // [0,2) MB bf16
  unsigned short* kb16   = (unsigned short*)(w + 2 * MB);  // [2,4)
  unsigned short* vbuf   = (unsigned short*)(w + 4 * MB);  // [4,8)
  unsigned short* sgbuf  = (unsigned short*)(w + 8 * MB);  // [8,12)
  float*          obuf   = (float*)(w + 12 * MB);          // [12,20) fp32
  char*           sreg   = w + 20 * MB;                    // [20,28) multi-phase
  unsigned short* xb     = (unsigned short*)sreg;          //   phase 0: 4 MB (prep->proj)
  unsigned short* STbuf  = (unsigned short*)sreg;          //   phase A: 8 MB [v][k]
  unsigned short* obuf_b = (unsigned short*)sreg;          //   phase B: 4 MB
  float*          xlbuf  = (float*)(w + 28 * MB);          // 128 KB
  float*          ebbuf  = (float*)(w + 28 * MB + 131072); // 64 KB
  unsigned short* wqT    = (unsigned short*)(w + 29 * MB); // 1 MB
  unsigned short* wkT    = (unsigned short*)(w + 30 * MB); // 1 MB
  unsigned short* wvT    = (unsigned short*)(w + 31 * MB); // 2 MB
  unsigned short* wgT    = (unsigned short*)(w + 33 * MB); // 2 MB
  unsigned short* woT    = (unsigned short*)(w + 35 * MB); // 2 MB

  prep_k<<<dim3(96, 16), 256, 0, stream>>>(Wq, Wk, Wv, Wg, Wout, x,
                                           wqT, wkT, wvT, wgT, woT, xb);
  lowrank_k<<<2048, 64, 0, stream>>>(x, Wgk1, xlbuf);
  proj_mfma_k<<<dim3(24, 16), 256, 0, stream>>>(xb, wqT, wkT, wvT, wgT, qb16, kb16, vbuf, sgbuf);
  gate_scan_k<<<4096, 256, 0, stream>>>(xlbuf, Wgk2, bgk2, qb16, kb16, ebbuf);
  intra_k<<<dim3(2, 16, 8), 256, 0, stream>>>(qb16, kb16, vbuf, obuf);
  kv_k<<<dim3(4, 16, 8), 256, 0, stream>>>(kb16, vbuf, STbuf);
  state_scan_k<<<128, 256, 0, stream>>>(STbuf, ebbuf);
  o_inter_k<<<dim3(2, 16, 8), 256, 0, stream>>>(qb16, STbuf, obuf);
  norm_gate_k<<<8192, 256, 0, stream>>>(obuf, rmsw, sgbuf, obuf_b);
  out_mfma_k<<<dim3(8, 16), 256, 0, stream>>>(obuf_b, woT, (float*)d_out);
}

// Round 9
// 209.327 us; speedup vs baseline: 3.9343x; 1.0811x over previous
//
#include <hip/hip_runtime.h>
#include <math.h>

// GLA: B=2, N=1024, D=1024, H=4, KD=512, VD=1024, DK=128, DV=256, LR=16
// Round 9: intra_k + kv_k fused into intra_kv_k, all-MFMA:
//   A = tril(QK^T) (MFMA) -> Asb bf16 in LDS
//   o_intra = A @ V (MFMA, B-frag from transposed Vt)
//   ST = V^T @ K  (MFMA, A-frag Vt / B-frag transposed Kt)
// LDS 78.3 KB -> 2 blocks/CU. 9 kernels. Workspace ~37 MB.

typedef __attribute__((ext_vector_type(4))) float vf4;
typedef __attribute__((ext_vector_type(4))) unsigned int vu4;
typedef __attribute__((ext_vector_type(8))) short short8;

#define DEVI static __device__ __forceinline__
DEVI vf4 vzero() { vf4 x = {0.f, 0.f, 0.f, 0.f}; return x; }

DEVI float bf2f(unsigned int u) {
  union { unsigned int i; float f; } c; c.i = u << 16; return c.f;
}
DEVI unsigned short f2bf(float f) {
  union { float f; unsigned int i; } c; c.f = f;
  unsigned int i = c.i;
  return (unsigned short)((i + 0x7fffu + ((i >> 16) & 1u)) >> 16);
}
DEVI void unpack8(vu4 r, float* f) {
  f[0] = bf2f(r.x & 0xffffu); f[1] = bf2f(r.x >> 16);
  f[2] = bf2f(r.y & 0xffffu); f[3] = bf2f(r.y >> 16);
  f[4] = bf2f(r.z & 0xffffu); f[5] = bf2f(r.z >> 16);
  f[6] = bf2f(r.w & 0xffffu); f[7] = bf2f(r.w >> 16);
}
DEVI vu4 pack8(const float* f) {
  vu4 o;
  o.x = (unsigned int)f2bf(f[0]) | ((unsigned int)f2bf(f[1]) << 16);
  o.y = (unsigned int)f2bf(f[2]) | ((unsigned int)f2bf(f[3]) << 16);
  o.z = (unsigned int)f2bf(f[4]) | ((unsigned int)f2bf(f[5]) << 16);
  o.w = (unsigned int)f2bf(f[6]) | ((unsigned int)f2bf(f[7]) << 16);
  return o;
}

// ---------------------------------------------------------------------------
// prep_k: ct<64 -> weight transpose+convert; ct>=64 -> x fp32->bf16.
// grid (96,16).
// ---------------------------------------------------------------------------
__global__ __launch_bounds__(256)
void prep_k(const float* __restrict__ Wq, const float* __restrict__ Wk,
            const float* __restrict__ Wv, const float* __restrict__ Wg,
            const float* __restrict__ Wo, const float* __restrict__ X,
            unsigned short* __restrict__ wqT, unsigned short* __restrict__ wkT,
            unsigned short* __restrict__ wvT, unsigned short* __restrict__ wgT,
            unsigned short* __restrict__ woT, unsigned short* __restrict__ xb) {
  __shared__ float T[64][65];
  const int ct = blockIdx.x, kt = blockIdx.y;
  const int t = threadIdx.x;
  const int r = t >> 2, s = t & 3;
  if (ct >= 64) {
    const int rt = ct - 64;
    const size_t base = (size_t)(rt * 64 + r) * 1024 + kt * 64 + s * 16;
    float f[16];
    *(vf4*)&f[0]  = *(const vf4*)(X + base);
    *(vf4*)&f[4]  = *(const vf4*)(X + base + 4);
    *(vf4*)&f[8]  = *(const vf4*)(X + base + 8);
    *(vf4*)&f[12] = *(const vf4*)(X + base + 12);
    *(vu4*)(xb + base) = pack8(f);
    *(vu4*)(xb + base + 8) = pack8(f + 8);
    return;
  }
  const float* W; unsigned short* O; int N; int cb;
  if (ct < 8)       { W = Wq; O = wqT; N = 512;  cb = ct; }
  else if (ct < 16) { W = Wk; O = wkT; N = 512;  cb = ct - 8; }
  else if (ct < 32) { W = Wv; O = wvT; N = 1024; cb = ct - 16; }
  else if (ct < 48) { W = Wg; O = wgT; N = 1024; cb = ct - 32; }
  else              { W = Wo; O = woT; N = 1024; cb = ct - 48; }
  const float* src = W + (size_t)(kt * 64 + r) * N + cb * 64 + s * 16;
#pragma unroll
  for (int u = 0; u < 4; ++u) {
    vf4 v4 = *(const vf4*)(src + u * 4);
    T[r][s * 16 + u * 4 + 0] = v4.x;
    T[r][s * 16 + u * 4 + 1] = v4.y;
    T[r][s * 16 + u * 4 + 2] = v4.z;
    T[r][s * 16 + u * 4 + 3] = v4.w;
  }
  __syncthreads();
  unsigned int pk[8];
#pragma unroll
  for (int u = 0; u < 8; ++u) {
    unsigned int lo = f2bf(T[s * 16 + 2 * u][r]);
    unsigned int hi = f2bf(T[s * 16 + 2 * u + 1][r]);
    pk[u] = lo | (hi << 16);
  }
  unsigned short* dst = O + (size_t)(cb * 64 + r) * 1024 + kt * 64 + s * 16;
  *(vu4*)dst = *(vu4*)&pk[0];
  *(vu4*)(dst + 8) = *(vu4*)&pk[4];
}

// ---------------------------------------------------------------------------
// MFMA projection: xb bf16 @ WT bf16 -> q,k,v,sg(silu) bf16. grid (24,16).
// ---------------------------------------------------------------------------
__global__ __launch_bounds__(256)
void proj_mfma_k(const unsigned short* __restrict__ xb,
                 const unsigned short* __restrict__ wqT, const unsigned short* __restrict__ wkT,
                 const unsigned short* __restrict__ wvT, const unsigned short* __restrict__ wgT,
                 unsigned short* __restrict__ qb, unsigned short* __restrict__ kb,
                 unsigned short* __restrict__ vb, unsigned short* __restrict__ sgb) {
  __shared__ __align__(16) unsigned short As[128 * 72];
  __shared__ __align__(16) unsigned short Bs[128 * 72];
  const int t = threadIdx.x;
  const int m0 = blockIdx.y << 7;
  const int nt = blockIdx.x;
  const unsigned short* WT; int n0; int kind;
  if (nt < 4)       { WT = wqT; n0 = nt * 128;        kind = 0; }
  else if (nt < 8)  { WT = wkT; n0 = (nt - 4) * 128;  kind = 1; }
  else if (nt < 16) { WT = wvT; n0 = (nt - 8) * 128;  kind = 2; }
  else              { WT = wgT; n0 = (nt - 16) * 128; kind = 3; }

  const int w = t >> 6, lane = t & 63;
  const int wm = (w >> 1) * 64, wn = (w & 1) * 64;
  const int qd = lane >> 4, m = lane & 15;

  vf4 acc[4][4];
#pragma unroll
  for (int i = 0; i < 4; ++i)
#pragma unroll
    for (int j = 0; j < 4; ++j) acc[i][j] = vzero();

  for (int k0 = 0; k0 < 1024; k0 += 64) {
    __syncthreads();
#pragma unroll
    for (int u2 = 0; u2 < 4; ++u2) {
      const int id = t + (u2 << 8);
      const int row = id >> 3, kg = id & 7;
      vu4 ra = *(const vu4*)(xb + (size_t)(m0 + row) * 1024 + k0 + kg * 8);
      *(vu4*)&As[row * 72 + kg * 8] = ra;
      vu4 rb = *(const vu4*)(WT + (size_t)(n0 + row) * 1024 + k0 + kg * 8);
      *(vu4*)&Bs[row * 72 + kg * 8] = rb;
    }
    __syncthreads();
#pragma unroll
    for (int ks = 0; ks < 2; ++ks) {
      short8 af[4], bf[4];
#pragma unroll
      for (int i = 0; i < 4; ++i) {
        af[i] = *(const short8*)&As[(wm + i * 16 + m) * 72 + ks * 32 + qd * 8];
        bf[i] = *(const short8*)&Bs[(wn + i * 16 + m) * 72 + ks * 32 + qd * 8];
      }
#pragma unroll
      for (int i = 0; i < 4; ++i)
#pragma unroll
        for (int j = 0; j < 4; ++j)
          acc[i][j] = __builtin_amdgcn_mfma_f32_16x16x32_bf16(af[i], bf[j], acc[i][j], 0, 0, 0);
    }
  }
#pragma unroll
  for (int i = 0; i < 4; ++i) {
#pragma unroll
    for (int j = 0; j < 4; ++j) {
#pragma unroll
      for (int r = 0; r < 4; ++r) {
        const int grow = m0 + wm + i * 16 + qd * 4 + r;
        const int gcol = n0 + wn + j * 16 + m;
        float val = acc[i][j][r];
        if (kind == 0)      qb[(size_t)grow * 512 + gcol] = f2bf(val);
        else if (kind == 1) kb[(size_t)grow * 512 + gcol] = f2bf(val);
        else if (kind == 2) vb[(size_t)grow * 1024 + gcol] = f2bf(val);
        else {
          val = val / (1.f + expf(-val));
          sgb[(size_t)grow * 1024 + gcol] = f2bf(val);
        }
      }
    }
  }
}

// ---------------------------------------------------------------------------
// MFMA output GEMM: obuf_b bf16 @ woT -> d_out fp32. grid (8,16).
// ---------------------------------------------------------------------------
__global__ __launch_bounds__(256)
void out_mfma_k(const unsigned short* __restrict__ Ab,
                const unsigned short* __restrict__ woT, float* __restrict__ Y) {
  __shared__ __align__(16) unsigned short As[128 * 72];
  __shared__ __align__(16) unsigned short Bs[128 * 72];
  const int t = threadIdx.x;
  const int m0 = blockIdx.y << 7;
  const int n0 = blockIdx.x << 7;
  const int w = t >> 6, lane = t & 63;
  const int wm = (w >> 1) * 64, wn = (w & 1) * 64;
  const int qd = lane >> 4, m = lane & 15;

  vf4 acc[4][4];
#pragma unroll
  for (int i = 0; i < 4; ++i)
#pragma unroll
    for (int j = 0; j < 4; ++j) acc[i][j] = vzero();

  for (int k0 = 0; k0 < 1024; k0 += 64) {
    __syncthreads();
#pragma unroll
    for (int u2 = 0; u2 < 4; ++u2) {
      const int id = t + (u2 << 8);
      const int row = id >> 3, kg = id & 7;
      vu4 ra = *(const vu4*)(Ab + (size_t)(m0 + row) * 1024 + k0 + kg * 8);
      *(vu4*)&As[row * 72 + kg * 8] = ra;
      vu4 rb = *(const vu4*)(woT + (size_t)(n0 + row) * 1024 + k0 + kg * 8);
      *(vu4*)&Bs[row * 72 + kg * 8] = rb;
    }
    __syncthreads();
#pragma unroll
    for (int ks = 0; ks < 2; ++ks) {
      short8 af[4], bf[4];
#pragma unroll
      for (int i = 0; i < 4; ++i) {
        af[i] = *(const short8*)&As[(wm + i * 16 + m) * 72 + ks * 32 + qd * 8];
        bf[i] = *(const short8*)&Bs[(wn + i * 16 + m) * 72 + ks * 32 + qd * 8];
      }
#pragma unroll
      for (int i = 0; i < 4; ++i)
#pragma unroll
        for (int j = 0; j < 4; ++j)
          acc[i][j] = __builtin_amdgcn_mfma_f32_16x16x32_bf16(af[i], bf[j], acc[i][j], 0, 0, 0);
    }
  }
#pragma unroll
  for (int i = 0; i < 4; ++i)
#pragma unroll
    for (int j = 0; j < 4; ++j)
#pragma unroll
      for (int r = 0; r < 4; ++r) {
        const int grow = m0 + wm + i * 16 + qd * 4 + r;
        const int gcol = n0 + wn + j * 16 + m;
        Y[(size_t)grow * 1024 + gcol] = acc[i][j][r];
      }
}

// ---------------------------------------------------------------------------
// xl = x @ Wgk1 [2048,16] fp32. One wave per row.
// ---------------------------------------------------------------------------
__global__ __launch_bounds__(64)
void lowrank_k(const float* __restrict__ X, const float* __restrict__ W1,
               float* __restrict__ xl) {
  const int row = blockIdx.x;
  const int t = threadIdx.x;
  float acc[16];
#pragma unroll
  for (int c2 = 0; c2 < 16; ++c2) acc[c2] = 0.f;
  const float* xp = X + (size_t)row * 1024 + t * 16;
  float xv[16];
#pragma unroll
  for (int u = 0; u < 4; ++u)
    *(vf4*)&xv[u * 4] = *(const vf4*)(xp + u * 4);
#pragma unroll
  for (int j = 0; j < 16; ++j) {
    const float* wp = W1 + (size_t)(t * 16 + j) * 16;
    float wv[16];
#pragma unroll
    for (int u = 0; u < 4; ++u)
      *(vf4*)&wv[u * 4] = *(const vf4*)(wp + u * 4);
#pragma unroll
    for (int c2 = 0; c2 < 16; ++c2) acc[c2] = fmaf(xv[j], wv[c2], acc[c2]);
  }
#pragma unroll
  for (int mm = 1; mm < 64; mm <<= 1) {
#pragma unroll
    for (int c2 = 0; c2 < 16; ++c2) acc[c2] += __shfl_xor(acc[c2], mm, 64);
  }
  if (t == 0) {
#pragma unroll
    for (int c2 = 0; c2 < 16; ++c2) xl[(size_t)row * 16 + c2] = acc[c2];
  }
}

// ---------------------------------------------------------------------------
// Fused gate + wave-parallel scan + q/k scaling (bf16 RMW). grid 4096 x 256.
// ---------------------------------------------------------------------------
__global__ __launch_bounds__(256)
void gate_scan_k(const float* __restrict__ xl, const float* __restrict__ W2,
                 const float* __restrict__ bias,
                 unsigned short* __restrict__ q, unsigned short* __restrict__ k,
                 float* __restrict__ ebtot) {
  const int t = threadIdx.x;
  const int w = t >> 6, lane = t & 63;
  const int wid = blockIdx.x * 4 + w;
  const int kcol = wid & 511;
  const int c = (wid >> 9) & 15;
  const int b = wid >> 13;
  const size_t rowbase = (size_t)b * 1024 + c * 64;

  const float* xp = xl + (rowbase + lane) * 16;
  float xv[16];
#pragma unroll
  for (int u = 0; u < 4; ++u)
    *(vf4*)&xv[u * 4] = *(const vf4*)(xp + u * 4);
  float z = bias[kcol];
#pragma unroll
  for (int r = 0; r < 16; ++r) z = fmaf(xv[r], W2[r * 512 + kcol], z);
  float ls = fminf(z, 0.f) - log1pf(expf(-fabsf(z)));
  float g = fmaxf(ls * (1.f / 16.f), -3.f);

#pragma unroll
  for (int d = 1; d < 64; d <<= 1) {
    float up = __shfl_up(g, d, 64);
    if (lane >= d) g += up;
  }

  const size_t a = (rowbase + lane) * 512 + kcol;
  float qv = bf2f((unsigned int)q[a]) * expf(g);
  float kv = bf2f((unsigned int)k[a]) * expf(fminf(-g, 80.f));
  q[a] = f2bf(qv);
  k[a] = f2bf(kv);
  if (lane == 63)
    ebtot[((size_t)b * 16 + c) * 512 + kcol] = expf(g);
}

// ---------------------------------------------------------------------------
// Fused intra+kv, all-MFMA. grid (vh2, chunk16, bh8) = 256 blocks.
// Phase 1: A = tril(QK^T) -> Asb bf16 (LDS).
// Phase 2: o_intra = A @ V  (B-frag from transposed Vt).
// Phase 3: ST[v][k] = V^T @ K (A-frag Vt, B-frag transposed Kt).
// LDS: Qs 17.4K + Ks 17.4K + Kt 17.4K + Vt 17.4K + Asb 8.7K = 78.3 KB.
// ---------------------------------------------------------------------------
__global__ __launch_bounds__(256)
void intra_kv_k(const unsigned short* __restrict__ q16, const unsigned short* __restrict__ k16,
                const unsigned short* __restrict__ v, float* __restrict__ o,
                unsigned short* __restrict__ ST) {
  __shared__ __align__(16) unsigned short Qs[64 * 136];
  __shared__ __align__(16) unsigned short Ks[64 * 136];
  __shared__ __align__(16) unsigned short Kt[128 * 68];  // [k][j]
  __shared__ __align__(16) unsigned short Vt[128 * 68];  // [v-half][j]
  __shared__ __align__(16) unsigned short Asb[64 * 68];  // bf16 masked A
  const int t = threadIdx.x;
  const int vh = blockIdx.x, c = blockIdx.y, bh = blockIdx.z;
  const int b = bh >> 2, h = bh & 3;
  const size_t rowbase = (size_t)b * 1024 + c * 64;

  // stage Q,K natural; K,V transposed
#pragma unroll
  for (int u2 = 0; u2 < 4; ++u2) {
    const int id = t + (u2 << 8);
    const int row = id >> 4, kg = id & 15;
    vu4 rq = *(const vu4*)(q16 + (rowbase + row) * 512 + h * 128 + kg * 8);
    *(vu4*)&Qs[row * 136 + kg * 8] = rq;
    vu4 rk = *(const vu4*)(k16 + (rowbase + row) * 512 + h * 128 + kg * 8);
    *(vu4*)&Ks[row * 136 + kg * 8] = rk;
    const unsigned short* kp = (const unsigned short*)&rk;
#pragma unroll
    for (int u = 0; u < 8; ++u)
      Kt[(kg * 8 + u) * 68 + row] = kp[u];
    vu4 rv = *(const vu4*)(v + (rowbase + row) * 1024 + h * 256 + vh * 128 + kg * 8);
    const unsigned short* vp = (const unsigned short*)&rv;
#pragma unroll
    for (int u = 0; u < 8; ++u)
      Vt[(kg * 8 + u) * 68 + row] = vp[u];
  }
  __syncthreads();

  const int w = t >> 6, lane = t & 63;
  const int qd = lane >> 4, m = lane & 15;

  // phase 1: A = tril(Q K^T); wave w -> rows w*16..+15
  {
    short8 af[4];
#pragma unroll
    for (int kf = 0; kf < 4; ++kf)
      af[kf] = *(const short8*)&Qs[(w * 16 + m) * 136 + kf * 32 + qd * 8];
    vf4 acc[4];
#pragma unroll
    for (int jt = 0; jt < 4; ++jt) acc[jt] = vzero();
#pragma unroll
    for (int jt = 0; jt < 4; ++jt)
#pragma unroll
      for (int kf = 0; kf < 4; ++kf) {
        short8 bfr = *(const short8*)&Ks[(jt * 16 + m) * 136 + kf * 32 + qd * 8];
        acc[jt] = __builtin_amdgcn_mfma_f32_16x16x32_bf16(af[kf], bfr, acc[jt], 0, 0, 0);
      }
#pragma unroll
    for (int jt = 0; jt < 4; ++jt)
#pragma unroll
      for (int r = 0; r < 4; ++r) {
        const int i = w * 16 + qd * 4 + r;
        const int j = jt * 16 + m;
        Asb[i * 68 + j] = f2bf((j <= i) ? acc[jt][r] : 0.f);
      }
  }
  __syncthreads();

  // phase 2: o_intra = A @ V  (M=64 i, N=128 v-half, K=64 j); wave w -> v w*32..+32
  {
    vf4 acc2[4][2];
#pragma unroll
    for (int mt = 0; mt < 4; ++mt) { acc2[mt][0] = vzero(); acc2[mt][1] = vzero(); }
#pragma unroll
    for (int kf = 0; kf < 2; ++kf) {
      short8 bf0 = *(const short8*)&Vt[(w * 32 + m) * 68 + kf * 32 + qd * 8];
      short8 bf1 = *(const short8*)&Vt[(w * 32 + 16 + m) * 68 + kf * 32 + qd * 8];
#pragma unroll
      for (int mt = 0; mt < 4; ++mt) {
        short8 af = *(const short8*)&Asb[(mt * 16 + m) * 68 + kf * 32 + qd * 8];
        acc2[mt][0] = __builtin_amdgcn_mfma_f32_16x16x32_bf16(af, bf0, acc2[mt][0], 0, 0, 0);
        acc2[mt][1] = __builtin_amdgcn_mfma_f32_16x16x32_bf16(af, bf1, acc2[mt][1], 0, 0, 0);
      }
    }
#pragma unroll
    for (int mt = 0; mt < 4; ++mt)
#pragma unroll
      for (int nt = 0; nt < 2; ++nt)
#pragma unroll
        for (int r = 0; r < 4; ++r) {
          const int i = mt * 16 + qd * 4 + r;
          const int vc = h * 256 + vh * 128 + w * 32 + nt * 16 + m;
          o[(rowbase + i) * 1024 + vc] = acc2[mt][nt][r];
        }
  }

  // phase 3: ST[v][k] = V^T @ K  (M=128 v-half, N=128 k, K=64 j); wave w -> v w*32..+32
  {
    short8 af3[2][2];
#pragma unroll
    for (int mt = 0; mt < 2; ++mt)
#pragma unroll
      for (int kf = 0; kf < 2; ++kf)
        af3[mt][kf] = *(const short8*)&Vt[(w * 32 + mt * 16 + m) * 68 + kf * 32 + qd * 8];
#pragma unroll
    for (int nt = 0; nt < 8; ++nt) {
      vf4 a0 = vzero(), a1 = vzero();
#pragma unroll
      for (int kf = 0; kf < 2; ++kf) {
        short8 bfr = *(const short8*)&Kt[(nt * 16 + m) * 68 + kf * 32 + qd * 8];
        a0 = __builtin_amdgcn_mfma_f32_16x16x32_bf16(af3[0][kf], bfr, a0, 0, 0, 0);
        a1 = __builtin_amdgcn_mfma_f32_16x16x32_bf16(af3[1][kf], bfr, a1, 0, 0, 0);
      }
      const size_t sbase = (size_t)(bh * 16 + c) * 256 + vh * 128 + w * 32;
#pragma unroll
      for (int r = 0; r < 4; ++r) {
        ST[(sbase + qd * 4 + r) * 128 + nt * 16 + m] = f2bf(a0[r]);
        ST[(sbase + 16 + qd * 4 + r) * 128 + nt * 16 + m] = f2bf(a1[r]);
      }
    }
  }
}

// ---------------------------------------------------------------------------
// State scan in place on bf16 ST[v][k]; fp32 carry; per-k decay vector.
// ---------------------------------------------------------------------------
__global__ __launch_bounds__(256)
void state_scan_k(unsigned short* __restrict__ ST, const float* __restrict__ ebtot) {
  const int idx = blockIdx.x * 256 + threadIdx.x;  // 0..32767
  const int kg = idx & 15;
  const int vv = (idx >> 4) & 255;
  const int bh = idx >> 12;
  const int b = bh >> 2, h = bh & 3;
  float s[8];
#pragma unroll
  for (int u = 0; u < 8; ++u) s[u] = 0.f;
  for (int c = 0; c < 16; ++c) {
    unsigned short* p = ST + ((size_t)(bh * 16 + c) * 256 + vv) * 128 + kg * 8;
    const float* ep = ebtot + ((size_t)b * 16 + c) * 512 + h * 128 + kg * 8;
    float e[8];
    *(vf4*)&e[0] = *(const vf4*)ep;
    *(vf4*)&e[4] = *(const vf4*)(ep + 4);
    float kv[8];
    unpack8(*(const vu4*)p, kv);
    *(vu4*)p = pack8(s);
#pragma unroll
    for (int u = 0; u < 8; ++u) s[u] = (s[u] + kv[u]) * e[u];
  }
}

// ---------------------------------------------------------------------------
// o += Q~ @ S_c via MFMA. grid (vt2, chunk16, bh8) = 256 blocks.
// ---------------------------------------------------------------------------
__global__ __launch_bounds__(256)
void o_inter_k(const unsigned short* __restrict__ q16, const unsigned short* __restrict__ ST,
               float* __restrict__ o) {
  __shared__ __align__(16) unsigned short Qs[64 * 136];
  __shared__ __align__(16) unsigned short Ss[128 * 136];
  const int t = threadIdx.x;
  const int vt = blockIdx.x, c = blockIdx.y, bh = blockIdx.z;
  const int b = bh >> 2, h = bh & 3;
  const size_t rowbase = (size_t)b * 1024 + c * 64;

#pragma unroll
  for (int u2 = 0; u2 < 4; ++u2) {
    const int id = t + (u2 << 8);
    const int row = id >> 4, kg = id & 15;
    *(vu4*)&Qs[row * 136 + kg * 8] =
        *(const vu4*)(q16 + (rowbase + row) * 512 + h * 128 + kg * 8);
  }
#pragma unroll
  for (int u2 = 0; u2 < 8; ++u2) {
    const int id = t + (u2 << 8);
    const int vrow = id >> 4, kg = id & 15;
    *(vu4*)&Ss[vrow * 136 + kg * 8] =
        *(const vu4*)(ST + ((size_t)(bh * 16 + c) * 256 + vt * 128 + vrow) * 128 + kg * 8);
  }
  __syncthreads();

  const int w = t >> 6, lane = t & 63;
  const int qd = lane >> 4, m = lane & 15;
  short8 af[4];
#pragma unroll
  for (int kf = 0; kf < 4; ++kf)
    af[kf] = *(const short8*)&Qs[(w * 16 + m) * 136 + kf * 32 + qd * 8];
#pragma unroll
  for (int nt = 0; nt < 8; ++nt) {
    vf4 acc = vzero();
#pragma unroll
    for (int kf = 0; kf < 4; ++kf) {
      short8 bfr = *(const short8*)&Ss[(nt * 16 + m) * 136 + kf * 32 + qd * 8];
      acc = __builtin_amdgcn_mfma_f32_16x16x32_bf16(af[kf], bfr, acc, 0, 0, 0);
    }
    float* base = o + (rowbase + w * 16 + qd * 4) * 1024 + h * 256 + vt * 128 + nt * 16 + m;
#pragma unroll
    for (int r = 0; r < 4; ++r)
      base[(size_t)r * 1024] += acc[r];
  }
}

// ---------------------------------------------------------------------------
// RMSNorm over DV=256 + silu-gate; obuf fp32 -> obuf_b bf16.
// ---------------------------------------------------------------------------
__global__ __launch_bounds__(256)
void norm_gate_k(const float* __restrict__ o, const float* __restrict__ rmsw,
                 const unsigned short* __restrict__ sg,
                 unsigned short* __restrict__ ob) {
  __shared__ float red[4];
  const int grp = blockIdx.x;
  const int row = grp >> 2, h = grp & 3;
  const int t = threadIdx.x;
  const size_t idx = (size_t)row * 1024 + h * 256 + t;
  const float val = o[idx];
  float ss = val * val;
#pragma unroll
  for (int mm = 1; mm < 64; mm <<= 1) ss += __shfl_xor(ss, mm, 64);
  if ((t & 63) == 0) red[t >> 6] = ss;
  __syncthreads();
  const float tot = red[0] + red[1] + red[2] + red[3];
  const float scale = rsqrtf(tot * (1.f / 256.f) + 1e-5f);
  ob[idx] = f2bf(val * scale * rmsw[t] * bf2f((unsigned int)sg[idx]));
}

// ---------------------------------------------------------------------------
extern "C" void kernel_launch(void* const* d_in, const int* in_sizes, int n_in,
                              void* d_out, int out_size, void* d_ws, size_t ws_size,
                              hipStream_t stream) {
  const float* x    = (const float*)d_in[0];
  const float* Wq   = (const float*)d_in[1];
  const float* Wk   = (const float*)d_in[2];
  const float* Wv   = (const float*)d_in[3];
  const float* Wg   = (const float*)d_in[4];
  const float* Wgk1 = (const float*)d_in[5];
  const float* Wgk2 = (const float*)d_in[6];
  const float* bgk2 = (const float*)d_in[7];
  const float* Wout = (const float*)d_in[8];
  const float* rmsw = (const float*)d_in[9];

  const size_t MB = 1u << 20;
  char* w = (char*)d_ws;
  unsigned short* qb16   = (unsigned short*)(w);           // [0,2) MB bf16
  unsigned short* kb16   = (unsigned short*)(w + 2 * MB);  // [2,4)
  unsigned short* vbuf   = (unsigned short*)(w + 4 * MB);  // [4,8)
  unsigned short* sgbuf  = (unsigned short*)(w + 8 * MB);  // [8,12)
  float*          obuf   = (float*)(w + 12 * MB);          // [12,20) fp32
  char*           sreg   = w + 20 * MB;                    // [20,28) multi-phase
  unsigned short* xb     = (unsigned short*)sreg;          //   phase 0: 4 MB
  unsigned short* STbuf  = (unsigned short*)sreg;          //   phase A: 8 MB [v][k]
  unsigned short* obuf_b = (unsigned short*)sreg;          //   phase B: 4 MB
  float*          xlbuf  = (float*)(w + 28 * MB);          // 128 KB
  float*          ebbuf  = (float*)(w + 28 * MB + 131072); // 64 KB
  unsigned short* wqT    = (unsigned short*)(w + 29 * MB); // 1 MB
  unsigned short* wkT    = (unsigned short*)(w + 30 * MB); // 1 MB
  unsigned short* wvT    = (unsigned short*)(w + 31 * MB); // 2 MB
  unsigned short* wgT    = (unsigned short*)(w + 33 * MB); // 2 MB
  unsigned short* woT    = (unsigned short*)(w + 35 * MB); // 2 MB

  prep_k<<<dim3(96, 16), 256, 0, stream>>>(Wq, Wk, Wv, Wg, Wout, x,
                                           wqT, wkT, wvT, wgT, woT, xb);
  lowrank_k<<<2048, 64, 0, stream>>>(x, Wgk1, xlbuf);
  proj_mfma_k<<<dim3(24, 16), 256, 0, stream>>>(xb, wqT, wkT, wvT, wgT, qb16, kb16, vbuf, sgbuf);
  gate_scan_k<<<4096, 256, 0, stream>>>(xlbuf, Wgk2, bgk2, qb16, kb16, ebbuf);
  intra_kv_k<<<dim3(2, 16, 8), 256, 0, stream>>>(qb16, kb16, vbuf, obuf, STbuf);
  state_scan_k<<<128, 256, 0, stream>>>(STbuf, ebbuf);
  o_inter_k<<<dim3(2, 16, 8), 256, 0, stream>>>(qb16, STbuf, obuf);
  norm_gate_k<<<8192, 256, 0, stream>>>(obuf, rmsw, sgbuf, obuf_b);
  out_mfma_k<<<dim3(8, 16), 256, 0, stream>>>(obuf_b, woT, (float*)d_out);
}

// Round 11
// 201.386 us; speedup vs baseline: 4.0894x; 1.0394x over previous
//
#include <hip/hip_runtime.h>
#include <math.h>

// GLA: B=2, N=1024, D=1024, H=4, KD=512, VD=1024, DK=128, DV=256, LR=16
// Round 11: round-9 base (replay-proven) + gate_scan v2-noLDS:
// one wave per (b, chunk, 16-kcol group), vectorized vu4 q/k RMW, W2/bias
// via wave-uniform scalar loads; no LDS, no __syncthreads in gate_scan.
// out_mfma reverted to round-9 exact. 9 kernels. Workspace ~37 MB.

typedef __attribute__((ext_vector_type(4))) float vf4;
typedef __attribute__((ext_vector_type(4))) unsigned int vu4;
typedef __attribute__((ext_vector_type(8))) short short8;

#define DEVI static __device__ __forceinline__
DEVI vf4 vzero() { vf4 x = {0.f, 0.f, 0.f, 0.f}; return x; }

DEVI float bf2f(unsigned int u) {
  union { unsigned int i; float f; } c; c.i = u << 16; return c.f;
}
DEVI unsigned short f2bf(float f) {
  union { float f; unsigned int i; } c; c.f = f;
  unsigned int i = c.i;
  return (unsigned short)((i + 0x7fffu + ((i >> 16) & 1u)) >> 16);
}
DEVI void unpack8(vu4 r, float* f) {
  f[0] = bf2f(r.x & 0xffffu); f[1] = bf2f(r.x >> 16);
  f[2] = bf2f(r.y & 0xffffu); f[3] = bf2f(r.y >> 16);
  f[4] = bf2f(r.z & 0xffffu); f[5] = bf2f(r.z >> 16);
  f[6] = bf2f(r.w & 0xffffu); f[7] = bf2f(r.w >> 16);
}
DEVI vu4 pack8(const float* f) {
  vu4 o;
  o.x = (unsigned int)f2bf(f[0]) | ((unsigned int)f2bf(f[1]) << 16);
  o.y = (unsigned int)f2bf(f[2]) | ((unsigned int)f2bf(f[3]) << 16);
  o.z = (unsigned int)f2bf(f[4]) | ((unsigned int)f2bf(f[5]) << 16);
  o.w = (unsigned int)f2bf(f[6]) | ((unsigned int)f2bf(f[7]) << 16);
  return o;
}

// ---------------------------------------------------------------------------
// prep_k: ct<64 -> weight transpose+convert; ct>=64 -> x fp32->bf16.
// grid (96,16).
// ---------------------------------------------------------------------------
__global__ __launch_bounds__(256)
void prep_k(const float* __restrict__ Wq, const float* __restrict__ Wk,
            const float* __restrict__ Wv, const float* __restrict__ Wg,
            const float* __restrict__ Wo, const float* __restrict__ X,
            unsigned short* __restrict__ wqT, unsigned short* __restrict__ wkT,
            unsigned short* __restrict__ wvT, unsigned short* __restrict__ wgT,
            unsigned short* __restrict__ woT, unsigned short* __restrict__ xb) {
  __shared__ float T[64][65];
  const int ct = blockIdx.x, kt = blockIdx.y;
  const int t = threadIdx.x;
  const int r = t >> 2, s = t & 3;
  if (ct >= 64) {
    const int rt = ct - 64;
    const size_t base = (size_t)(rt * 64 + r) * 1024 + kt * 64 + s * 16;
    float f[16];
    *(vf4*)&f[0]  = *(const vf4*)(X + base);
    *(vf4*)&f[4]  = *(const vf4*)(X + base + 4);
    *(vf4*)&f[8]  = *(const vf4*)(X + base + 8);
    *(vf4*)&f[12] = *(const vf4*)(X + base + 12);
    *(vu4*)(xb + base) = pack8(f);
    *(vu4*)(xb + base + 8) = pack8(f + 8);
    return;
  }
  const float* W; unsigned short* O; int N; int cb;
  if (ct < 8)       { W = Wq; O = wqT; N = 512;  cb = ct; }
  else if (ct < 16) { W = Wk; O = wkT; N = 512;  cb = ct - 8; }
  else if (ct < 32) { W = Wv; O = wvT; N = 1024; cb = ct - 16; }
  else if (ct < 48) { W = Wg; O = wgT; N = 1024; cb = ct - 32; }
  else              { W = Wo; O = woT; N = 1024; cb = ct - 48; }
  const float* src = W + (size_t)(kt * 64 + r) * N + cb * 64 + s * 16;
#pragma unroll
  for (int u = 0; u < 4; ++u) {
    vf4 v4 = *(const vf4*)(src + u * 4);
    T[r][s * 16 + u * 4 + 0] = v4.x;
    T[r][s * 16 + u * 4 + 1] = v4.y;
    T[r][s * 16 + u * 4 + 2] = v4.z;
    T[r][s * 16 + u * 4 + 3] = v4.w;
  }
  __syncthreads();
  unsigned int pk[8];
#pragma unroll
  for (int u = 0; u < 8; ++u) {
    unsigned int lo = f2bf(T[s * 16 + 2 * u][r]);
    unsigned int hi = f2bf(T[s * 16 + 2 * u + 1][r]);
    pk[u] = lo | (hi << 16);
  }
  unsigned short* dst = O + (size_t)(cb * 64 + r) * 1024 + kt * 64 + s * 16;
  *(vu4*)dst = *(vu4*)&pk[0];
  *(vu4*)(dst + 8) = *(vu4*)&pk[4];
}

// ---------------------------------------------------------------------------
// MFMA projection: xb bf16 @ WT bf16 -> q,k,v,sg(silu) bf16. grid (24,16).
// ---------------------------------------------------------------------------
__global__ __launch_bounds__(256)
void proj_mfma_k(const unsigned short* __restrict__ xb,
                 const unsigned short* __restrict__ wqT, const unsigned short* __restrict__ wkT,
                 const unsigned short* __restrict__ wvT, const unsigned short* __restrict__ wgT,
                 unsigned short* __restrict__ qb, unsigned short* __restrict__ kb,
                 unsigned short* __restrict__ vb, unsigned short* __restrict__ sgb) {
  __shared__ __align__(16) unsigned short As[128 * 72];
  __shared__ __align__(16) unsigned short Bs[128 * 72];
  const int t = threadIdx.x;
  const int m0 = blockIdx.y << 7;
  const int nt = blockIdx.x;
  const unsigned short* WT; int n0; int kind;
  if (nt < 4)       { WT = wqT; n0 = nt * 128;        kind = 0; }
  else if (nt < 8)  { WT = wkT; n0 = (nt - 4) * 128;  kind = 1; }
  else if (nt < 16) { WT = wvT; n0 = (nt - 8) * 128;  kind = 2; }
  else              { WT = wgT; n0 = (nt - 16) * 128; kind = 3; }

  const int w = t >> 6, lane = t & 63;
  const int wm = (w >> 1) * 64, wn = (w & 1) * 64;
  const int qd = lane >> 4, m = lane & 15;

  vf4 acc[4][4];
#pragma unroll
  for (int i = 0; i < 4; ++i)
#pragma unroll
    for (int j = 0; j < 4; ++j) acc[i][j] = vzero();

  for (int k0 = 0; k0 < 1024; k0 += 64) {
    __syncthreads();
#pragma unroll
    for (int u2 = 0; u2 < 4; ++u2) {
      const int id = t + (u2 << 8);
      const int row = id >> 3, kg = id & 7;
      vu4 ra = *(const vu4*)(xb + (size_t)(m0 + row) * 1024 + k0 + kg * 8);
      *(vu4*)&As[row * 72 + kg * 8] = ra;
      vu4 rb = *(const vu4*)(WT + (size_t)(n0 + row) * 1024 + k0 + kg * 8);
      *(vu4*)&Bs[row * 72 + kg * 8] = rb;
    }
    __syncthreads();
#pragma unroll
    for (int ks = 0; ks < 2; ++ks) {
      short8 af[4], bf[4];
#pragma unroll
      for (int i = 0; i < 4; ++i) {
        af[i] = *(const short8*)&As[(wm + i * 16 + m) * 72 + ks * 32 + qd * 8];
        bf[i] = *(const short8*)&Bs[(wn + i * 16 + m) * 72 + ks * 32 + qd * 8];
      }
#pragma unroll
      for (int i = 0; i < 4; ++i)
#pragma unroll
        for (int j = 0; j < 4; ++j)
          acc[i][j] = __builtin_amdgcn_mfma_f32_16x16x32_bf16(af[i], bf[j], acc[i][j], 0, 0, 0);
    }
  }
#pragma unroll
  for (int i = 0; i < 4; ++i) {
#pragma unroll
    for (int j = 0; j < 4; ++j) {
#pragma unroll
      for (int r = 0; r < 4; ++r) {
        const int grow = m0 + wm + i * 16 + qd * 4 + r;
        const int gcol = n0 + wn + j * 16 + m;
        float val = acc[i][j][r];
        if (kind == 0)      qb[(size_t)grow * 512 + gcol] = f2bf(val);
        else if (kind == 1) kb[(size_t)grow * 512 + gcol] = f2bf(val);
        else if (kind == 2) vb[(size_t)grow * 1024 + gcol] = f2bf(val);
        else {
          val = val / (1.f + expf(-val));
          sgb[(size_t)grow * 1024 + gcol] = f2bf(val);
        }
      }
    }
  }
}

// ---------------------------------------------------------------------------
// MFMA output GEMM: obuf_b bf16 @ woT -> d_out fp32. grid (8,16). (round-9)
// ---------------------------------------------------------------------------
__global__ __launch_bounds__(256)
void out_mfma_k(const unsigned short* __restrict__ Ab,
                const unsigned short* __restrict__ woT, float* __restrict__ Y) {
  __shared__ __align__(16) unsigned short As[128 * 72];
  __shared__ __align__(16) unsigned short Bs[128 * 72];
  const int t = threadIdx.x;
  const int m0 = blockIdx.y << 7;
  const int n0 = blockIdx.x << 7;
  const int w = t >> 6, lane = t & 63;
  const int wm = (w >> 1) * 64, wn = (w & 1) * 64;
  const int qd = lane >> 4, m = lane & 15;

  vf4 acc[4][4];
#pragma unroll
  for (int i = 0; i < 4; ++i)
#pragma unroll
    for (int j = 0; j < 4; ++j) acc[i][j] = vzero();

  for (int k0 = 0; k0 < 1024; k0 += 64) {
    __syncthreads();
#pragma unroll
    for (int u2 = 0; u2 < 4; ++u2) {
      const int id = t + (u2 << 8);
      const int row = id >> 3, kg = id & 7;
      vu4 ra = *(const vu4*)(Ab + (size_t)(m0 + row) * 1024 + k0 + kg * 8);
      *(vu4*)&As[row * 72 + kg * 8] = ra;
      vu4 rb = *(const vu4*)(woT + (size_t)(n0 + row) * 1024 + k0 + kg * 8);
      *(vu4*)&Bs[row * 72 + kg * 8] = rb;
    }
    __syncthreads();
#pragma unroll
    for (int ks = 0; ks < 2; ++ks) {
      short8 af[4], bf[4];
#pragma unroll
      for (int i = 0; i < 4; ++i) {
        af[i] = *(const short8*)&As[(wm + i * 16 + m) * 72 + ks * 32 + qd * 8];
        bf[i] = *(const short8*)&Bs[(wn + i * 16 + m) * 72 + ks * 32 + qd * 8];
      }
#pragma unroll
      for (int i = 0; i < 4; ++i)
#pragma unroll
        for (int j = 0; j < 4; ++j)
          acc[i][j] = __builtin_amdgcn_mfma_f32_16x16x32_bf16(af[i], bf[j], acc[i][j], 0, 0, 0);
    }
  }
#pragma unroll
  for (int i = 0; i < 4; ++i)
#pragma unroll
    for (int j = 0; j < 4; ++j)
#pragma unroll
      for (int r = 0; r < 4; ++r) {
        const int grow = m0 + wm + i * 16 + qd * 4 + r;
        const int gcol = n0 + wn + j * 16 + m;
        Y[(size_t)grow * 1024 + gcol] = acc[i][j][r];
      }
}

// ---------------------------------------------------------------------------
// xl = x @ Wgk1 [2048,16] fp32. One wave per row.
// ---------------------------------------------------------------------------
__global__ __launch_bounds__(64)
void lowrank_k(const float* __restrict__ X, const float* __restrict__ W1,
               float* __restrict__ xl) {
  const int row = blockIdx.x;
  const int t = threadIdx.x;
  float acc[16];
#pragma unroll
  for (int c2 = 0; c2 < 16; ++c2) acc[c2] = 0.f;
  const float* xp = X + (size_t)row * 1024 + t * 16;
  float xv[16];
#pragma unroll
  for (int u = 0; u < 4; ++u)
    *(vf4*)&xv[u * 4] = *(const vf4*)(xp + u * 4);
#pragma unroll
  for (int j = 0; j < 16; ++j) {
    const float* wp = W1 + (size_t)(t * 16 + j) * 16;
    float wv[16];
#pragma unroll
    for (int u = 0; u < 4; ++u)
      *(vf4*)&wv[u * 4] = *(const vf4*)(wp + u * 4);
#pragma unroll
    for (int c2 = 0; c2 < 16; ++c2) acc[c2] = fmaf(xv[j], wv[c2], acc[c2]);
  }
#pragma unroll
  for (int mm = 1; mm < 64; mm <<= 1) {
#pragma unroll
    for (int c2 = 0; c2 < 16; ++c2) acc[c2] += __shfl_xor(acc[c2], mm, 64);
  }
  if (t == 0) {
#pragma unroll
    for (int c2 = 0; c2 < 16; ++c2) xl[(size_t)row * 16 + c2] = acc[c2];
  }
}

// ---------------------------------------------------------------------------
// gate_scan v2-noLDS: one wave per (b, chunk, 16-kcol group); lane = row.
// Vectorized vu4 q/k RMW; W2/bias via wave-uniform scalar loads.
// No LDS, no __syncthreads. grid 256 x 256 (1024 waves total).
// ---------------------------------------------------------------------------
__global__ __launch_bounds__(256)
void gate_scan_k(const float* __restrict__ xl, const float* __restrict__ W2,
                 const float* __restrict__ bias,
                 unsigned short* __restrict__ q, unsigned short* __restrict__ k,
                 float* __restrict__ ebtot) {
  const int t = threadIdx.x;
  const int w = t >> 6, lane = t & 63;
  const int wid = blockIdx.x * 4 + w;     // 0..1023
  const int kt = wid & 31;                // 16-col group (512/16 = 32)
  const int c = (wid >> 5) & 15;
  const int b = wid >> 9;
  const int kbase = kt * 16;
  const size_t rowbase = (size_t)b * 1024 + c * 64;

  // lane's xl row
  const float* xp = xl + (rowbase + lane) * 16;
  float xv[16];
#pragma unroll
  for (int u = 0; u < 4; ++u)
    *(vf4*)&xv[u * 4] = *(const vf4*)(xp + u * 4);

  // lane's 16 q/k values (vectorized, 16B-aligned: a multiple of 16 elems)
  const size_t a = (rowbase + lane) * 512 + kbase;
  vu4 qr0 = *(const vu4*)(q + a), qr1 = *(const vu4*)(q + a + 8);
  vu4 kr0 = *(const vu4*)(k + a), kr1 = *(const vu4*)(k + a + 8);
  float qf[16], kf[16];
  unpack8(qr0, qf); unpack8(qr1, qf + 8);
  unpack8(kr0, kf); unpack8(kr1, kf + 8);

  float gf[16];
#pragma unroll
  for (int cc = 0; cc < 16; ++cc) {
    const int col = kbase + cc;           // wave-uniform -> s_loads below
    float z = bias[col];
#pragma unroll
    for (int j = 0; j < 16; ++j) z = fmaf(xv[j], W2[j * 512 + col], z);
    float ls = fminf(z, 0.f) - log1pf(expf(-fabsf(z)));
    float g = fmaxf(ls * (1.f / 16.f), -3.f);
#pragma unroll
    for (int d = 1; d < 64; d <<= 1) {
      float up = __shfl_up(g, d, 64);
      if (lane >= d) g += up;
    }
    qf[cc] *= expf(g);
    kf[cc] *= expf(fminf(-g, 80.f));
    gf[cc] = g;
  }
  *(vu4*)(q + a) = pack8(qf);
  *(vu4*)(q + a + 8) = pack8(qf + 8);
  *(vu4*)(k + a) = pack8(kf);
  *(vu4*)(k + a + 8) = pack8(kf + 8);
  if (lane == 63) {
    float* ep = ebtot + ((size_t)b * 16 + c) * 512 + kbase;
#pragma unroll
    for (int cc = 0; cc < 16; ++cc) ep[cc] = expf(gf[cc]);
  }
}

// ---------------------------------------------------------------------------
// Fused intra+kv, all-MFMA. grid (vh2, chunk16, bh8) = 256 blocks.
// ---------------------------------------------------------------------------
__global__ __launch_bounds__(256)
void intra_kv_k(const unsigned short* __restrict__ q16, const unsigned short* __restrict__ k16,
                const unsigned short* __restrict__ v, float* __restrict__ o,
                unsigned short* __restrict__ ST) {
  __shared__ __align__(16) unsigned short Qs[64 * 136];
  __shared__ __align__(16) unsigned short Ks[64 * 136];
  __shared__ __align__(16) unsigned short Kt[128 * 68];  // [k][j]
  __shared__ __align__(16) unsigned short Vt[128 * 68];  // [v-half][j]
  __shared__ __align__(16) unsigned short Asb[64 * 68];  // bf16 masked A
  const int t = threadIdx.x;
  const int vh = blockIdx.x, c = blockIdx.y, bh = blockIdx.z;
  const int b = bh >> 2, h = bh & 3;
  const size_t rowbase = (size_t)b * 1024 + c * 64;

#pragma unroll
  for (int u2 = 0; u2 < 4; ++u2) {
    const int id = t + (u2 << 8);
    const int row = id >> 4, kg = id & 15;
    vu4 rq = *(const vu4*)(q16 + (rowbase + row) * 512 + h * 128 + kg * 8);
    *(vu4*)&Qs[row * 136 + kg * 8] = rq;
    vu4 rk = *(const vu4*)(k16 + (rowbase + row) * 512 + h * 128 + kg * 8);
    *(vu4*)&Ks[row * 136 + kg * 8] = rk;
    const unsigned short* kp = (const unsigned short*)&rk;
#pragma unroll
    for (int u = 0; u < 8; ++u)
      Kt[(kg * 8 + u) * 68 + row] = kp[u];
    vu4 rv = *(const vu4*)(v + (rowbase + row) * 1024 + h * 256 + vh * 128 + kg * 8);
    const unsigned short* vp = (const unsigned short*)&rv;
#pragma unroll
    for (int u = 0; u < 8; ++u)
      Vt[(kg * 8 + u) * 68 + row] = vp[u];
  }
  __syncthreads();

  const int w = t >> 6, lane = t & 63;
  const int qd = lane >> 4, m = lane & 15;

  // phase 1: A = tril(Q K^T)
  {
    short8 af[4];
#pragma unroll
    for (int kf = 0; kf < 4; ++kf)
      af[kf] = *(const short8*)&Qs[(w * 16 + m) * 136 + kf * 32 + qd * 8];
    vf4 acc[4];
#pragma unroll
    for (int jt = 0; jt < 4; ++jt) acc[jt] = vzero();
#pragma unroll
    for (int jt = 0; jt < 4; ++jt)
#pragma unroll
      for (int kf = 0; kf < 4; ++kf) {
        short8 bfr = *(const short8*)&Ks[(jt * 16 + m) * 136 + kf * 32 + qd * 8];
        acc[jt] = __builtin_amdgcn_mfma_f32_16x16x32_bf16(af[kf], bfr, acc[jt], 0, 0, 0);
      }
#pragma unroll
    for (int jt = 0; jt < 4; ++jt)
#pragma unroll
      for (int r = 0; r < 4; ++r) {
        const int i = w * 16 + qd * 4 + r;
        const int j = jt * 16 + m;
        Asb[i * 68 + j] = f2bf((j <= i) ? acc[jt][r] : 0.f);
      }
  }
  __syncthreads();

  // phase 2: o_intra = A @ V
  {
    vf4 acc2[4][2];
#pragma unroll
    for (int mt = 0; mt < 4; ++mt) { acc2[mt][0] = vzero(); acc2[mt][1] = vzero(); }
#pragma unroll
    for (int kf = 0; kf < 2; ++kf) {
      short8 bf0 = *(const short8*)&Vt[(w * 32 + m) * 68 + kf * 32 + qd * 8];
      short8 bf1 = *(const short8*)&Vt[(w * 32 + 16 + m) * 68 + kf * 32 + qd * 8];
#pragma unroll
      for (int mt = 0; mt < 4; ++mt) {
        short8 af = *(const short8*)&Asb[(mt * 16 + m) * 68 + kf * 32 + qd * 8];
        acc2[mt][0] = __builtin_amdgcn_mfma_f32_16x16x32_bf16(af, bf0, acc2[mt][0], 0, 0, 0);
        acc2[mt][1] = __builtin_amdgcn_mfma_f32_16x16x32_bf16(af, bf1, acc2[mt][1], 0, 0, 0);
      }
    }
#pragma unroll
    for (int mt = 0; mt < 4; ++mt)
#pragma unroll
      for (int nt = 0; nt < 2; ++nt)
#pragma unroll
        for (int r = 0; r < 4; ++r) {
          const int i = mt * 16 + qd * 4 + r;
          const int vc = h * 256 + vh * 128 + w * 32 + nt * 16 + m;
          o[(rowbase + i) * 1024 + vc] = acc2[mt][nt][r];
        }
  }

  // phase 3: ST[v][k] = V^T @ K
  {
    short8 af3[2][2];
#pragma unroll
    for (int mt = 0; mt < 2; ++mt)
#pragma unroll
      for (int kf = 0; kf < 2; ++kf)
        af3[mt][kf] = *(const short8*)&Vt[(w * 32 + mt * 16 + m) * 68 + kf * 32 + qd * 8];
#pragma unroll
    for (int nt = 0; nt < 8; ++nt) {
      vf4 a0 = vzero(), a1 = vzero();
#pragma unroll
      for (int kf = 0; kf < 2; ++kf) {
        short8 bfr = *(const short8*)&Kt[(nt * 16 + m) * 68 + kf * 32 + qd * 8];
        a0 = __builtin_amdgcn_mfma_f32_16x16x32_bf16(af3[0][kf], bfr, a0, 0, 0, 0);
        a1 = __builtin_amdgcn_mfma_f32_16x16x32_bf16(af3[1][kf], bfr, a1, 0, 0, 0);
      }
      const size_t sbase = (size_t)(bh * 16 + c) * 256 + vh * 128 + w * 32;
#pragma unroll
      for (int r = 0; r < 4; ++r) {
        ST[(sbase + qd * 4 + r) * 128 + nt * 16 + m] = f2bf(a0[r]);
        ST[(sbase + 16 + qd * 4 + r) * 128 + nt * 16 + m] = f2bf(a1[r]);
      }
    }
  }
}

// ---------------------------------------------------------------------------
// State scan in place on bf16 ST[v][k]; fp32 carry; per-k decay vector.
// ---------------------------------------------------------------------------
__global__ __launch_bounds__(256)
void state_scan_k(unsigned short* __restrict__ ST, const float* __restrict__ ebtot) {
  const int idx = blockIdx.x * 256 + threadIdx.x;  // 0..32767
  const int kg = idx & 15;
  const int vv = (idx >> 4) & 255;
  const int bh = idx >> 12;
  const int b = bh >> 2, h = bh & 3;
  float s[8];
#pragma unroll
  for (int u = 0; u < 8; ++u) s[u] = 0.f;
  for (int c = 0; c < 16; ++c) {
    unsigned short* p = ST + ((size_t)(bh * 16 + c) * 256 + vv) * 128 + kg * 8;
    const float* ep = ebtot + ((size_t)b * 16 + c) * 512 + h * 128 + kg * 8;
    float e[8];
    *(vf4*)&e[0] = *(const vf4*)ep;
    *(vf4*)&e[4] = *(const vf4*)(ep + 4);
    float kv[8];
    unpack8(*(const vu4*)p, kv);
    *(vu4*)p = pack8(s);
#pragma unroll
    for (int u = 0; u < 8; ++u) s[u] = (s[u] + kv[u]) * e[u];
  }
}

// ---------------------------------------------------------------------------
// o += Q~ @ S_c via MFMA. grid (vt2, chunk16, bh8) = 256 blocks.
// ---------------------------------------------------------------------------
__global__ __launch_bounds__(256)
void o_inter_k(const unsigned short* __restrict__ q16, const unsigned short* __restrict__ ST,
               float* __restrict__ o) {
  __shared__ __align__(16) unsigned short Qs[64 * 136];
  __shared__ __align__(16) unsigned short Ss[128 * 136];
  const int t = threadIdx.x;
  const int vt = blockIdx.x, c = blockIdx.y, bh = blockIdx.z;
  const int b = bh >> 2, h = bh & 3;
  const size_t rowbase = (size_t)b * 1024 + c * 64;

#pragma unroll
  for (int u2 = 0; u2 < 4; ++u2) {
    const int id = t + (u2 << 8);
    const int row = id >> 4, kg = id & 15;
    *(vu4*)&Qs[row * 136 + kg * 8] =
        *(const vu4*)(q16 + (rowbase + row) * 512 + h * 128 + kg * 8);
  }
#pragma unroll
  for (int u2 = 0; u2 < 8; ++u2) {
    const int id = t + (u2 << 8);
    const int vrow = id >> 4, kg = id & 15;
    *(vu4*)&Ss[vrow * 136 + kg * 8] =
        *(const vu4*)(ST + ((size_t)(bh * 16 + c) * 256 + vt * 128 + vrow) * 128 + kg * 8);
  }
  __syncthreads();

  const int w = t >> 6, lane = t & 63;
  const int qd = lane >> 4, m = lane & 15;
  short8 af[4];
#pragma unroll
  for (int kf = 0; kf < 4; ++kf)
    af[kf] = *(const short8*)&Qs[(w * 16 + m) * 136 + kf * 32 + qd * 8];
#pragma unroll
  for (int nt = 0; nt < 8; ++nt) {
    vf4 acc = vzero();
#pragma unroll
    for (int kf = 0; kf < 4; ++kf) {
      short8 bfr = *(const short8*)&Ss[(nt * 16 + m) * 136 + kf * 32 + qd * 8];
      acc = __builtin_amdgcn_mfma_f32_16x16x32_bf16(af[kf], bfr, acc, 0, 0, 0);
    }
    float* base = o + (rowbase + w * 16 + qd * 4) * 1024 + h * 256 + vt * 128 + nt * 16 + m;
#pragma unroll
    for (int r = 0; r < 4; ++r)
      base[(size_t)r * 1024] += acc[r];
  }
}

// ---------------------------------------------------------------------------
// RMSNorm over DV=256 + silu-gate; obuf fp32 -> obuf_b bf16.
// ---------------------------------------------------------------------------
__global__ __launch_bounds__(256)
void norm_gate_k(const float* __restrict__ o, const float* __restrict__ rmsw,
                 const unsigned short* __restrict__ sg,
                 unsigned short* __restrict__ ob) {
  __shared__ float red[4];
  const int grp = blockIdx.x;
  const int row = grp >> 2, h = grp & 3;
  const int t = threadIdx.x;
  const size_t idx = (size_t)row * 1024 + h * 256 + t;
  const float val = o[idx];
  float ss = val * val;
#pragma unroll
  for (int mm = 1; mm < 64; mm <<= 1) ss += __shfl_xor(ss, mm, 64);
  if ((t & 63) == 0) red[t >> 6] = ss;
  __syncthreads();
  const float tot = red[0] + red[1] + red[2] + red[3];
  const float scale = rsqrtf(tot * (1.f / 256.f) + 1e-5f);
  ob[idx] = f2bf(val * scale * rmsw[t] * bf2f((unsigned int)sg[idx]));
}

// ---------------------------------------------------------------------------
extern "C" void kernel_launch(void* const* d_in, const int* in_sizes, int n_in,
                              void* d_out, int out_size, void* d_ws, size_t ws_size,
                              hipStream_t stream) {
  const float* x    = (const float*)d_in[0];
  const float* Wq   = (const float*)d_in[1];
  const float* Wk   = (const float*)d_in[2];
  const float* Wv   = (const float*)d_in[3];
  const float* Wg   = (const float*)d_in[4];
  const float* Wgk1 = (const float*)d_in[5];
  const float* Wgk2 = (const float*)d_in[6];
  const float* bgk2 = (const float*)d_in[7];
  const float* Wout = (const float*)d_in[8];
  const float* rmsw = (const float*)d_in[9];

  const size_t MB = 1u << 20;
  char* w = (char*)d_ws;
  unsigned short* qb16   = (unsigned short*)(w);           // [0,2) MB bf16
  unsigned short* kb16   = (unsigned short*)(w + 2 * MB);  // [2,4)
  unsigned short* vbuf   = (unsigned short*)(w + 4 * MB);  // [4,8)
  unsigned short* sgbuf  = (unsigned short*)(w + 8 * MB);  // [8,12)
  float*          obuf   = (float*)(w + 12 * MB);          // [12,20) fp32
  char*           sreg   = w + 20 * MB;                    // [20,28) multi-phase
  unsigned short* xb     = (unsigned short*)sreg;          //   phase 0: 4 MB
  unsigned short* STbuf  = (unsigned short*)sreg;          //   phase A: 8 MB [v][k]
  unsigned short* obuf_b = (unsigned short*)sreg;          //   phase B: 4 MB
  float*          xlbuf  = (float*)(w + 28 * MB);          // 128 KB
  float*          ebbuf  = (float*)(w + 28 * MB + 131072); // 64 KB
  unsigned short* wqT    = (unsigned short*)(w + 29 * MB); // 1 MB
  unsigned short* wkT    = (unsigned short*)(w + 30 * MB); // 1 MB
  unsigned short* wvT    = (unsigned short*)(w + 31 * MB); // 2 MB
  unsigned short* wgT    = (unsigned short*)(w + 33 * MB); // 2 MB
  unsigned short* woT    = (unsigned short*)(w + 35 * MB); // 2 MB

  prep_k<<<dim3(96, 16), 256, 0, stream>>>(Wq, Wk, Wv, Wg, Wout, x,
                                           wqT, wkT, wvT, wgT, woT, xb);
  lowrank_k<<<2048, 64, 0, stream>>>(x, Wgk1, xlbuf);
  proj_mfma_k<<<dim3(24, 16), 256, 0, stream>>>(xb, wqT, wkT, wvT, wgT, qb16, kb16, vbuf, sgbuf);
  gate_scan_k<<<256, 256, 0, stream>>>(xlbuf, Wgk2, bgk2, qb16, kb16, ebbuf);
  intra_kv_k<<<dim3(2, 16, 8), 256, 0, stream>>>(qb16, kb16, vbuf, obuf, STbuf);
  state_scan_k<<<128, 256, 0, stream>>>(STbuf, ebbuf);
  o_inter_k<<<dim3(2, 16, 8), 256, 0, stream>>>(qb16, STbuf, obuf);
  norm_gate_k<<<8192, 256, 0, stream>>>(obuf, rmsw, sgbuf, obuf_b);
  out_mfma_k<<<dim3(8, 16), 256, 0, stream>>>(obuf_b, woT, (float*)d_out);
}

// Round 12
// 194.421 us; speedup vs baseline: 4.2359x; 1.0358x over previous
//
#include <hip/hip_runtime.h>
#include <math.h>

// GLA: B=2, N=1024, D=1024, H=4, KD=512, VD=1024, DK=128, DV=256, LR=16
// Round 12: proj_mfma and out_mfma retiled to 64-row M-tiles (128 cols kept):
// proj grid (24,32)=768 blocks, out grid (8,32)=256 blocks. Same K-loop
// accumulation order (bit-identical outputs); LDS 27.6 KB/block.
// Rest identical to round 11. 9 kernels. Workspace ~37 MB.

typedef __attribute__((ext_vector_type(4))) float vf4;
typedef __attribute__((ext_vector_type(4))) unsigned int vu4;
typedef __attribute__((ext_vector_type(8))) short short8;

#define DEVI static __device__ __forceinline__
DEVI vf4 vzero() { vf4 x = {0.f, 0.f, 0.f, 0.f}; return x; }

DEVI float bf2f(unsigned int u) {
  union { unsigned int i; float f; } c; c.i = u << 16; return c.f;
}
DEVI unsigned short f2bf(float f) {
  union { float f; unsigned int i; } c; c.f = f;
  unsigned int i = c.i;
  return (unsigned short)((i + 0x7fffu + ((i >> 16) & 1u)) >> 16);
}
DEVI void unpack8(vu4 r, float* f) {
  f[0] = bf2f(r.x & 0xffffu); f[1] = bf2f(r.x >> 16);
  f[2] = bf2f(r.y & 0xffffu); f[3] = bf2f(r.y >> 16);
  f[4] = bf2f(r.z & 0xffffu); f[5] = bf2f(r.z >> 16);
  f[6] = bf2f(r.w & 0xffffu); f[7] = bf2f(r.w >> 16);
}
DEVI vu4 pack8(const float* f) {
  vu4 o;
  o.x = (unsigned int)f2bf(f[0]) | ((unsigned int)f2bf(f[1]) << 16);
  o.y = (unsigned int)f2bf(f[2]) | ((unsigned int)f2bf(f[3]) << 16);
  o.z = (unsigned int)f2bf(f[4]) | ((unsigned int)f2bf(f[5]) << 16);
  o.w = (unsigned int)f2bf(f[6]) | ((unsigned int)f2bf(f[7]) << 16);
  return o;
}

// ---------------------------------------------------------------------------
// prep_k: ct<64 -> weight transpose+convert; ct>=64 -> x fp32->bf16.
// grid (96,16).
// ---------------------------------------------------------------------------
__global__ __launch_bounds__(256)
void prep_k(const float* __restrict__ Wq, const float* __restrict__ Wk,
            const float* __restrict__ Wv, const float* __restrict__ Wg,
            const float* __restrict__ Wo, const float* __restrict__ X,
            unsigned short* __restrict__ wqT, unsigned short* __restrict__ wkT,
            unsigned short* __restrict__ wvT, unsigned short* __restrict__ wgT,
            unsigned short* __restrict__ woT, unsigned short* __restrict__ xb) {
  __shared__ float T[64][65];
  const int ct = blockIdx.x, kt = blockIdx.y;
  const int t = threadIdx.x;
  const int r = t >> 2, s = t & 3;
  if (ct >= 64) {
    const int rt = ct - 64;
    const size_t base = (size_t)(rt * 64 + r) * 1024 + kt * 64 + s * 16;
    float f[16];
    *(vf4*)&f[0]  = *(const vf4*)(X + base);
    *(vf4*)&f[4]  = *(const vf4*)(X + base + 4);
    *(vf4*)&f[8]  = *(const vf4*)(X + base + 8);
    *(vf4*)&f[12] = *(const vf4*)(X + base + 12);
    *(vu4*)(xb + base) = pack8(f);
    *(vu4*)(xb + base + 8) = pack8(f + 8);
    return;
  }
  const float* W; unsigned short* O; int N; int cb;
  if (ct < 8)       { W = Wq; O = wqT; N = 512;  cb = ct; }
  else if (ct < 16) { W = Wk; O = wkT; N = 512;  cb = ct - 8; }
  else if (ct < 32) { W = Wv; O = wvT; N = 1024; cb = ct - 16; }
  else if (ct < 48) { W = Wg; O = wgT; N = 1024; cb = ct - 32; }
  else              { W = Wo; O = woT; N = 1024; cb = ct - 48; }
  const float* src = W + (size_t)(kt * 64 + r) * N + cb * 64 + s * 16;
#pragma unroll
  for (int u = 0; u < 4; ++u) {
    vf4 v4 = *(const vf4*)(src + u * 4);
    T[r][s * 16 + u * 4 + 0] = v4.x;
    T[r][s * 16 + u * 4 + 1] = v4.y;
    T[r][s * 16 + u * 4 + 2] = v4.z;
    T[r][s * 16 + u * 4 + 3] = v4.w;
  }
  __syncthreads();
  unsigned int pk[8];
#pragma unroll
  for (int u = 0; u < 8; ++u) {
    unsigned int lo = f2bf(T[s * 16 + 2 * u][r]);
    unsigned int hi = f2bf(T[s * 16 + 2 * u + 1][r]);
    pk[u] = lo | (hi << 16);
  }
  unsigned short* dst = O + (size_t)(cb * 64 + r) * 1024 + kt * 64 + s * 16;
  *(vu4*)dst = *(vu4*)&pk[0];
  *(vu4*)(dst + 8) = *(vu4*)&pk[4];
}

// ---------------------------------------------------------------------------
// MFMA projection: xb bf16 @ WT bf16 -> q,k,v,sg(silu) bf16.
// 64x128 tile, BK=64. grid (24,32) = 768 blocks. LDS 27.6 KB.
// ---------------------------------------------------------------------------
__global__ __launch_bounds__(256)
void proj_mfma_k(const unsigned short* __restrict__ xb,
                 const unsigned short* __restrict__ wqT, const unsigned short* __restrict__ wkT,
                 const unsigned short* __restrict__ wvT, const unsigned short* __restrict__ wgT,
                 unsigned short* __restrict__ qb, unsigned short* __restrict__ kb,
                 unsigned short* __restrict__ vb, unsigned short* __restrict__ sgb) {
  __shared__ __align__(16) unsigned short As[64 * 72];
  __shared__ __align__(16) unsigned short Bs[128 * 72];
  const int t = threadIdx.x;
  const int m0 = blockIdx.y << 6;
  const int nt = blockIdx.x;
  const unsigned short* WT; int n0; int kind;
  if (nt < 4)       { WT = wqT; n0 = nt * 128;        kind = 0; }
  else if (nt < 8)  { WT = wkT; n0 = (nt - 4) * 128;  kind = 1; }
  else if (nt < 16) { WT = wvT; n0 = (nt - 8) * 128;  kind = 2; }
  else              { WT = wgT; n0 = (nt - 16) * 128; kind = 3; }

  const int w = t >> 6, lane = t & 63;
  const int wm = (w >> 1) * 32, wn = (w & 1) * 64;
  const int qd = lane >> 4, m = lane & 15;

  vf4 acc[2][4];
#pragma unroll
  for (int i = 0; i < 2; ++i)
#pragma unroll
    for (int j = 0; j < 4; ++j) acc[i][j] = vzero();

  for (int k0 = 0; k0 < 1024; k0 += 64) {
    __syncthreads();
#pragma unroll
    for (int u2 = 0; u2 < 2; ++u2) {
      const int id = t + (u2 << 8);
      const int row = id >> 3, kg = id & 7;
      vu4 ra = *(const vu4*)(xb + (size_t)(m0 + row) * 1024 + k0 + kg * 8);
      *(vu4*)&As[row * 72 + kg * 8] = ra;
    }
#pragma unroll
    for (int u2 = 0; u2 < 4; ++u2) {
      const int id = t + (u2 << 8);
      const int row = id >> 3, kg = id & 7;
      vu4 rb = *(const vu4*)(WT + (size_t)(n0 + row) * 1024 + k0 + kg * 8);
      *(vu4*)&Bs[row * 72 + kg * 8] = rb;
    }
    __syncthreads();
#pragma unroll
    for (int ks = 0; ks < 2; ++ks) {
      short8 af[2], bf[4];
#pragma unroll
      for (int i = 0; i < 2; ++i)
        af[i] = *(const short8*)&As[(wm + i * 16 + m) * 72 + ks * 32 + qd * 8];
#pragma unroll
      for (int j = 0; j < 4; ++j)
        bf[j] = *(const short8*)&Bs[(wn + j * 16 + m) * 72 + ks * 32 + qd * 8];
#pragma unroll
      for (int i = 0; i < 2; ++i)
#pragma unroll
        for (int j = 0; j < 4; ++j)
          acc[i][j] = __builtin_amdgcn_mfma_f32_16x16x32_bf16(af[i], bf[j], acc[i][j], 0, 0, 0);
    }
  }
#pragma unroll
  for (int i = 0; i < 2; ++i) {
#pragma unroll
    for (int j = 0; j < 4; ++j) {
#pragma unroll
      for (int r = 0; r < 4; ++r) {
        const int grow = m0 + wm + i * 16 + qd * 4 + r;
        const int gcol = n0 + wn + j * 16 + m;
        float val = acc[i][j][r];
        if (kind == 0)      qb[(size_t)grow * 512 + gcol] = f2bf(val);
        else if (kind == 1) kb[(size_t)grow * 512 + gcol] = f2bf(val);
        else if (kind == 2) vb[(size_t)grow * 1024 + gcol] = f2bf(val);
        else {
          val = val / (1.f + expf(-val));
          sgb[(size_t)grow * 1024 + gcol] = f2bf(val);
        }
      }
    }
  }
}

// ---------------------------------------------------------------------------
// MFMA output GEMM: obuf_b bf16 @ woT -> d_out fp32.
// 64x128 tile, grid (8,32) = 256 blocks.
// ---------------------------------------------------------------------------
__global__ __launch_bounds__(256)
void out_mfma_k(const unsigned short* __restrict__ Ab,
                const unsigned short* __restrict__ woT, float* __restrict__ Y) {
  __shared__ __align__(16) unsigned short As[64 * 72];
  __shared__ __align__(16) unsigned short Bs[128 * 72];
  const int t = threadIdx.x;
  const int m0 = blockIdx.y << 6;
  const int n0 = blockIdx.x << 7;
  const int w = t >> 6, lane = t & 63;
  const int wm = (w >> 1) * 32, wn = (w & 1) * 64;
  const int qd = lane >> 4, m = lane & 15;

  vf4 acc[2][4];
#pragma unroll
  for (int i = 0; i < 2; ++i)
#pragma unroll
    for (int j = 0; j < 4; ++j) acc[i][j] = vzero();

  for (int k0 = 0; k0 < 1024; k0 += 64) {
    __syncthreads();
#pragma unroll
    for (int u2 = 0; u2 < 2; ++u2) {
      const int id = t + (u2 << 8);
      const int row = id >> 3, kg = id & 7;
      vu4 ra = *(const vu4*)(Ab + (size_t)(m0 + row) * 1024 + k0 + kg * 8);
      *(vu4*)&As[row * 72 + kg * 8] = ra;
    }
#pragma unroll
    for (int u2 = 0; u2 < 4; ++u2) {
      const int id = t + (u2 << 8);
      const int row = id >> 3, kg = id & 7;
      vu4 rb = *(const vu4*)(woT + (size_t)(n0 + row) * 1024 + k0 + kg * 8);
      *(vu4*)&Bs[row * 72 + kg * 8] = rb;
    }
    __syncthreads();
#pragma unroll
    for (int ks = 0; ks < 2; ++ks) {
      short8 af[2], bf[4];
#pragma unroll
      for (int i = 0; i < 2; ++i)
        af[i] = *(const short8*)&As[(wm + i * 16 + m) * 72 + ks * 32 + qd * 8];
#pragma unroll
      for (int j = 0; j < 4; ++j)
        bf[j] = *(const short8*)&Bs[(wn + j * 16 + m) * 72 + ks * 32 + qd * 8];
#pragma unroll
      for (int i = 0; i < 2; ++i)
#pragma unroll
        for (int j = 0; j < 4; ++j)
          acc[i][j] = __builtin_amdgcn_mfma_f32_16x16x32_bf16(af[i], bf[j], acc[i][j], 0, 0, 0);
    }
  }
#pragma unroll
  for (int i = 0; i < 2; ++i)
#pragma unroll
    for (int j = 0; j < 4; ++j)
#pragma unroll
      for (int r = 0; r < 4; ++r) {
        const int grow = m0 + wm + i * 16 + qd * 4 + r;
        const int gcol = n0 + wn + j * 16 + m;
        Y[(size_t)grow * 1024 + gcol] = acc[i][j][r];
      }
}

// ---------------------------------------------------------------------------
// xl = x @ Wgk1 [2048,16] fp32. One wave per row.
// ---------------------------------------------------------------------------
__global__ __launch_bounds__(64)
void lowrank_k(const float* __restrict__ X, const float* __restrict__ W1,
               float* __restrict__ xl) {
  const int row = blockIdx.x;
  const int t = threadIdx.x;
  float acc[16];
#pragma unroll
  for (int c2 = 0; c2 < 16; ++c2) acc[c2] = 0.f;
  const float* xp = X + (size_t)row * 1024 + t * 16;
  float xv[16];
#pragma unroll
  for (int u = 0; u < 4; ++u)
    *(vf4*)&xv[u * 4] = *(const vf4*)(xp + u * 4);
#pragma unroll
  for (int j = 0; j < 16; ++j) {
    const float* wp = W1 + (size_t)(t * 16 + j) * 16;
    float wv[16];
#pragma unroll
    for (int u = 0; u < 4; ++u)
      *(vf4*)&wv[u * 4] = *(const vf4*)(wp + u * 4);
#pragma unroll
    for (int c2 = 0; c2 < 16; ++c2) acc[c2] = fmaf(xv[j], wv[c2], acc[c2]);
  }
#pragma unroll
  for (int mm = 1; mm < 64; mm <<= 1) {
#pragma unroll
    for (int c2 = 0; c2 < 16; ++c2) acc[c2] += __shfl_xor(acc[c2], mm, 64);
  }
  if (t == 0) {
#pragma unroll
    for (int c2 = 0; c2 < 16; ++c2) xl[(size_t)row * 16 + c2] = acc[c2];
  }
}

// ---------------------------------------------------------------------------
// gate_scan v2-noLDS: one wave per (b, chunk, 16-kcol group); lane = row.
// grid 256 x 256.
// ---------------------------------------------------------------------------
__global__ __launch_bounds__(256)
void gate_scan_k(const float* __restrict__ xl, const float* __restrict__ W2,
                 const float* __restrict__ bias,
                 unsigned short* __restrict__ q, unsigned short* __restrict__ k,
                 float* __restrict__ ebtot) {
  const int t = threadIdx.x;
  const int w = t >> 6, lane = t & 63;
  const int wid = blockIdx.x * 4 + w;     // 0..1023
  const int kt = wid & 31;                // 16-col group
  const int c = (wid >> 5) & 15;
  const int b = wid >> 9;
  const int kbase = kt * 16;
  const size_t rowbase = (size_t)b * 1024 + c * 64;

  const float* xp = xl + (rowbase + lane) * 16;
  float xv[16];
#pragma unroll
  for (int u = 0; u < 4; ++u)
    *(vf4*)&xv[u * 4] = *(const vf4*)(xp + u * 4);

  const size_t a = (rowbase + lane) * 512 + kbase;
  vu4 qr0 = *(const vu4*)(q + a), qr1 = *(const vu4*)(q + a + 8);
  vu4 kr0 = *(const vu4*)(k + a), kr1 = *(const vu4*)(k + a + 8);
  float qf[16], kf[16];
  unpack8(qr0, qf); unpack8(qr1, qf + 8);
  unpack8(kr0, kf); unpack8(kr1, kf + 8);

  float gf[16];
#pragma unroll
  for (int cc = 0; cc < 16; ++cc) {
    const int col = kbase + cc;           // wave-uniform
    float z = bias[col];
#pragma unroll
    for (int j = 0; j < 16; ++j) z = fmaf(xv[j], W2[j * 512 + col], z);
    float ls = fminf(z, 0.f) - log1pf(expf(-fabsf(z)));
    float g = fmaxf(ls * (1.f / 16.f), -3.f);
#pragma unroll
    for (int d = 1; d < 64; d <<= 1) {
      float up = __shfl_up(g, d, 64);
      if (lane >= d) g += up;
    }
    qf[cc] *= expf(g);
    kf[cc] *= expf(fminf(-g, 80.f));
    gf[cc] = g;
  }
  *(vu4*)(q + a) = pack8(qf);
  *(vu4*)(q + a + 8) = pack8(qf + 8);
  *(vu4*)(k + a) = pack8(kf);
  *(vu4*)(k + a + 8) = pack8(kf + 8);
  if (lane == 63) {
    float* ep = ebtot + ((size_t)b * 16 + c) * 512 + kbase;
#pragma unroll
    for (int cc = 0; cc < 16; ++cc) ep[cc] = expf(gf[cc]);
  }
}

// ---------------------------------------------------------------------------
// Fused intra+kv, all-MFMA. grid (vh2, chunk16, bh8) = 256 blocks.
// ---------------------------------------------------------------------------
__global__ __launch_bounds__(256)
void intra_kv_k(const unsigned short* __restrict__ q16, const unsigned short* __restrict__ k16,
                const unsigned short* __restrict__ v, float* __restrict__ o,
                unsigned short* __restrict__ ST) {
  __shared__ __align__(16) unsigned short Qs[64 * 136];
  __shared__ __align__(16) unsigned short Ks[64 * 136];
  __shared__ __align__(16) unsigned short Kt[128 * 68];  // [k][j]
  __shared__ __align__(16) unsigned short Vt[128 * 68];  // [v-half][j]
  __shared__ __align__(16) unsigned short Asb[64 * 68];  // bf16 masked A
  const int t = threadIdx.x;
  const int vh = blockIdx.x, c = blockIdx.y, bh = blockIdx.z;
  const int b = bh >> 2, h = bh & 3;
  const size_t rowbase = (size_t)b * 1024 + c * 64;

#pragma unroll
  for (int u2 = 0; u2 < 4; ++u2) {
    const int id = t + (u2 << 8);
    const int row = id >> 4, kg = id & 15;
    vu4 rq = *(const vu4*)(q16 + (rowbase + row) * 512 + h * 128 + kg * 8);
    *(vu4*)&Qs[row * 136 + kg * 8] = rq;
    vu4 rk = *(const vu4*)(k16 + (rowbase + row) * 512 + h * 128 + kg * 8);
    *(vu4*)&Ks[row * 136 + kg * 8] = rk;
    const unsigned short* kp = (const unsigned short*)&rk;
#pragma unroll
    for (int u = 0; u < 8; ++u)
      Kt[(kg * 8 + u) * 68 + row] = kp[u];
    vu4 rv = *(const vu4*)(v + (rowbase + row) * 1024 + h * 256 + vh * 128 + kg * 8);
    const unsigned short* vp = (const unsigned short*)&rv;
#pragma unroll
    for (int u = 0; u < 8; ++u)
      Vt[(kg * 8 + u) * 68 + row] = vp[u];
  }
  __syncthreads();

  const int w = t >> 6, lane = t & 63;
  const int qd = lane >> 4, m = lane & 15;

  // phase 1: A = tril(Q K^T)
  {
    short8 af[4];
#pragma unroll
    for (int kf = 0; kf < 4; ++kf)
      af[kf] = *(const short8*)&Qs[(w * 16 + m) * 136 + kf * 32 + qd * 8];
    vf4 acc[4];
#pragma unroll
    for (int jt = 0; jt < 4; ++jt) acc[jt] = vzero();
#pragma unroll
    for (int jt = 0; jt < 4; ++jt)
#pragma unroll
      for (int kf = 0; kf < 4; ++kf) {
        short8 bfr = *(const short8*)&Ks[(jt * 16 + m) * 136 + kf * 32 + qd * 8];
        acc[jt] = __builtin_amdgcn_mfma_f32_16x16x32_bf16(af[kf], bfr, acc[jt], 0, 0, 0);
      }
#pragma unroll
    for (int jt = 0; jt < 4; ++jt)
#pragma unroll
      for (int r = 0; r < 4; ++r) {
        const int i = w * 16 + qd * 4 + r;
        const int j = jt * 16 + m;
        Asb[i * 68 + j] = f2bf((j <= i) ? acc[jt][r] : 0.f);
      }
  }
  __syncthreads();

  // phase 2: o_intra = A @ V
  {
    vf4 acc2[4][2];
#pragma unroll
    for (int mt = 0; mt < 4; ++mt) { acc2[mt][0] = vzero(); acc2[mt][1] = vzero(); }
#pragma unroll
    for (int kf = 0; kf < 2; ++kf) {
      short8 bf0 = *(const short8*)&Vt[(w * 32 + m) * 68 + kf * 32 + qd * 8];
      short8 bf1 = *(const short8*)&Vt[(w * 32 + 16 + m) * 68 + kf * 32 + qd * 8];
#pragma unroll
      for (int mt = 0; mt < 4; ++mt) {
        short8 af = *(const short8*)&Asb[(mt * 16 + m) * 68 + kf * 32 + qd * 8];
        acc2[mt][0] = __builtin_amdgcn_mfma_f32_16x16x32_bf16(af, bf0, acc2[mt][0], 0, 0, 0);
        acc2[mt][1] = __builtin_amdgcn_mfma_f32_16x16x32_bf16(af, bf1, acc2[mt][1], 0, 0, 0);
      }
    }
#pragma unroll
    for (int mt = 0; mt < 4; ++mt)
#pragma unroll
      for (int nt = 0; nt < 2; ++nt)
#pragma unroll
        for (int r = 0; r < 4; ++r) {
          const int i = mt * 16 + qd * 4 + r;
          const int vc = h * 256 + vh * 128 + w * 32 + nt * 16 + m;
          o[(rowbase + i) * 1024 + vc] = acc2[mt][nt][r];
        }
  }

  // phase 3: ST[v][k] = V^T @ K
  {
    short8 af3[2][2];
#pragma unroll
    for (int mt = 0; mt < 2; ++mt)
#pragma unroll
      for (int kf = 0; kf < 2; ++kf)
        af3[mt][kf] = *(const short8*)&Vt[(w * 32 + mt * 16 + m) * 68 + kf * 32 + qd * 8];
#pragma unroll
    for (int nt = 0; nt < 8; ++nt) {
      vf4 a0 = vzero(), a1 = vzero();
#pragma unroll
      for (int kf = 0; kf < 2; ++kf) {
        short8 bfr = *(const short8*)&Kt[(nt * 16 + m) * 68 + kf * 32 + qd * 8];
        a0 = __builtin_amdgcn_mfma_f32_16x16x32_bf16(af3[0][kf], bfr, a0, 0, 0, 0);
        a1 = __builtin_amdgcn_mfma_f32_16x16x32_bf16(af3[1][kf], bfr, a1, 0, 0, 0);
      }
      const size_t sbase = (size_t)(bh * 16 + c) * 256 + vh * 128 + w * 32;
#pragma unroll
      for (int r = 0; r < 4; ++r) {
        ST[(sbase + qd * 4 + r) * 128 + nt * 16 + m] = f2bf(a0[r]);
        ST[(sbase + 16 + qd * 4 + r) * 128 + nt * 16 + m] = f2bf(a1[r]);
      }
    }
  }
}

// ---------------------------------------------------------------------------
// State scan in place on bf16 ST[v][k]; fp32 carry; per-k decay vector.
// ---------------------------------------------------------------------------
__global__ __launch_bounds__(256)
void state_scan_k(unsigned short* __restrict__ ST, const float* __restrict__ ebtot) {
  const int idx = blockIdx.x * 256 + threadIdx.x;  // 0..32767
  const int kg = idx & 15;
  const int vv = (idx >> 4) & 255;
  const int bh = idx >> 12;
  const int b = bh >> 2, h = bh & 3;
  float s[8];
#pragma unroll
  for (int u = 0; u < 8; ++u) s[u] = 0.f;
  for (int c = 0; c < 16; ++c) {
    unsigned short* p = ST + ((size_t)(bh * 16 + c) * 256 + vv) * 128 + kg * 8;
    const float* ep = ebtot + ((size_t)b * 16 + c) * 512 + h * 128 + kg * 8;
    float e[8];
    *(vf4*)&e[0] = *(const vf4*)ep;
    *(vf4*)&e[4] = *(const vf4*)(ep + 4);
    float kv[8];
    unpack8(*(const vu4*)p, kv);
    *(vu4*)p = pack8(s);
#pragma unroll
    for (int u = 0; u < 8; ++u) s[u] = (s[u] + kv[u]) * e[u];
  }
}

// ---------------------------------------------------------------------------
// o += Q~ @ S_c via MFMA. grid (vt2, chunk16, bh8) = 256 blocks.
// ---------------------------------------------------------------------------
__global__ __launch_bounds__(256)
void o_inter_k(const unsigned short* __restrict__ q16, const unsigned short* __restrict__ ST,
               float* __restrict__ o) {
  __shared__ __align__(16) unsigned short Qs[64 * 136];
  __shared__ __align__(16) unsigned short Ss[128 * 136];
  const int t = threadIdx.x;
  const int vt = blockIdx.x, c = blockIdx.y, bh = blockIdx.z;
  const int b = bh >> 2, h = bh & 3;
  const size_t rowbase = (size_t)b * 1024 + c * 64;

#pragma unroll
  for (int u2 = 0; u2 < 4; ++u2) {
    const int id = t + (u2 << 8);
    const int row = id >> 4, kg = id & 15;
    *(vu4*)&Qs[row * 136 + kg * 8] =
        *(const vu4*)(q16 + (rowbase + row) * 512 + h * 128 + kg * 8);
  }
#pragma unroll
  for (int u2 = 0; u2 < 8; ++u2) {
    const int id = t + (u2 << 8);
    const int vrow = id >> 4, kg = id & 15;
    *(vu4*)&Ss[vrow * 136 + kg * 8] =
        *(const vu4*)(ST + ((size_t)(bh * 16 + c) * 256 + vt * 128 + vrow) * 128 + kg * 8);
  }
  __syncthreads();

  const int w = t >> 6, lane = t & 63;
  const int qd = lane >> 4, m = lane & 15;
  short8 af[4];
#pragma unroll
  for (int kf = 0; kf < 4; ++kf)
    af[kf] = *(const short8*)&Qs[(w * 16 + m) * 136 + kf * 32 + qd * 8];
#pragma unroll
  for (int nt = 0; nt < 8; ++nt) {
    vf4 acc = vzero();
#pragma unroll
    for (int kf = 0; kf < 4; ++kf) {
      short8 bfr = *(const short8*)&Ss[(nt * 16 + m) * 136 + kf * 32 + qd * 8];
      acc = __builtin_amdgcn_mfma_f32_16x16x32_bf16(af[kf], bfr, acc, 0, 0, 0);
    }
    float* base = o + (rowbase + w * 16 + qd * 4) * 1024 + h * 256 + vt * 128 + nt * 16 + m;
#pragma unroll
    for (int r = 0; r < 4; ++r)
      base[(size_t)r * 1024] += acc[r];
  }
}

// ---------------------------------------------------------------------------
// RMSNorm over DV=256 + silu-gate; obuf fp32 -> obuf_b bf16.
// ---------------------------------------------------------------------------
__global__ __launch_bounds__(256)
void norm_gate_k(const float* __restrict__ o, const float* __restrict__ rmsw,
                 const unsigned short* __restrict__ sg,
                 unsigned short* __restrict__ ob) {
  __shared__ float red[4];
  const int grp = blockIdx.x;
  const int row = grp >> 2, h = grp & 3;
  const int t = threadIdx.x;
  const size_t idx = (size_t)row * 1024 + h * 256 + t;
  const float val = o[idx];
  float ss = val * val;
#pragma unroll
  for (int mm = 1; mm < 64; mm <<= 1) ss += __shfl_xor(ss, mm, 64);
  if ((t & 63) == 0) red[t >> 6] = ss;
  __syncthreads();
  const float tot = red[0] + red[1] + red[2] + red[3];
  const float scale = rsqrtf(tot * (1.f / 256.f) + 1e-5f);
  ob[idx] = f2bf(val * scale * rmsw[t] * bf2f((unsigned int)sg[idx]));
}

// ---------------------------------------------------------------------------
extern "C" void kernel_launch(void* const* d_in, const int* in_sizes, int n_in,
                              void* d_out, int out_size, void* d_ws, size_t ws_size,
                              hipStream_t stream) {
  const float* x    = (const float*)d_in[0];
  const float* Wq   = (const float*)d_in[1];
  const float* Wk   = (const float*)d_in[2];
  const float* Wv   = (const float*)d_in[3];
  const float* Wg   = (const float*)d_in[4];
  const float* Wgk1 = (const float*)d_in[5];
  const float* Wgk2 = (const float*)d_in[6];
  const float* bgk2 = (const float*)d_in[7];
  const float* Wout = (const float*)d_in[8];
  const float* rmsw = (const float*)d_in[9];

  const size_t MB = 1u << 20;
  char* w = (char*)d_ws;
  unsigned short* qb16   = (unsigned short*)(w);           // [0,2) MB bf16
  unsigned short* kb16   = (unsigned short*)(w + 2 * MB);  // [2,4)
  unsigned short* vbuf   = (unsigned short*)(w + 4 * MB);  // [4,8)
  unsigned short* sgbuf  = (unsigned short*)(w + 8 * MB);  // [8,12)
  float*          obuf   = (float*)(w + 12 * MB);          // [12,20) fp32
  char*           sreg   = w + 20 * MB;                    // [20,28) multi-phase
  unsigned short* xb     = (unsigned short*)sreg;          //   phase 0: 4 MB
  unsigned short* STbuf  = (unsigned short*)sreg;          //   phase A: 8 MB [v][k]
  unsigned short* obuf_b = (unsigned short*)sreg;          //   phase B: 4 MB
  float*          xlbuf  = (float*)(w + 28 * MB);          // 128 KB
  float*          ebbuf  = (float*)(w + 28 * MB + 131072); // 64 KB
  unsigned short* wqT    = (unsigned short*)(w + 29 * MB); // 1 MB
  unsigned short* wkT    = (unsigned short*)(w + 30 * MB); // 1 MB
  unsigned short* wvT    = (unsigned short*)(w + 31 * MB); // 2 MB
  unsigned short* wgT    = (unsigned short*)(w + 33 * MB); // 2 MB
  unsigned short* woT    = (unsigned short*)(w + 35 * MB); // 2 MB

  prep_k<<<dim3(96, 16), 256, 0, stream>>>(Wq, Wk, Wv, Wg, Wout, x,
                                           wqT, wkT, wvT, wgT, woT, xb);
  lowrank_k<<<2048, 64, 0, stream>>>(x, Wgk1, xlbuf);
  proj_mfma_k<<<dim3(24, 32), 256, 0, stream>>>(xb, wqT, wkT, wvT, wgT, qb16, kb16, vbuf, sgbuf);
  gate_scan_k<<<256, 256, 0, stream>>>(xlbuf, Wgk2, bgk2, qb16, kb16, ebbuf);
  intra_kv_k<<<dim3(2, 16, 8), 256, 0, stream>>>(qb16, kb16, vbuf, obuf, STbuf);
  state_scan_k<<<128, 256, 0, stream>>>(STbuf, ebbuf);
  o_inter_k<<<dim3(2, 16, 8), 256, 0, stream>>>(qb16, STbuf, obuf);
  norm_gate_k<<<8192, 256, 0, stream>>>(obuf, rmsw, sgbuf, obuf_b);
  out_mfma_k<<<dim3(8, 32), 256, 0, stream>>>(obuf_b, woT, (float*)d_out);
}